// Round 2
// baseline (2540.524 us; speedup 1.0000x reference)
//
#include <hip/hip_runtime.h>

#define BB   32
#define NN   512
#define NH   8
#define FIN  768
#define FHID 64
#define NROWS (BB*NN)   // 16384

__device__ __forceinline__ float lrelu_f(float s){ return s >= 0.f ? s : 0.2f*s; }
__device__ __forceinline__ float elu_f(float s){ return s > 0.f ? s : expm1f(s); }

// ---------------------------------------------------------------------------
// K1: adjacency -> bitmask words; node type -> per-type gathered row lists
// ---------------------------------------------------------------------------
__global__ __launch_bounds__(256) void prep_kernel(
    const int* __restrict__ adj, const float* __restrict__ vt,
    unsigned long long* __restrict__ maskw,
    int* __restrict__ rowlist, int* __restrict__ counts)
{
  int row  = blockIdx.x * 4 + (threadIdx.x >> 6);
  int lane = threadIdx.x & 63;
  const int* arow = adj + (long)row * NN;
  #pragma unroll
  for (int w = 0; w < 8; ++w) {
    unsigned long long bal = __ballot(arow[w*64 + lane] > 0);
    if (lane == 0) maskw[(long)row*8 + w] = bal;
  }
  if (lane == 0) {
    const float* v = vt + (long)row*3;
    int t = v[1] > 0.5f ? 1 : (v[2] > 0.5f ? 2 : 0);
    int pos = atomicAdd(&counts[t], 1);
    rowlist[t*NROWS + pos] = row;
  }
}

// ---------------------------------------------------------------------------
// K2/K5: gathered-row f32 GEMM.  C[row, colbase+0..63] = A[row,:] @ Bm[k,o]
// ---------------------------------------------------------------------------
__global__ __launch_bounds__(256) void gat_gemm(
    const float* __restrict__ A, int lda,
    const float* __restrict__ B0, long sBt, long sBh, int K,
    const int* __restrict__ rowlist, const int* __restrict__ counts,
    float* __restrict__ C, int ldc)
{
  int t   = blockIdx.z;
  int cnt = counts[t];
  int r0  = blockIdx.y * 64;
  if (r0 >= cnt) return;
  const float* Bm = B0 + (long)t*sBt + (long)blockIdx.x*sBh;
  int colbase = blockIdx.x * 64;

  __shared__ float aS[16][68];   // [k][row], padded
  __shared__ float bS[16][64];   // [k][o]
  __shared__ int   rowsS[64];

  int tid = threadIdx.x;
  if (tid < 64) {
    int rr = r0 + tid;
    rowsS[tid] = (rr < cnt) ? rowlist[t*NROWS + rr] : -1;
  }
  __syncthreads();

  int tx = tid & 15, ty = tid >> 4;
  int la_row = tid >> 2, la_k = (tid & 3) * 4;
  int lb_k = tid >> 4,  lb_o = (tid & 15) * 4;
  int rowg = rowsS[la_row];
  const float* aptr = (rowg >= 0) ? (A + (long)rowg*lda) : nullptr;

  float acc[4][4] = {};
  for (int k0 = 0; k0 < K; k0 += 16) {
    float4 av = make_float4(0.f,0.f,0.f,0.f);
    if (aptr) av = *(const float4*)(aptr + k0 + la_k);
    float4 bv = *(const float4*)(Bm + (long)(k0 + lb_k)*64 + lb_o);
    __syncthreads();
    aS[la_k+0][la_row] = av.x;
    aS[la_k+1][la_row] = av.y;
    aS[la_k+2][la_row] = av.z;
    aS[la_k+3][la_row] = av.w;
    *(float4*)&bS[lb_k][lb_o] = bv;
    __syncthreads();
    #pragma unroll
    for (int kk = 0; kk < 16; ++kk) {
      float4 a4 = *(const float4*)&aS[kk][ty*4];
      float4 b4 = *(const float4*)&bS[kk][tx*4];
      float aa[4] = {a4.x, a4.y, a4.z, a4.w};
      float bb[4] = {b4.x, b4.y, b4.z, b4.w};
      #pragma unroll
      for (int i = 0; i < 4; ++i)
        #pragma unroll
        for (int j = 0; j < 4; ++j)
          acc[i][j] += aa[i]*bb[j];
    }
  }
  #pragma unroll
  for (int i = 0; i < 4; ++i) {
    int rr = ty*4 + i;
    int rg = rowsS[rr];
    if (r0 + rr < cnt && rg >= 0) {
      float4 v = make_float4(acc[i][0], acc[i][1], acc[i][2], acc[i][3]);
      *(float4*)(C + (long)rg*ldc + colbase + tx*4) = v;
    }
  }
}

// ---------------------------------------------------------------------------
// K3: GAT layer-1 attention. 4 blocks per (b,h), each owns 128 query rows.
// hp[b,:,h,:] fully in LDS (needed as PV values for all m). 4 blocks/CU.
// ---------------------------------------------------------------------------
__global__ __launch_bounds__(256, 4) void gat1_attn(
    const float* __restrict__ hp1, const unsigned long long* __restrict__ maskw,
    const float* __restrict__ a_src, const float* __restrict__ a_dst,
    const float* __restrict__ b1, float* __restrict__ xout)
{
  extern __shared__ float sm[];
  float* hpS  = sm;              // 512*64 = 32768
  float* srcS = hpS + 32768;     // 512
  float* dstS = srcS + 512;      // 512
  float* pS   = dstS + 512;      // 8*512 = 4096   (reduction scratch aliases)
  float* rcpS = pS + 4096;       // 8
  float4* hpS4 = (float4*)hpS;

  int bh = blockIdx.x >> 2, q = blockIdx.x & 3;
  int b = bh >> 3, h = bh & 7;
  int tid = threadIdx.x;
  int og = tid & 15, m16 = tid >> 4;

  // load hp[b, :, h, :] -> LDS
  for (int it = 0; it < 32; ++it) {
    int fi = it*256 + tid;
    int m = fi >> 4, o4 = fi & 15;
    hpS4[m*16 + o4] = *(const float4*)(hp1 + ((long)(b*NN + m)*512 + h*64 + o4*4));
  }
  __syncthreads();

  // src/dst dots for all 512 rows (16 lanes per row)
  float4 as4 = *(const float4*)(a_src + h*64 + og*4);
  float4 ad4 = *(const float4*)(a_dst + h*64 + og*4);
  for (int it = 0; it < 32; ++it) {
    int m = it*16 + m16;
    float4 hv = hpS4[m*16 + og];
    float ls = hv.x*as4.x + hv.y*as4.y + hv.z*as4.z + hv.w*as4.w;
    float ld = hv.x*ad4.x + hv.y*ad4.y + hv.z*ad4.z + hv.w*ad4.w;
    #pragma unroll
    for (int mk = 1; mk <= 8; mk <<= 1) {
      ls += __shfl_xor(ls, mk);
      ld += __shfl_xor(ld, mk);
    }
    if (og == 0) { srcS[m] = ls; dstS[m] = ld; }
  }

  int team = tid >> 5, lane32 = tid & 31;
  for (int c8l = 0; c8l < 16; ++c8l) {
    int c8 = q*16 + c8l;
    __syncthreads();   // protects pS reuse (and first-iter src/dst visibility)
    int row = c8*8 + team;
    float srcv = srcS[row];
    const unsigned long long* mrow = maskw + (long)(b*NN + row)*8;

    float ev[16];
    float emax = -3.0e38f;
    #pragma unroll
    for (int j = 0; j < 16; ++j) {
      int m = j*32 + lane32;
      unsigned long long w = mrow[j >> 1];
      int bit = (int)((w >> (((j & 1) << 5) + lane32)) & 1ull);
      float s = srcv + dstS[m];
      float e = bit ? lrelu_f(s) : -1.0e9f;
      ev[j] = e;
      emax = fmaxf(emax, e);
    }
    #pragma unroll
    for (int mk = 1; mk <= 16; mk <<= 1) emax = fmaxf(emax, __shfl_xor(emax, mk));
    float lsum = 0.f;
    #pragma unroll
    for (int j = 0; j < 16; ++j) {
      float p = __expf(ev[j] - emax);
      lsum += p;
      pS[team*512 + j*32 + lane32] = p;
    }
    #pragma unroll
    for (int mk = 1; mk <= 16; mk <<= 1) lsum += __shfl_xor(lsum, mk);
    if (lane32 == 0) rcpS[team] = 1.f / lsum;
    __syncthreads();

    // PV: thread (m16,og) covers m = mq*64 + m16*4 + {0..3}, 8 rows each.
    // p read as float4 (broadcast across og lanes), hv as 4x b128.
    float4 acc[8];
    #pragma unroll
    for (int r = 0; r < 8; ++r) acc[r] = make_float4(0.f,0.f,0.f,0.f);
    #pragma unroll
    for (int mq = 0; mq < 8; ++mq) {
      int mbase = mq*64 + m16*4;
      float4 hv0 = hpS4[(mbase+0)*16 + og];
      float4 hv1 = hpS4[(mbase+1)*16 + og];
      float4 hv2 = hpS4[(mbase+2)*16 + og];
      float4 hv3 = hpS4[(mbase+3)*16 + og];
      #pragma unroll
      for (int r = 0; r < 8; ++r) {
        float4 p4 = *(const float4*)&pS[r*512 + mbase];
        acc[r].x += p4.x*hv0.x + p4.y*hv1.x + p4.z*hv2.x + p4.w*hv3.x;
        acc[r].y += p4.x*hv0.y + p4.y*hv1.y + p4.z*hv2.y + p4.w*hv3.y;
        acc[r].z += p4.x*hv0.z + p4.y*hv1.z + p4.z*hv2.z + p4.w*hv3.z;
        acc[r].w += p4.x*hv0.w + p4.y*hv1.w + p4.z*hv2.w + p4.w*hv3.w;
      }
    }
    #pragma unroll
    for (int r = 0; r < 8; ++r) {
      acc[r].x += __shfl_xor(acc[r].x, 16); acc[r].y += __shfl_xor(acc[r].y, 16);
      acc[r].z += __shfl_xor(acc[r].z, 16); acc[r].w += __shfl_xor(acc[r].w, 16);
      acc[r].x += __shfl_xor(acc[r].x, 32); acc[r].y += __shfl_xor(acc[r].y, 32);
      acc[r].z += __shfl_xor(acc[r].z, 32); acc[r].w += __shfl_xor(acc[r].w, 32);
    }
    __syncthreads();                    // all PV reads of pS done
    int wv = tid >> 6, lane = tid & 63;
    if (lane < 16) {
      #pragma unroll
      for (int r = 0; r < 8; ++r)
        ((float4*)pS)[(wv*8 + r)*16 + lane] = acc[r];   // reduction scratch
    }
    __syncthreads();
    if (tid < 128) {
      int r = tid >> 4, o2 = tid & 15;
      float4 s = make_float4(0.f,0.f,0.f,0.f);
      #pragma unroll
      for (int w = 0; w < 4; ++w) {
        float4 v = ((float4*)pS)[(w*8 + r)*16 + o2];
        s.x += v.x; s.y += v.y; s.z += v.z; s.w += v.w;
      }
      float rc = rcpS[r];
      float4 bb = *(const float4*)(b1 + o2*4);
      float4 o;
      o.x = elu_f(s.x*rc + bb.x); o.y = elu_f(s.y*rc + bb.y);
      o.z = elu_f(s.z*rc + bb.z); o.w = elu_f(s.w*rc + bb.w);
      int rown = c8*8 + r;
      *(float4*)(xout + ((long)(b*NN + rown)*512 + h*64 + o2*4)) = o;
    }
  }
}

// ---------------------------------------------------------------------------
// K6: GAT layer-2 attention (rows 0,1 only) + ELU + MLP + log_softmax.
// ---------------------------------------------------------------------------
__global__ __launch_bounds__(256) void gat2_final(
    const float* __restrict__ hp2, const unsigned long long* __restrict__ maskw,
    const float* __restrict__ a_src2, const float* __restrict__ a_dst2,
    const float* __restrict__ b2,
    const float* __restrict__ fc1_w, const float* __restrict__ fc1_b,
    const float* __restrict__ fc2_w, const float* __restrict__ fc2_b,
    const float* __restrict__ fc3_w, const float* __restrict__ fc3_b,
    float* __restrict__ out)
{
  extern __shared__ float sm[];
  float* hpS  = sm;              // 32768
  float* dstS = hpS + 32768;     // 512
  float* srcS = dstS + 512;      // 512
  float* pS   = srcS + 512;      // 512
  float* redS = pS + 512;        // 256
  float* outS = redS + 256;      // 128
  float* vS   = outS + 128;      // 64
  float* y1S  = vS + 64;         // 192
  float* redM = y1S + 192;       // 8
  float4* hpS4 = (float4*)hpS;

  int b = blockIdx.x;
  int tid = threadIdx.x;
  int og = tid & 15, m16 = tid >> 4;

  for (int it = 0; it < 32; ++it) {
    int fi = it*256 + tid;
    int m = fi >> 4, o4 = fi & 15;
    hpS4[m*16 + o4] = *(const float4*)(hp2 + (long)(b*NN + m)*64 + o4*4);
  }
  __syncthreads();

  float4 as4 = *(const float4*)(a_src2 + og*4);
  float4 ad4 = *(const float4*)(a_dst2 + og*4);
  for (int it = 0; it < 32; ++it) {
    int m = it*16 + m16;
    float4 hv = hpS4[m*16 + og];
    float ls = hv.x*as4.x + hv.y*as4.y + hv.z*as4.z + hv.w*as4.w;
    float ld = hv.x*ad4.x + hv.y*ad4.y + hv.z*ad4.z + hv.w*ad4.w;
    #pragma unroll
    for (int mk = 1; mk <= 8; mk <<= 1) {
      ls += __shfl_xor(ls, mk);
      ld += __shfl_xor(ld, mk);
    }
    if (og == 0) { srcS[m] = ls; dstS[m] = ld; }
  }
  __syncthreads();

  for (int n = 0; n < 2; ++n) {
    float srcv = srcS[n];
    const unsigned long long* mrow = maskw + (long)(b*NN + n)*8;
    int m0 = tid, m1 = tid + 256;
    unsigned long long w0 = mrow[m0 >> 6], w1 = mrow[m1 >> 6];
    float s0 = srcv + dstS[m0], s1 = srcv + dstS[m1];
    float e0 = ((w0 >> (m0 & 63)) & 1ull) ? lrelu_f(s0) : -1.0e9f;
    float e1 = ((w1 >> (m1 & 63)) & 1ull) ? lrelu_f(s1) : -1.0e9f;
    float emax = fmaxf(e0, e1);
    #pragma unroll
    for (int mk = 1; mk <= 32; mk <<= 1) emax = fmaxf(emax, __shfl_xor(emax, mk));
    if ((tid & 63) == 0) redM[tid >> 6] = emax;
    __syncthreads();
    emax = fmaxf(fmaxf(redM[0], redM[1]), fmaxf(redM[2], redM[3]));
    float p0 = __expf(e0 - emax), p1 = __expf(e1 - emax);
    pS[m0] = p0; pS[m1] = p1;
    float lsum = p0 + p1;
    #pragma unroll
    for (int mk = 1; mk <= 32; mk <<= 1) lsum += __shfl_xor(lsum, mk);
    if ((tid & 63) == 0) redM[4 + (tid >> 6)] = lsum;
    __syncthreads();
    float rcp = 1.f / (redM[4] + redM[5] + redM[6] + redM[7]);

    float4 acc = make_float4(0.f,0.f,0.f,0.f);
    for (int mm = 0; mm < 32; ++mm) {
      int m = mm*16 + m16;
      float4 hv = hpS4[m*16 + og];
      float p = pS[m];
      acc.x += hv.x*p; acc.y += hv.y*p; acc.z += hv.z*p; acc.w += hv.w*p;
    }
    acc.x += __shfl_xor(acc.x, 16); acc.y += __shfl_xor(acc.y, 16);
    acc.z += __shfl_xor(acc.z, 16); acc.w += __shfl_xor(acc.w, 16);
    acc.x += __shfl_xor(acc.x, 32); acc.y += __shfl_xor(acc.y, 32);
    acc.z += __shfl_xor(acc.z, 32); acc.w += __shfl_xor(acc.w, 32);
    __syncthreads();
    if ((tid & 63) < 16) ((float4*)redS)[(tid >> 6)*16 + (tid & 15)] = acc;
    __syncthreads();
    if (tid < 16) {
      float4 s = make_float4(0.f,0.f,0.f,0.f);
      #pragma unroll
      for (int w = 0; w < 4; ++w) {
        float4 v = ((float4*)redS)[w*16 + tid];
        s.x += v.x; s.y += v.y; s.z += v.z; s.w += v.w;
      }
      float4 bb = *(const float4*)(b2 + tid*4);
      outS[n*64 + tid*4 + 0] = elu_f(s.x*rcp + bb.x);
      outS[n*64 + tid*4 + 1] = elu_f(s.y*rcp + bb.y);
      outS[n*64 + tid*4 + 2] = elu_f(s.z*rcp + bb.z);
      outS[n*64 + tid*4 + 3] = elu_f(s.w*rcp + bb.w);
    }
    __syncthreads();
  }

  // MLP
  if (tid < 64) vS[tid] = outS[tid] * outS[64 + tid];
  __syncthreads();
  if (tid < 192) {
    float a = fc1_b[tid];
    for (int o = 0; o < 64; ++o) a += vS[o]*fc1_w[o*192 + tid];
    y1S[tid] = a > 0.f ? a : 0.f;
  }
  __syncthreads();
  if (tid < 64) {
    float a = fc2_b[tid];
    for (int j = 0; j < 192; ++j) a += y1S[j]*fc2_w[j*64 + tid];
    vS[tid] = a > 0.f ? a : 0.f;   // reuse vS as y2
  }
  __syncthreads();
  if (tid == 0) {
    float t0 = fc3_b[0], t1 = fc3_b[1];
    for (int k = 0; k < 64; ++k) {
      float y = vS[k];
      t0 += y*fc3_w[k*2 + 0];
      t1 += y*fc3_w[k*2 + 1];
    }
    float mx = fmaxf(t0, t1);
    float lse = mx + logf(__expf(t0 - mx) + __expf(t1 - mx));
    out[b*2 + 0] = t0 - lse;
    out[b*2 + 1] = t1 - lse;
  }
}

// ---------------------------------------------------------------------------
extern "C" void kernel_launch(void* const* d_in, const int* in_sizes, int n_in,
                              void* d_out, int out_size, void* d_ws, size_t ws_size,
                              hipStream_t stream) {
  const float* emb    = (const float*)d_in[0];
  const int*   adj    = (const int*)d_in[1];
  const float* vt     = (const float*)d_in[2];
  const float* w1     = (const float*)d_in[3];
  const float* a_src1 = (const float*)d_in[4];
  const float* a_dst1 = (const float*)d_in[5];
  const float* b1     = (const float*)d_in[6];
  const float* w2     = (const float*)d_in[7];
  const float* a_src2 = (const float*)d_in[8];
  const float* a_dst2 = (const float*)d_in[9];
  const float* b2     = (const float*)d_in[10];
  const float* fc1_w  = (const float*)d_in[11];
  const float* fc1_b  = (const float*)d_in[12];
  const float* fc2_w  = (const float*)d_in[13];
  const float* fc2_b  = (const float*)d_in[14];
  const float* fc3_w  = (const float*)d_in[15];
  const float* fc3_b  = (const float*)d_in[16];

  char* ws = (char*)d_ws;
  int* counts  = (int*)ws;                                   // 16 B
  int* rowlist = (int*)(ws + 4096);                          // 3*16384*4
  unsigned long long* maskw = (unsigned long long*)(ws + 204800);  // 1 MB
  float* hp1 = (float*)(ws + 204800 + 1048576);              // 33.55 MB (aliased as x)
  float* hp2 = (float*)(ws + 204800 + 1048576 + (size_t)NROWS*512*4); // 4.19 MB
  float* xbuf = hp1;

  hipMemsetAsync(counts, 0, 16, stream);
  prep_kernel<<<NROWS/4, 256, 0, stream>>>(adj, vt, maskw, rowlist, counts);

  // layer 1 transform: K=768, col blocks = 8 heads
  gat_gemm<<<dim3(8, 256, 3), 256, 0, stream>>>(
      emb, FIN, w1, (long)NH*FIN*FHID, (long)FIN*FHID, FIN,
      rowlist, counts, hp1, 512);

  size_t sm1 = (size_t)(32768 + 512 + 512 + 4096 + 8) * 4;
  gat1_attn<<<BB*NH*4, 256, sm1, stream>>>(hp1, maskw, a_src1, a_dst1, b1, xbuf);

  // layer 2 transform: K=512, single 64-col block
  gat_gemm<<<dim3(1, 256, 3), 256, 0, stream>>>(
      xbuf, 512, w2, (long)512*64, 0, 512,
      rowlist, counts, hp2, 64);

  size_t sm2 = (size_t)(32768 + 512 + 512 + 512 + 256 + 128 + 64 + 192 + 8) * 4;
  gat2_final<<<BB, 256, sm2, stream>>>(hp2, maskw, a_src2, a_dst2, b2,
                                       fc1_w, fc1_b, fc2_w, fc2_b, fc3_w, fc3_b,
                                       (float*)d_out);
}

// Round 3
// 539.146 us; speedup vs baseline: 4.7121x; 4.7121x over previous
//
#include <hip/hip_runtime.h>

#define BB   32
#define NN   512
#define NH   8
#define FIN  768
#define FHID 64
#define NROWS (BB*NN)   // 16384

typedef __attribute__((ext_vector_type(8))) short bf16x8;
typedef __attribute__((ext_vector_type(4))) float f32x4;
typedef unsigned long long u64;

__device__ __forceinline__ float lrelu_f(float s){ return fmaxf(s, 0.2f*s); }
__device__ __forceinline__ float elu_f(float s){ return s > 0.f ? s : expm1f(s); }
__device__ __forceinline__ short f2bf(float f){
  unsigned u = __float_as_uint(f);
  return (short)((u + 0x7fffu + ((u >> 16) & 1u)) >> 16);   // RNE
}

// ---------------------------------------------------------------------------
// K1: adjacency -> bitmask words; node type -> per-type gathered row lists
// ---------------------------------------------------------------------------
__global__ __launch_bounds__(256) void prep_kernel(
    const int* __restrict__ adj, const float* __restrict__ vt,
    u64* __restrict__ maskw,
    int* __restrict__ rowlist, int* __restrict__ counts)
{
  int row  = blockIdx.x * 4 + (threadIdx.x >> 6);
  int lane = threadIdx.x & 63;
  const int* arow = adj + (long)row * NN;
  #pragma unroll
  for (int w = 0; w < 8; ++w) {
    u64 bal = __ballot(arow[w*64 + lane] > 0);
    if (lane == 0) maskw[(long)row*8 + w] = bal;
  }
  if (lane == 0) {
    const float* v = vt + (long)row*3;
    int t = v[1] > 0.5f ? 1 : (v[2] > 0.5f ? 2 : 0);
    int pos = atomicAdd(&counts[t], 1);
    rowlist[t*NROWS + pos] = row;
  }
}

// ---------------------------------------------------------------------------
// K2/K5: gathered-row f32 GEMM.
// aHeadMajor: A element (row,k) at A + (row>>9)*262144 + (k>>6)*32768
//                                 + (row&511)*64 + (k&63)   (x head-major)
// cHeadMajor: C row (=b*512+n), head = blockIdx.x:
//   C + ((row>>9)*NH + head)*32768 + (row&511)*64 + col
// ---------------------------------------------------------------------------
__global__ __launch_bounds__(256) void gat_gemm(
    const float* __restrict__ A, int lda,
    const float* __restrict__ B0, long sBt, long sBh, int K,
    const int* __restrict__ rowlist, const int* __restrict__ counts,
    float* __restrict__ C, int ldc, int aHeadMajor, int cHeadMajor)
{
  int t   = blockIdx.z;
  int cnt = counts[t];
  int r0  = blockIdx.y * 64;
  if (r0 >= cnt) return;
  const float* Bm = B0 + (long)t*sBt + (long)blockIdx.x*sBh;
  int colbase = blockIdx.x * 64;

  __shared__ float aS[16][68];   // [k][row], padded
  __shared__ float bS[16][64];   // [k][o]
  __shared__ int   rowsS[64];

  int tid = threadIdx.x;
  if (tid < 64) {
    int rr = r0 + tid;
    rowsS[tid] = (rr < cnt) ? rowlist[t*NROWS + rr] : -1;
  }
  __syncthreads();

  int tx = tid & 15, ty = tid >> 4;
  int la_row = tid >> 2, la_k = (tid & 3) * 4;
  int lb_k = tid >> 4,  lb_o = (tid & 15) * 4;
  int rowg = rowsS[la_row];
  const float* aptr = nullptr;
  if (rowg >= 0) {
    if (aHeadMajor) aptr = A + (long)(rowg >> 9)*262144 + (long)(rowg & 511)*64;
    else            aptr = A + (long)rowg*lda;
  }

  float acc[4][4] = {};
  for (int k0 = 0; k0 < K; k0 += 16) {
    float4 av = make_float4(0.f,0.f,0.f,0.f);
    int kk0 = k0 + la_k;
    if (aptr) {
      if (aHeadMajor) av = *(const float4*)(aptr + (long)(kk0 >> 6)*32768 + (kk0 & 63));
      else            av = *(const float4*)(aptr + kk0);
    }
    float4 bv = *(const float4*)(Bm + (long)(k0 + lb_k)*64 + lb_o);
    __syncthreads();
    aS[la_k+0][la_row] = av.x;
    aS[la_k+1][la_row] = av.y;
    aS[la_k+2][la_row] = av.z;
    aS[la_k+3][la_row] = av.w;
    *(float4*)&bS[lb_k][lb_o] = bv;
    __syncthreads();
    #pragma unroll
    for (int kk = 0; kk < 16; ++kk) {
      float4 a4 = *(const float4*)&aS[kk][ty*4];
      float4 b4 = *(const float4*)&bS[kk][tx*4];
      float aa[4] = {a4.x, a4.y, a4.z, a4.w};
      float bb[4] = {b4.x, b4.y, b4.z, b4.w};
      #pragma unroll
      for (int i = 0; i < 4; ++i)
        #pragma unroll
        for (int j = 0; j < 4; ++j)
          acc[i][j] += aa[i]*bb[j];
    }
  }
  #pragma unroll
  for (int i = 0; i < 4; ++i) {
    int rr = ty*4 + i;
    int rg = rowsS[rr];
    if (r0 + rr < cnt && rg >= 0) {
      float4 v = make_float4(acc[i][0], acc[i][1], acc[i][2], acc[i][3]);
      float* dst;
      if (cHeadMajor)
        dst = C + ((long)(rg >> 9)*NH + blockIdx.x)*32768 + (long)(rg & 511)*64 + tx*4;
      else
        dst = C + (long)rg*ldc + colbase + tx*4;
      *(float4*)dst = v;
    }
  }
}

// ---------------------------------------------------------------------------
// K3: GAT layer-1 attention. One 1024-thread block per (b,h); 16 waves/CU.
// hp slice held in LDS as bf16 TRANSPOSED (hpT[64][520], padded).
// Softmax: one wave per query row (f32, rcp folded into p, p -> bf16 pS).
// PV: mfma_f32_16x16x32_bf16, 16 waves = 4 row-subtiles x 4 col-tiles,
// full K=512 per wave (no cross-wave reduction).
// Writes x = elu(PV + b1) f32 head-major into xout (aliases hp1 region of
// THIS block only; all reads of hp1 complete in phase 0).
// ---------------------------------------------------------------------------
__global__ __launch_bounds__(1024) void gat1_attn(
    const float* __restrict__ hp1, const u64* __restrict__ maskw,
    const float* __restrict__ a_src, const float* __restrict__ a_dst,
    const float* __restrict__ b1, float* __restrict__ xout)
{
  extern __shared__ char smc[];
  short* hpT  = (short*)smc;                 // [64][520] bf16  (66,560 B)
  short* pS   = (short*)(smc + 66560);       // [64][520] bf16  (66,560 B)
  float* srcS = (float*)(smc + 133120);      // [512]
  float* dstS = (float*)(smc + 135168);      // [512]

  int bh = blockIdx.x;
  int b = bh >> 3, h = bh & 7;
  int tid = threadIdx.x;

  // ---- phase 0: load hp slice (contiguous, head-major), src/dst dots,
  //               build bf16 transposed hpT
  {
    int m  = tid >> 1;
    int oh = (tid & 1) * 32;
    const float* hpRow = hp1 + ((long)bh*NN + m)*64 + oh;
    const float* as = a_src + h*64 + oh;
    const float* ad = a_dst + h*64 + oh;
    float ps = 0.f, pd = 0.f;
    #pragma unroll
    for (int q = 0; q < 8; ++q) {
      float4 hv = *(const float4*)(hpRow + q*4);
      float4 av = *(const float4*)(as + q*4);
      float4 dv = *(const float4*)(ad + q*4);
      ps += hv.x*av.x + hv.y*av.y + hv.z*av.z + hv.w*av.w;
      pd += hv.x*dv.x + hv.y*dv.y + hv.z*dv.z + hv.w*dv.w;
      int o = oh + q*4;
      hpT[(o+0)*520 + m] = f2bf(hv.x);
      hpT[(o+1)*520 + m] = f2bf(hv.y);
      hpT[(o+2)*520 + m] = f2bf(hv.z);
      hpT[(o+3)*520 + m] = f2bf(hv.w);
    }
    ps += __shfl_xor(ps, 1);
    pd += __shfl_xor(pd, 1);
    if ((tid & 1) == 0) { srcS[m] = ps; dstS[m] = pd; }
  }
  __syncthreads();

  int wv = tid >> 6, lane = tid & 63;
  int l15 = lane & 15, lg = lane >> 4;
  int cgl = wv >> 2, nt = wv & 3;
  const char* aBase = (const char*)pS  + (cgl*16 + l15)*1040 + lg*16;
  const char* bBase = (const char*)hpT + (nt*16  + l15)*1040 + lg*16;
  int   o_out = nt*16 + l15;
  float bb    = b1[o_out];

  for (int sup = 0; sup < 8; ++sup) {
    // ---- softmax: wave wv owns rows sup*64 + wv*4 + {0..3}
    #pragma unroll
    for (int rr = 0; rr < 4; ++rr) {
      int rloc = wv*4 + rr;
      int row  = sup*64 + rloc;
      float srcv = srcS[row];
      const u64* mrow = maskw + ((long)(b*NN + row))*8;
      float ev[8];
      float emax = -3.0e38f;
      #pragma unroll
      for (int j = 0; j < 8; ++j) {
        u64 w = mrow[j];
        float s = srcv + dstS[j*64 + lane];
        float e = ((w >> lane) & 1ull) ? lrelu_f(s) : -1.0e9f;
        ev[j] = e;
        emax = fmaxf(emax, e);
      }
      #pragma unroll
      for (int mk = 1; mk <= 32; mk <<= 1) emax = fmaxf(emax, __shfl_xor(emax, mk));
      float lsum = 0.f;
      #pragma unroll
      for (int j = 0; j < 8; ++j) { float p = __expf(ev[j] - emax); ev[j] = p; lsum += p; }
      #pragma unroll
      for (int mk = 1; mk <= 32; mk <<= 1) lsum += __shfl_xor(lsum, mk);
      float rcp = 1.f / lsum;
      #pragma unroll
      for (int j = 0; j < 8; ++j)
        pS[rloc*520 + j*64 + lane] = f2bf(ev[j] * rcp);
    }
    __syncthreads();

    // ---- PV via MFMA: acc[4] = P-tile(16x512) @ hpT-tile(512x16)
    f32x4 acc = {0.f, 0.f, 0.f, 0.f};
    #pragma unroll
    for (int ks = 0; ks < 16; ++ks) {
      bf16x8 af = *(const bf16x8*)(aBase + ks*64);
      bf16x8 bf = *(const bf16x8*)(bBase + ks*64);
      acc = __builtin_amdgcn_mfma_f32_16x16x32_bf16(af, bf, acc, 0, 0, 0);
    }
    #pragma unroll
    for (int reg = 0; reg < 4; ++reg) {
      int row = sup*64 + cgl*16 + lg*4 + reg;
      float v = elu_f(acc[reg] + bb);
      xout[((long)bh*NN + row)*64 + o_out] = v;
    }
    __syncthreads();
  }
}

// ---------------------------------------------------------------------------
// K6: GAT layer-2 attention (rows 0,1 only) + ELU + MLP + log_softmax.
// ---------------------------------------------------------------------------
__global__ __launch_bounds__(256) void gat2_final(
    const float* __restrict__ hp2, const u64* __restrict__ maskw,
    const float* __restrict__ a_src2, const float* __restrict__ a_dst2,
    const float* __restrict__ b2,
    const float* __restrict__ fc1_w, const float* __restrict__ fc1_b,
    const float* __restrict__ fc2_w, const float* __restrict__ fc2_b,
    const float* __restrict__ fc3_w, const float* __restrict__ fc3_b,
    float* __restrict__ out)
{
  extern __shared__ float sm[];
  float* hpS  = sm;              // 32768
  float* dstS = hpS + 32768;     // 512
  float* srcS = dstS + 512;      // 512
  float* pS   = srcS + 512;      // 512
  float* redS = pS + 512;        // 256
  float* outS = redS + 256;      // 128
  float* vS   = outS + 128;      // 64
  float* y1S  = vS + 64;         // 192
  float* redM = y1S + 192;       // 8
  float4* hpS4 = (float4*)hpS;

  int b = blockIdx.x;
  int tid = threadIdx.x;
  int og = tid & 15, m16 = tid >> 4;

  for (int it = 0; it < 32; ++it) {
    int fi = it*256 + tid;
    int m = fi >> 4, o4 = fi & 15;
    hpS4[m*16 + o4] = *(const float4*)(hp2 + (long)(b*NN + m)*64 + o4*4);
  }
  __syncthreads();

  float4 as4 = *(const float4*)(a_src2 + og*4);
  float4 ad4 = *(const float4*)(a_dst2 + og*4);
  for (int it = 0; it < 32; ++it) {
    int m = it*16 + m16;
    float4 hv = hpS4[m*16 + og];
    float ls = hv.x*as4.x + hv.y*as4.y + hv.z*as4.z + hv.w*as4.w;
    float ld = hv.x*ad4.x + hv.y*ad4.y + hv.z*ad4.z + hv.w*ad4.w;
    #pragma unroll
    for (int mk = 1; mk <= 8; mk <<= 1) {
      ls += __shfl_xor(ls, mk);
      ld += __shfl_xor(ld, mk);
    }
    if (og == 0) { srcS[m] = ls; dstS[m] = ld; }
  }
  __syncthreads();

  for (int n = 0; n < 2; ++n) {
    float srcv = srcS[n];
    const u64* mrow = maskw + (long)(b*NN + n)*8;
    int m0 = tid, m1 = tid + 256;
    u64 w0 = mrow[m0 >> 6], w1 = mrow[m1 >> 6];
    float s0 = srcv + dstS[m0], s1 = srcv + dstS[m1];
    float e0 = ((w0 >> (m0 & 63)) & 1ull) ? lrelu_f(s0) : -1.0e9f;
    float e1 = ((w1 >> (m1 & 63)) & 1ull) ? lrelu_f(s1) : -1.0e9f;
    float emax = fmaxf(e0, e1);
    #pragma unroll
    for (int mk = 1; mk <= 32; mk <<= 1) emax = fmaxf(emax, __shfl_xor(emax, mk));
    if ((tid & 63) == 0) redM[tid >> 6] = emax;
    __syncthreads();
    emax = fmaxf(fmaxf(redM[0], redM[1]), fmaxf(redM[2], redM[3]));
    float p0 = __expf(e0 - emax), p1 = __expf(e1 - emax);
    pS[m0] = p0; pS[m1] = p1;
    float lsum = p0 + p1;
    #pragma unroll
    for (int mk = 1; mk <= 32; mk <<= 1) lsum += __shfl_xor(lsum, mk);
    if ((tid & 63) == 0) redM[4 + (tid >> 6)] = lsum;
    __syncthreads();
    float rcp = 1.f / (redM[4] + redM[5] + redM[6] + redM[7]);

    float4 acc = make_float4(0.f,0.f,0.f,0.f);
    for (int mm = 0; mm < 32; ++mm) {
      int m = mm*16 + m16;
      float4 hv = hpS4[m*16 + og];
      float p = pS[m];
      acc.x += hv.x*p; acc.y += hv.y*p; acc.z += hv.z*p; acc.w += hv.w*p;
    }
    acc.x += __shfl_xor(acc.x, 16); acc.y += __shfl_xor(acc.y, 16);
    acc.z += __shfl_xor(acc.z, 16); acc.w += __shfl_xor(acc.w, 16);
    acc.x += __shfl_xor(acc.x, 32); acc.y += __shfl_xor(acc.y, 32);
    acc.z += __shfl_xor(acc.z, 32); acc.w += __shfl_xor(acc.w, 32);
    __syncthreads();
    if ((tid & 63) < 16) ((float4*)redS)[(tid >> 6)*16 + (tid & 15)] = acc;
    __syncthreads();
    if (tid < 16) {
      float4 s = make_float4(0.f,0.f,0.f,0.f);
      #pragma unroll
      for (int w = 0; w < 4; ++w) {
        float4 v = ((float4*)redS)[w*16 + tid];
        s.x += v.x; s.y += v.y; s.z += v.z; s.w += v.w;
      }
      float4 bv = *(const float4*)(b2 + tid*4);
      outS[n*64 + tid*4 + 0] = elu_f(s.x*rcp + bv.x);
      outS[n*64 + tid*4 + 1] = elu_f(s.y*rcp + bv.y);
      outS[n*64 + tid*4 + 2] = elu_f(s.z*rcp + bv.z);
      outS[n*64 + tid*4 + 3] = elu_f(s.w*rcp + bv.w);
    }
    __syncthreads();
  }

  // MLP
  if (tid < 64) vS[tid] = outS[tid] * outS[64 + tid];
  __syncthreads();
  if (tid < 192) {
    float a = fc1_b[tid];
    for (int o = 0; o < 64; ++o) a += vS[o]*fc1_w[o*192 + tid];
    y1S[tid] = a > 0.f ? a : 0.f;
  }
  __syncthreads();
  if (tid < 64) {
    float a = fc2_b[tid];
    for (int j = 0; j < 192; ++j) a += y1S[j]*fc2_w[j*64 + tid];
    vS[tid] = a > 0.f ? a : 0.f;
  }
  __syncthreads();
  if (tid == 0) {
    float t0 = fc3_b[0], t1 = fc3_b[1];
    for (int k = 0; k < 64; ++k) {
      float y = vS[k];
      t0 += y*fc3_w[k*2 + 0];
      t1 += y*fc3_w[k*2 + 1];
    }
    float mx = fmaxf(t0, t1);
    float lse = mx + logf(__expf(t0 - mx) + __expf(t1 - mx));
    out[b*2 + 0] = t0 - lse;
    out[b*2 + 1] = t1 - lse;
  }
}

// ---------------------------------------------------------------------------
extern "C" void kernel_launch(void* const* d_in, const int* in_sizes, int n_in,
                              void* d_out, int out_size, void* d_ws, size_t ws_size,
                              hipStream_t stream) {
  const float* emb    = (const float*)d_in[0];
  const int*   adj    = (const int*)d_in[1];
  const float* vt     = (const float*)d_in[2];
  const float* w1     = (const float*)d_in[3];
  const float* a_src1 = (const float*)d_in[4];
  const float* a_dst1 = (const float*)d_in[5];
  const float* b1     = (const float*)d_in[6];
  const float* w2     = (const float*)d_in[7];
  const float* a_src2 = (const float*)d_in[8];
  const float* a_dst2 = (const float*)d_in[9];
  const float* b2     = (const float*)d_in[10];
  const float* fc1_w  = (const float*)d_in[11];
  const float* fc1_b  = (const float*)d_in[12];
  const float* fc2_w  = (const float*)d_in[13];
  const float* fc2_b  = (const float*)d_in[14];
  const float* fc3_w  = (const float*)d_in[15];
  const float* fc3_b  = (const float*)d_in[16];

  char* ws = (char*)d_ws;
  int* counts  = (int*)ws;                                   // 16 B
  int* rowlist = (int*)(ws + 4096);                          // 3*16384*4
  u64* maskw   = (u64*)(ws + 204800);                        // 1 MB
  float* hp1 = (float*)(ws + 204800 + 1048576);              // 33.55 MB head-major (aliased as x)
  float* hp2 = (float*)(ws + 204800 + 1048576 + (size_t)NROWS*512*4); // 4.19 MB
  float* xbuf = hp1;

  hipMemsetAsync(counts, 0, 16, stream);
  prep_kernel<<<NROWS/4, 256, 0, stream>>>(adj, vt, maskw, rowlist, counts);

  // layer 1 transform: K=768, 8 head col-blocks, C head-major
  gat_gemm<<<dim3(8, 256, 3), 256, 0, stream>>>(
      emb, FIN, w1, (long)NH*FIN*FHID, (long)FIN*FHID, FIN,
      rowlist, counts, hp1, 512, 0, 1);

  size_t sm1 = 137216;   // hpT 66,560 + pS 66,560 + srcS 2048 + dstS 2048
  gat1_attn<<<BB*NH, 1024, sm1, stream>>>(hp1, maskw, a_src1, a_dst1, b1, xbuf);

  // layer 2 transform: K=512, A head-major, C row-major [row][64]
  gat_gemm<<<dim3(1, 256, 3), 256, 0, stream>>>(
      xbuf, 512, w2, (long)512*64, 0, 512,
      rowlist, counts, hp2, 64, 1, 0);

  size_t sm2 = (size_t)(32768 + 512 + 512 + 512 + 256 + 128 + 64 + 192 + 8) * 4;
  gat2_final<<<BB, 256, sm2, stream>>>(hp2, maskw, a_src2, a_dst2, b2,
                                       fc1_w, fc1_b, fc2_w, fc2_b, fc3_w, fc3_b,
                                       (float*)d_out);
}

// Round 4
// 429.126 us; speedup vs baseline: 5.9202x; 1.2564x over previous
//
#include <hip/hip_runtime.h>

#define BB   32
#define NN   512
#define NH   8
#define FIN  768
#define FHID 64
#define NROWS (BB*NN)   // 16384

typedef __attribute__((ext_vector_type(8))) short bf16x8;
typedef __attribute__((ext_vector_type(4))) float f32x4;
typedef unsigned long long u64;
typedef unsigned short u16;

__device__ __forceinline__ float lrelu_f(float s){ return fmaxf(s, 0.2f*s); }
__device__ __forceinline__ float elu_f(float s){ return s > 0.f ? s : expm1f(s); }
__device__ __forceinline__ short f2bf(float f){
  unsigned u = __float_as_uint(f);
  return (short)((u + 0x7fffu + ((u >> 16) & 1u)) >> 16);   // RNE
}
__device__ __forceinline__ float bf2f(short s){
  return __uint_as_float(((unsigned)(u16)s) << 16);
}

// ---------------------------------------------------------------------------
// K1: adjacency -> bitmask words; node type -> per-type gathered row lists
// ---------------------------------------------------------------------------
__global__ __launch_bounds__(256) void prep_kernel(
    const int* __restrict__ adj, const float* __restrict__ vt,
    u64* __restrict__ maskw,
    int* __restrict__ rowlist, int* __restrict__ counts)
{
  int row  = blockIdx.x * 4 + (threadIdx.x >> 6);
  int lane = threadIdx.x & 63;
  const int* arow = adj + (long)row * NN;
  #pragma unroll
  for (int w = 0; w < 8; ++w) {
    u64 bal = __ballot(arow[w*64 + lane] > 0);
    if (lane == 0) maskw[(long)row*8 + w] = bal;
  }
  if (lane == 0) {
    const float* v = vt + (long)row*3;
    int t = v[1] > 0.5f ? 1 : (v[2] > 0.5f ? 2 : 0);
    int pos = atomicAdd(&counts[t], 1);
    rowlist[t*NROWS + pos] = row;
  }
}

// ---------------------------------------------------------------------------
// K2: weight transpose+cast: w1[t][h][768][64] -> w1t[(t*8+h)][64][768] bf16
//     w2[t][512][64]        -> w2t[t][64][512] bf16
// blocks 0..23 = w1 (t*8+h), blocks 24..26 = w2 (t)
// ---------------------------------------------------------------------------
__global__ __launch_bounds__(256) void conv_w(
    const float* __restrict__ w1, const float* __restrict__ w2,
    u16* __restrict__ w1t, u16* __restrict__ w2t)
{
  __shared__ float tile[64][68];
  int bid = blockIdx.x, tid = threadIdx.x;
  const float* src; u16* dst; int K;
  if (bid < 24) { src = w1 + (long)bid*768*64; dst = w1t + (long)bid*64*768; K = 768; }
  else { int t = bid - 24; src = w2 + (long)t*512*64; dst = w2t + (long)t*64*512; K = 512; }

  for (int k0 = 0; k0 < K; k0 += 64) {
    __syncthreads();
    #pragma unroll
    for (int i = 0; i < 4; ++i) {
      int kk = i*16 + (tid >> 4);
      int oo = (tid & 15) * 4;
      float4 v = *(const float4*)(src + (long)(k0 + kk)*64 + oo);
      *(float4*)&tile[kk][oo] = v;
    }
    __syncthreads();
    int o = tid >> 2, kp = (tid & 3) * 16;
    bf16x8 r0, r1;
    #pragma unroll
    for (int j = 0; j < 8; ++j) r0[j] = f2bf(tile[kp + j][o]);
    #pragma unroll
    for (int j = 0; j < 8; ++j) r1[j] = f2bf(tile[kp + 8 + j][o]);
    u16* d = dst + (long)o*K + k0 + kp;
    *(bf16x8*)d = r0;
    *(bf16x8*)(d + 8) = r1;
  }
}

// ---------------------------------------------------------------------------
// K3: layer-1 gathered GEMM via bf16 MFMA.
// BM=128, BN=256 (heads hb*4..hb*4+3), 4 waves, wave tile 64x128.
// A: emb f32 -> bf16 LDS fragments; B: w1t bf16 (L2-resident).
// C: hp1b bf16 head-major [(b*8+h)][n][64].
// ---------------------------------------------------------------------------
__global__ __launch_bounds__(256) void gemm1_mfma(
    const float* __restrict__ emb,
    const u16* __restrict__ w1t,
    const int* __restrict__ rowlist, const int* __restrict__ counts,
    u16* __restrict__ hp1b)
{
  int t   = blockIdx.z;
  int cnt = counts[t];
  int r0  = blockIdx.y * 128;
  if (r0 >= cnt) return;
  int hb  = blockIdx.x;                 // 0..1

  __shared__ short aT[4*128*8];         // [kg][row][8]   8 KB
  __shared__ short bT[4*256*8];         // [kg][col][8]  16 KB
  __shared__ int rowsS[128];

  int tid = threadIdx.x;
  if (tid < 128) {
    int rr = r0 + tid;
    rowsS[tid] = (rr < cnt) ? rowlist[t*NROWS + rr] : -1;
  }
  __syncthreads();

  int arow = tid & 127, ahalf = tid >> 7;
  int sg = rowsS[arow]; if (sg < 0) sg = rowsS[0];
  const float* aP = emb + (long)sg*768 + ahalf*16;
  const u16* bP_st = w1t + (((long)t*8 + hb*4)*64 + tid)*768;

  int wv = tid >> 6, l = tid & 63;
  int wr = wv >> 1, wc = wv & 1;
  int l15 = l & 15, lg = l >> 4;

  f32x4 acc[4][8];
  #pragma unroll
  for (int fr = 0; fr < 4; ++fr)
    #pragma unroll
    for (int cf = 0; cf < 8; ++cf) acc[fr][cf] = (f32x4){0.f,0.f,0.f,0.f};

  for (int k0 = 0; k0 < 768; k0 += 32) {
    float4 av0 = *(const float4*)(aP + k0);
    float4 av1 = *(const float4*)(aP + k0 + 4);
    float4 av2 = *(const float4*)(aP + k0 + 8);
    float4 av3 = *(const float4*)(aP + k0 + 12);
    bf16x8 bv0 = *(const bf16x8*)(bP_st + k0);
    bf16x8 bv1 = *(const bf16x8*)(bP_st + k0 + 8);
    bf16x8 bv2 = *(const bf16x8*)(bP_st + k0 + 16);
    bf16x8 bv3 = *(const bf16x8*)(bP_st + k0 + 24);
    __syncthreads();
    bf16x8 pa0, pa1;
    pa0[0]=f2bf(av0.x); pa0[1]=f2bf(av0.y); pa0[2]=f2bf(av0.z); pa0[3]=f2bf(av0.w);
    pa0[4]=f2bf(av1.x); pa0[5]=f2bf(av1.y); pa0[6]=f2bf(av1.z); pa0[7]=f2bf(av1.w);
    pa1[0]=f2bf(av2.x); pa1[1]=f2bf(av2.y); pa1[2]=f2bf(av2.z); pa1[3]=f2bf(av2.w);
    pa1[4]=f2bf(av3.x); pa1[5]=f2bf(av3.y); pa1[6]=f2bf(av3.z); pa1[7]=f2bf(av3.w);
    *(bf16x8*)&aT[((ahalf*2 + 0)*128 + arow)*8] = pa0;
    *(bf16x8*)&aT[((ahalf*2 + 1)*128 + arow)*8] = pa1;
    *(bf16x8*)&bT[(0*256 + tid)*8] = bv0;
    *(bf16x8*)&bT[(1*256 + tid)*8] = bv1;
    *(bf16x8*)&bT[(2*256 + tid)*8] = bv2;
    *(bf16x8*)&bT[(3*256 + tid)*8] = bv3;
    __syncthreads();
    bf16x8 af[4], bfr[8];
    #pragma unroll
    for (int fr = 0; fr < 4; ++fr)
      af[fr] = *(const bf16x8*)&aT[(lg*128 + wr*64 + fr*16 + l15)*8];
    #pragma unroll
    for (int cf = 0; cf < 8; ++cf)
      bfr[cf] = *(const bf16x8*)&bT[(lg*256 + wc*128 + cf*16 + l15)*8];
    #pragma unroll
    for (int fr = 0; fr < 4; ++fr)
      #pragma unroll
      for (int cf = 0; cf < 8; ++cf)
        acc[fr][cf] = __builtin_amdgcn_mfma_f32_16x16x32_bf16(af[fr], bfr[cf], acc[fr][cf], 0, 0, 0);
  }

  #pragma unroll
  for (int fr = 0; fr < 4; ++fr) {
    #pragma unroll
    for (int r = 0; r < 4; ++r) {
      int rloc = wr*64 + fr*16 + lg*4 + r;
      int rg = rowsS[rloc];
      if (rg < 0) continue;
      long obase = ((long)(rg >> 9) * 8) * 32768 + (long)(rg & 511) * 64;
      #pragma unroll
      for (int cf = 0; cf < 8; ++cf) {
        int c = wc*128 + cf*16 + l15;
        hp1b[obase + (long)(hb*4 + (c >> 6))*32768 + (c & 63)] = (u16)f2bf(acc[fr][cf][r]);
      }
    }
  }
}

// ---------------------------------------------------------------------------
// K5: layer-2 gathered GEMM via bf16 MFMA. BM=128, BN=64, wave tile 32x64.
// A: xbf bf16 head-major; B: w2t bf16; C: hp2 f32 [row][64].
// ---------------------------------------------------------------------------
__global__ __launch_bounds__(256) void gemm2_mfma(
    const u16* __restrict__ xbf,
    const u16* __restrict__ w2t,
    const int* __restrict__ rowlist, const int* __restrict__ counts,
    float* __restrict__ hp2)
{
  int t   = blockIdx.z;
  int cnt = counts[t];
  int r0  = blockIdx.y * 128;
  if (r0 >= cnt) return;

  __shared__ short aT[4*128*8];   // 8 KB
  __shared__ short bT[4*64*8];    // 4 KB
  __shared__ int rowsS[128];

  int tid = threadIdx.x;
  if (tid < 128) {
    int rr = r0 + tid;
    rowsS[tid] = (rr < cnt) ? rowlist[t*NROWS + rr] : -1;
  }
  __syncthreads();

  int arow = tid & 127, ahalf = tid >> 7;
  int sg = rowsS[arow]; if (sg < 0) sg = rowsS[0];
  long apart = ((long)(sg >> 9) * 8) * 32768 + (long)(sg & 511) * 64;
  int bcol = tid & 63, bkg = tid >> 6;
  const u16* bP_st = w2t + ((long)t*64 + bcol)*512 + bkg*8;

  int wv = tid >> 6, l = tid & 63;
  int l15 = l & 15, lg = l >> 4;

  f32x4 acc[2][4];
  #pragma unroll
  for (int fr = 0; fr < 2; ++fr)
    #pragma unroll
    for (int cf = 0; cf < 4; ++cf) acc[fr][cf] = (f32x4){0.f,0.f,0.f,0.f};

  for (int k0 = 0; k0 < 512; k0 += 32) {
    int ka = k0 + ahalf*16, ka2 = ka + 8;
    bf16x8 av0 = *(const bf16x8*)(xbf + apart + (long)(ka  >> 6)*32768 + (ka  & 63));
    bf16x8 av1 = *(const bf16x8*)(xbf + apart + (long)(ka2 >> 6)*32768 + (ka2 & 63));
    bf16x8 bv  = *(const bf16x8*)(bP_st + k0);
    __syncthreads();
    *(bf16x8*)&aT[((ahalf*2 + 0)*128 + arow)*8] = av0;
    *(bf16x8*)&aT[((ahalf*2 + 1)*128 + arow)*8] = av1;
    *(bf16x8*)&bT[(bkg*64 + bcol)*8] = bv;
    __syncthreads();
    bf16x8 af[2], bfr[4];
    #pragma unroll
    for (int fr = 0; fr < 2; ++fr)
      af[fr] = *(const bf16x8*)&aT[(lg*128 + wv*32 + fr*16 + l15)*8];
    #pragma unroll
    for (int cf = 0; cf < 4; ++cf)
      bfr[cf] = *(const bf16x8*)&bT[(lg*64 + cf*16 + l15)*8];
    #pragma unroll
    for (int fr = 0; fr < 2; ++fr)
      #pragma unroll
      for (int cf = 0; cf < 4; ++cf)
        acc[fr][cf] = __builtin_amdgcn_mfma_f32_16x16x32_bf16(af[fr], bfr[cf], acc[fr][cf], 0, 0, 0);
  }

  #pragma unroll
  for (int fr = 0; fr < 2; ++fr) {
    #pragma unroll
    for (int r = 0; r < 4; ++r) {
      int rloc = wv*32 + fr*16 + lg*4 + r;
      int rg = rowsS[rloc];
      if (rg < 0) continue;
      #pragma unroll
      for (int cf = 0; cf < 4; ++cf)
        hp2[(long)rg*64 + cf*16 + l15] = acc[fr][cf][r];
    }
  }
}

// ---------------------------------------------------------------------------
// K4: GAT layer-1 attention. One 1024-thread block per (b,h).
// hp slice bf16 -> LDS transposed hpT[64][520]; softmax one wave/row;
// PV via mfma 16x16x32 bf16. Writes x = elu(PV+b1) bf16 IN-PLACE into hp1b
// (block reads its whole slice in phase 0 before any write).
// ---------------------------------------------------------------------------
__global__ __launch_bounds__(1024) void gat1_attn(
    u16* __restrict__ hp1b, const u64* __restrict__ maskw,
    const float* __restrict__ a_src, const float* __restrict__ a_dst,
    const float* __restrict__ b1)
{
  extern __shared__ char smc[];
  short* hpT  = (short*)smc;                 // [64][520] bf16 (66,560 B)
  short* pS   = (short*)(smc + 66560);       // [64][520] bf16 (66,560 B)
  float* srcS = (float*)(smc + 133120);      // [512]
  float* dstS = (float*)(smc + 135168);      // [512]
  float* asS  = (float*)(smc + 137216);      // [64]
  float* adS  = (float*)(smc + 137472);      // [64]

  int bh = blockIdx.x;
  int b = bh >> 3, h = bh & 7;
  int tid = threadIdx.x;

  if (tid < 64) asS[tid] = a_src[h*64 + tid];
  else if (tid < 128) adS[tid - 64] = a_dst[h*64 + (tid - 64)];
  __syncthreads();

  // phase 0: load bf16 slice, dots, transpose into hpT
  {
    int m = tid >> 1, half = tid & 1;
    const u16* hpRow = hp1b + ((long)bh*NN + m)*64 + half*32;
    float ps = 0.f, pd = 0.f;
    #pragma unroll
    for (int q = 0; q < 4; ++q) {
      bf16x8 hv = *(const bf16x8*)(hpRow + q*8);
      int o = half*32 + q*8;
      #pragma unroll
      for (int j = 0; j < 8; ++j) {
        float f = bf2f(hv[j]);
        ps += f * asS[o + j];
        pd += f * adS[o + j];
        hpT[(o + j)*520 + m] = hv[j];
      }
    }
    ps += __shfl_xor(ps, 1);
    pd += __shfl_xor(pd, 1);
    if ((tid & 1) == 0) { srcS[m] = ps; dstS[m] = pd; }
  }
  __syncthreads();

  int wv = tid >> 6, lane = tid & 63;
  int l15 = lane & 15, lg = lane >> 4;
  int cgl = wv >> 2, nt = wv & 3;
  const char* aBase = (const char*)pS  + (cgl*16 + l15)*1040 + lg*16;
  const char* bBase = (const char*)hpT + (nt*16  + l15)*1040 + lg*16;
  int   o_out = nt*16 + l15;
  float bb    = b1[o_out];

  for (int sup = 0; sup < 8; ++sup) {
    #pragma unroll
    for (int rr = 0; rr < 4; ++rr) {
      int rloc = wv*4 + rr;
      int row  = sup*64 + rloc;
      float srcv = srcS[row];
      const u64* mrow = maskw + ((long)(b*NN + row))*8;
      float ev[8];
      float emax = -3.0e38f;
      #pragma unroll
      for (int j = 0; j < 8; ++j) {
        u64 w = mrow[j];
        float s = srcv + dstS[j*64 + lane];
        float e = ((w >> lane) & 1ull) ? lrelu_f(s) : -1.0e9f;
        ev[j] = e;
        emax = fmaxf(emax, e);
      }
      #pragma unroll
      for (int mk = 1; mk <= 32; mk <<= 1) emax = fmaxf(emax, __shfl_xor(emax, mk));
      float lsum = 0.f;
      #pragma unroll
      for (int j = 0; j < 8; ++j) { float p = __expf(ev[j] - emax); ev[j] = p; lsum += p; }
      #pragma unroll
      for (int mk = 1; mk <= 32; mk <<= 1) lsum += __shfl_xor(lsum, mk);
      float rcp = 1.f / lsum;
      #pragma unroll
      for (int j = 0; j < 8; ++j)
        pS[rloc*520 + j*64 + lane] = f2bf(ev[j] * rcp);
    }
    __syncthreads();

    f32x4 acc = {0.f, 0.f, 0.f, 0.f};
    #pragma unroll
    for (int ks = 0; ks < 16; ++ks) {
      bf16x8 af = *(const bf16x8*)(aBase + ks*64);
      bf16x8 bf = *(const bf16x8*)(bBase + ks*64);
      acc = __builtin_amdgcn_mfma_f32_16x16x32_bf16(af, bf, acc, 0, 0, 0);
    }
    #pragma unroll
    for (int reg = 0; reg < 4; ++reg) {
      int row = sup*64 + cgl*16 + lg*4 + reg;
      float v = elu_f(acc[reg] + bb);
      hp1b[((long)bh*NN + row)*64 + o_out] = (u16)f2bf(v);
    }
    __syncthreads();
  }
}

// ---------------------------------------------------------------------------
// K6: GAT layer-2 attention (rows 0,1 only) + ELU + MLP + log_softmax.
// ---------------------------------------------------------------------------
__global__ __launch_bounds__(256) void gat2_final(
    const float* __restrict__ hp2, const u64* __restrict__ maskw,
    const float* __restrict__ a_src2, const float* __restrict__ a_dst2,
    const float* __restrict__ b2,
    const float* __restrict__ fc1_w, const float* __restrict__ fc1_b,
    const float* __restrict__ fc2_w, const float* __restrict__ fc2_b,
    const float* __restrict__ fc3_w, const float* __restrict__ fc3_b,
    float* __restrict__ out)
{
  extern __shared__ float sm[];
  float* hpS  = sm;              // 32768
  float* dstS = hpS + 32768;     // 512
  float* srcS = dstS + 512;      // 512
  float* pS   = srcS + 512;      // 512
  float* redS = pS + 512;        // 256
  float* outS = redS + 256;      // 128
  float* vS   = outS + 128;      // 64
  float* y1S  = vS + 64;         // 192
  float* redM = y1S + 192;       // 8
  float4* hpS4 = (float4*)hpS;

  int b = blockIdx.x;
  int tid = threadIdx.x;
  int og = tid & 15, m16 = tid >> 4;

  for (int it = 0; it < 32; ++it) {
    int fi = it*256 + tid;
    int m = fi >> 4, o4 = fi & 15;
    hpS4[m*16 + o4] = *(const float4*)(hp2 + (long)(b*NN + m)*64 + o4*4);
  }
  __syncthreads();

  float4 as4 = *(const float4*)(a_src2 + og*4);
  float4 ad4 = *(const float4*)(a_dst2 + og*4);
  for (int it = 0; it < 32; ++it) {
    int m = it*16 + m16;
    float4 hv = hpS4[m*16 + og];
    float ls = hv.x*as4.x + hv.y*as4.y + hv.z*as4.z + hv.w*as4.w;
    float ld = hv.x*ad4.x + hv.y*ad4.y + hv.z*ad4.z + hv.w*ad4.w;
    #pragma unroll
    for (int mk = 1; mk <= 8; mk <<= 1) {
      ls += __shfl_xor(ls, mk);
      ld += __shfl_xor(ld, mk);
    }
    if (og == 0) { srcS[m] = ls; dstS[m] = ld; }
  }
  __syncthreads();

  for (int n = 0; n < 2; ++n) {
    float srcv = srcS[n];
    const u64* mrow = maskw + (long)(b*NN + n)*8;
    int m0 = tid, m1 = tid + 256;
    u64 w0 = mrow[m0 >> 6], w1 = mrow[m1 >> 6];
    float s0 = srcv + dstS[m0], s1 = srcv + dstS[m1];
    float e0 = ((w0 >> (m0 & 63)) & 1ull) ? lrelu_f(s0) : -1.0e9f;
    float e1 = ((w1 >> (m1 & 63)) & 1ull) ? lrelu_f(s1) : -1.0e9f;
    float emax = fmaxf(e0, e1);
    #pragma unroll
    for (int mk = 1; mk <= 32; mk <<= 1) emax = fmaxf(emax, __shfl_xor(emax, mk));
    if ((tid & 63) == 0) redM[tid >> 6] = emax;
    __syncthreads();
    emax = fmaxf(fmaxf(redM[0], redM[1]), fmaxf(redM[2], redM[3]));
    float p0 = __expf(e0 - emax), p1 = __expf(e1 - emax);
    pS[m0] = p0; pS[m1] = p1;
    float lsum = p0 + p1;
    #pragma unroll
    for (int mk = 1; mk <= 32; mk <<= 1) lsum += __shfl_xor(lsum, mk);
    if ((tid & 63) == 0) redM[4 + (tid >> 6)] = lsum;
    __syncthreads();
    float rcp = 1.f / (redM[4] + redM[5] + redM[6] + redM[7]);

    float4 acc = make_float4(0.f,0.f,0.f,0.f);
    for (int mm = 0; mm < 32; ++mm) {
      int m = mm*16 + m16;
      float4 hv = hpS4[m*16 + og];
      float p = pS[m];
      acc.x += hv.x*p; acc.y += hv.y*p; acc.z += hv.z*p; acc.w += hv.w*p;
    }
    acc.x += __shfl_xor(acc.x, 16); acc.y += __shfl_xor(acc.y, 16);
    acc.z += __shfl_xor(acc.z, 16); acc.w += __shfl_xor(acc.w, 16);
    acc.x += __shfl_xor(acc.x, 32); acc.y += __shfl_xor(acc.y, 32);
    acc.z += __shfl_xor(acc.z, 32); acc.w += __shfl_xor(acc.w, 32);
    __syncthreads();
    if ((tid & 63) < 16) ((float4*)redS)[(tid >> 6)*16 + (tid & 15)] = acc;
    __syncthreads();
    if (tid < 16) {
      float4 s = make_float4(0.f,0.f,0.f,0.f);
      #pragma unroll
      for (int w = 0; w < 4; ++w) {
        float4 v = ((float4*)redS)[w*16 + tid];
        s.x += v.x; s.y += v.y; s.z += v.z; s.w += v.w;
      }
      float4 bv = *(const float4*)(b2 + tid*4);
      outS[n*64 + tid*4 + 0] = elu_f(s.x*rcp + bv.x);
      outS[n*64 + tid*4 + 1] = elu_f(s.y*rcp + bv.y);
      outS[n*64 + tid*4 + 2] = elu_f(s.z*rcp + bv.z);
      outS[n*64 + tid*4 + 3] = elu_f(s.w*rcp + bv.w);
    }
    __syncthreads();
  }

  if (tid < 64) vS[tid] = outS[tid] * outS[64 + tid];
  __syncthreads();
  if (tid < 192) {
    float a = fc1_b[tid];
    for (int o = 0; o < 64; ++o) a += vS[o]*fc1_w[o*192 + tid];
    y1S[tid] = a > 0.f ? a : 0.f;
  }
  __syncthreads();
  if (tid < 64) {
    float a = fc2_b[tid];
    for (int j = 0; j < 192; ++j) a += y1S[j]*fc2_w[j*64 + tid];
    vS[tid] = a > 0.f ? a : 0.f;
  }
  __syncthreads();
  if (tid == 0) {
    float t0 = fc3_b[0], t1 = fc3_b[1];
    for (int k = 0; k < 64; ++k) {
      float y = vS[k];
      t0 += y*fc3_w[k*2 + 0];
      t1 += y*fc3_w[k*2 + 1];
    }
    float mx = fmaxf(t0, t1);
    float lse = mx + logf(__expf(t0 - mx) + __expf(t1 - mx));
    out[b*2 + 0] = t0 - lse;
    out[b*2 + 1] = t1 - lse;
  }
}

// ---------------------------------------------------------------------------
extern "C" void kernel_launch(void* const* d_in, const int* in_sizes, int n_in,
                              void* d_out, int out_size, void* d_ws, size_t ws_size,
                              hipStream_t stream) {
  const float* emb    = (const float*)d_in[0];
  const int*   adj    = (const int*)d_in[1];
  const float* vt     = (const float*)d_in[2];
  const float* w1     = (const float*)d_in[3];
  const float* a_src1 = (const float*)d_in[4];
  const float* a_dst1 = (const float*)d_in[5];
  const float* b1     = (const float*)d_in[6];
  const float* w2     = (const float*)d_in[7];
  const float* a_src2 = (const float*)d_in[8];
  const float* a_dst2 = (const float*)d_in[9];
  const float* b2     = (const float*)d_in[10];
  const float* fc1_w  = (const float*)d_in[11];
  const float* fc1_b  = (const float*)d_in[12];
  const float* fc2_w  = (const float*)d_in[13];
  const float* fc2_b  = (const float*)d_in[14];
  const float* fc3_w  = (const float*)d_in[15];
  const float* fc3_b  = (const float*)d_in[16];

  char* ws = (char*)d_ws;
  int* counts  = (int*)ws;                       // @0
  int* rowlist = (int*)(ws + 4096);              // 196,608 B
  u64* maskw   = (u64*)(ws + 204800);            // 1 MB
  u16* w1t     = (u16*)(ws + 1310720);           // 2,359,296 B
  u16* w2t     = (u16*)(ws + 3670016);           // 196,608 B
  u16* hp1b    = (u16*)(ws + 3932160);           // 16,777,216 B (x in-place)
  float* hp2   = (float*)(ws + 20709376);        // 4,194,304 B  -> end 24.9 MB

  hipMemsetAsync(counts, 0, 16, stream);
  prep_kernel<<<NROWS/4, 256, 0, stream>>>(adj, vt, maskw, rowlist, counts);
  conv_w<<<27, 256, 0, stream>>>(w1, w2, w1t, w2t);

  gemm1_mfma<<<dim3(2, 128, 3), 256, 0, stream>>>(emb, w1t, rowlist, counts, hp1b);

  size_t sm1 = 137728;
  gat1_attn<<<BB*NH, 1024, sm1, stream>>>(hp1b, maskw, a_src1, a_dst1, b1);

  gemm2_mfma<<<dim3(1, 128, 3), 256, 0, stream>>>(hp1b, w2t, rowlist, counts, hp2);

  size_t sm2 = (size_t)(32768 + 512 + 512 + 512 + 256 + 128 + 64 + 192 + 8) * 4;
  gat2_final<<<BB, 256, sm2, stream>>>(hp2, maskw, a_src2, a_dst2, b2,
                                       fc1_w, fc1_b, fc2_w, fc2_b, fc3_w, fc3_b,
                                       (float*)d_out);
}

// Round 5
// 246.469 us; speedup vs baseline: 10.3077x; 1.7411x over previous
//
#include <hip/hip_runtime.h>

#define BB   32
#define NN   512
#define NH   8
#define FIN  768
#define FHID 64
#define NROWS (BB*NN)   // 16384

typedef __attribute__((ext_vector_type(8))) short bf16x8;
typedef __attribute__((ext_vector_type(4))) float f32x4;
typedef unsigned long long u64;
typedef unsigned short u16;

__device__ __forceinline__ float lrelu_f(float s){ return fmaxf(s, 0.2f*s); }
__device__ __forceinline__ float elu_f(float s){ return s > 0.f ? s : expm1f(s); }
__device__ __forceinline__ short f2bf(float f){
  unsigned u = __float_as_uint(f);
  return (short)((u + 0x7fffu + ((u >> 16) & 1u)) >> 16);   // RNE
}
__device__ __forceinline__ float bf2f(short s){
  return __uint_as_float(((unsigned)(u16)s) << 16);
}

// ---------------------------------------------------------------------------
// K1a: adjacency -> bitmask words (no atomics)
// ---------------------------------------------------------------------------
__global__ __launch_bounds__(256) void prep_kernel(
    const int* __restrict__ adj,
    u64* __restrict__ maskw)
{
  int row  = blockIdx.x * 4 + (threadIdx.x >> 6);
  int lane = threadIdx.x & 63;
  const int* arow = adj + (long)row * NN;
  #pragma unroll
  for (int w = 0; w < 8; ++w) {
    u64 bal = __ballot(arow[w*64 + lane] > 0);
    if (lane == 0) maskw[(long)row*8 + w] = bal;
  }
}

// ---------------------------------------------------------------------------
// K1b: node type -> per-type gathered row lists.
// One thread per row; LDS histogram; 3 global atomics per block (192 total)
// instead of 16384 contended same-line atomics (was 193 us of serialization).
// Rowlist ordering is schedule-dependent but output is invariant to it.
// ---------------------------------------------------------------------------
__global__ __launch_bounds__(256) void rowlist_kernel(
    const float* __restrict__ vt,
    int* __restrict__ rowlist, int* __restrict__ counts)
{
  __shared__ int lc[3];
  __shared__ int lbase[3];
  int tid = threadIdx.x;
  int row = blockIdx.x * 256 + tid;
  if (tid < 3) lc[tid] = 0;
  __syncthreads();
  const float* v = vt + (long)row*3;
  int t = v[1] > 0.5f ? 1 : (v[2] > 0.5f ? 2 : 0);
  int p = atomicAdd(&lc[t], 1);
  __syncthreads();
  if (tid < 3) lbase[tid] = atomicAdd(&counts[tid], lc[tid]);
  __syncthreads();
  rowlist[t*NROWS + lbase[t] + p] = row;
}

// ---------------------------------------------------------------------------
// K2: weight transpose+cast: w1[t][h][768][64] -> w1t[(t*8+h)][64][768] bf16
//     w2[t][512][64]        -> w2t[t][64][512] bf16
// ---------------------------------------------------------------------------
__global__ __launch_bounds__(256) void conv_w(
    const float* __restrict__ w1, const float* __restrict__ w2,
    u16* __restrict__ w1t, u16* __restrict__ w2t)
{
  __shared__ float tile[64][68];
  int bid = blockIdx.x, tid = threadIdx.x;
  const float* src; u16* dst; int K;
  if (bid < 24) { src = w1 + (long)bid*768*64; dst = w1t + (long)bid*64*768; K = 768; }
  else { int t = bid - 24; src = w2 + (long)t*512*64; dst = w2t + (long)t*64*512; K = 512; }

  for (int k0 = 0; k0 < K; k0 += 64) {
    __syncthreads();
    #pragma unroll
    for (int i = 0; i < 4; ++i) {
      int kk = i*16 + (tid >> 4);
      int oo = (tid & 15) * 4;
      float4 v = *(const float4*)(src + (long)(k0 + kk)*64 + oo);
      *(float4*)&tile[kk][oo] = v;
    }
    __syncthreads();
    int o = tid >> 2, kp = (tid & 3) * 16;
    bf16x8 r0, r1;
    #pragma unroll
    for (int j = 0; j < 8; ++j) r0[j] = f2bf(tile[kp + j][o]);
    #pragma unroll
    for (int j = 0; j < 8; ++j) r1[j] = f2bf(tile[kp + 8 + j][o]);
    u16* d = dst + (long)o*K + k0 + kp;
    *(bf16x8*)d = r0;
    *(bf16x8*)(d + 8) = r1;
  }
}

// ---------------------------------------------------------------------------
// K3: layer-1 gathered GEMM via bf16 MFMA.
// BM=128, BN=256 (heads hb*4..hb*4+3), 4 waves, wave tile 64x128.
// ---------------------------------------------------------------------------
__global__ __launch_bounds__(256) void gemm1_mfma(
    const float* __restrict__ emb,
    const u16* __restrict__ w1t,
    const int* __restrict__ rowlist, const int* __restrict__ counts,
    u16* __restrict__ hp1b)
{
  int t   = blockIdx.z;
  int cnt = counts[t];
  int r0  = blockIdx.y * 128;
  if (r0 >= cnt) return;
  int hb  = blockIdx.x;                 // 0..1

  __shared__ short aT[4*128*8];         // [kg][row][8]   8 KB
  __shared__ short bT[4*256*8];         // [kg][col][8]  16 KB
  __shared__ int rowsS[128];

  int tid = threadIdx.x;
  if (tid < 128) {
    int rr = r0 + tid;
    rowsS[tid] = (rr < cnt) ? rowlist[t*NROWS + rr] : -1;
  }
  __syncthreads();

  int arow = tid & 127, ahalf = tid >> 7;
  int sg = rowsS[arow]; if (sg < 0) sg = rowsS[0];
  const float* aP = emb + (long)sg*768 + ahalf*16;
  const u16* bP_st = w1t + (((long)t*8 + hb*4)*64 + tid)*768;

  int wv = tid >> 6, l = tid & 63;
  int wr = wv >> 1, wc = wv & 1;
  int l15 = l & 15, lg = l >> 4;

  f32x4 acc[4][8];
  #pragma unroll
  for (int fr = 0; fr < 4; ++fr)
    #pragma unroll
    for (int cf = 0; cf < 8; ++cf) acc[fr][cf] = (f32x4){0.f,0.f,0.f,0.f};

  for (int k0 = 0; k0 < 768; k0 += 32) {
    float4 av0 = *(const float4*)(aP + k0);
    float4 av1 = *(const float4*)(aP + k0 + 4);
    float4 av2 = *(const float4*)(aP + k0 + 8);
    float4 av3 = *(const float4*)(aP + k0 + 12);
    bf16x8 bv0 = *(const bf16x8*)(bP_st + k0);
    bf16x8 bv1 = *(const bf16x8*)(bP_st + k0 + 8);
    bf16x8 bv2 = *(const bf16x8*)(bP_st + k0 + 16);
    bf16x8 bv3 = *(const bf16x8*)(bP_st + k0 + 24);
    __syncthreads();
    bf16x8 pa0, pa1;
    pa0[0]=f2bf(av0.x); pa0[1]=f2bf(av0.y); pa0[2]=f2bf(av0.z); pa0[3]=f2bf(av0.w);
    pa0[4]=f2bf(av1.x); pa0[5]=f2bf(av1.y); pa0[6]=f2bf(av1.z); pa0[7]=f2bf(av1.w);
    pa1[0]=f2bf(av2.x); pa1[1]=f2bf(av2.y); pa1[2]=f2bf(av2.z); pa1[3]=f2bf(av2.w);
    pa1[4]=f2bf(av3.x); pa1[5]=f2bf(av3.y); pa1[6]=f2bf(av3.z); pa1[7]=f2bf(av3.w);
    *(bf16x8*)&aT[((ahalf*2 + 0)*128 + arow)*8] = pa0;
    *(bf16x8*)&aT[((ahalf*2 + 1)*128 + arow)*8] = pa1;
    *(bf16x8*)&bT[(0*256 + tid)*8] = bv0;
    *(bf16x8*)&bT[(1*256 + tid)*8] = bv1;
    *(bf16x8*)&bT[(2*256 + tid)*8] = bv2;
    *(bf16x8*)&bT[(3*256 + tid)*8] = bv3;
    __syncthreads();
    bf16x8 af[4], bfr[8];
    #pragma unroll
    for (int fr = 0; fr < 4; ++fr)
      af[fr] = *(const bf16x8*)&aT[(lg*128 + wr*64 + fr*16 + l15)*8];
    #pragma unroll
    for (int cf = 0; cf < 8; ++cf)
      bfr[cf] = *(const bf16x8*)&bT[(lg*256 + wc*128 + cf*16 + l15)*8];
    #pragma unroll
    for (int fr = 0; fr < 4; ++fr)
      #pragma unroll
      for (int cf = 0; cf < 8; ++cf)
        acc[fr][cf] = __builtin_amdgcn_mfma_f32_16x16x32_bf16(af[fr], bfr[cf], acc[fr][cf], 0, 0, 0);
  }

  #pragma unroll
  for (int fr = 0; fr < 4; ++fr) {
    #pragma unroll
    for (int r = 0; r < 4; ++r) {
      int rloc = wr*64 + fr*16 + lg*4 + r;
      int rg = rowsS[rloc];
      if (rg < 0) continue;
      long obase = ((long)(rg >> 9) * 8) * 32768 + (long)(rg & 511) * 64;
      #pragma unroll
      for (int cf = 0; cf < 8; ++cf) {
        int c = wc*128 + cf*16 + l15;
        hp1b[obase + (long)(hb*4 + (c >> 6))*32768 + (c & 63)] = (u16)f2bf(acc[fr][cf][r]);
      }
    }
  }
}

// ---------------------------------------------------------------------------
// K5: layer-2 gathered GEMM via bf16 MFMA. BM=128, BN=64, wave tile 32x64.
// ---------------------------------------------------------------------------
__global__ __launch_bounds__(256) void gemm2_mfma(
    const u16* __restrict__ xbf,
    const u16* __restrict__ w2t,
    const int* __restrict__ rowlist, const int* __restrict__ counts,
    float* __restrict__ hp2)
{
  int t   = blockIdx.z;
  int cnt = counts[t];
  int r0  = blockIdx.y * 128;
  if (r0 >= cnt) return;

  __shared__ short aT[4*128*8];   // 8 KB
  __shared__ short bT[4*64*8];    // 4 KB
  __shared__ int rowsS[128];

  int tid = threadIdx.x;
  if (tid < 128) {
    int rr = r0 + tid;
    rowsS[tid] = (rr < cnt) ? rowlist[t*NROWS + rr] : -1;
  }
  __syncthreads();

  int arow = tid & 127, ahalf = tid >> 7;
  int sg = rowsS[arow]; if (sg < 0) sg = rowsS[0];
  long apart = ((long)(sg >> 9) * 8) * 32768 + (long)(sg & 511) * 64;
  int bcol = tid & 63, bkg = tid >> 6;
  const u16* bP_st = w2t + ((long)t*64 + bcol)*512 + bkg*8;

  int wv = tid >> 6, l = tid & 63;
  int l15 = l & 15, lg = l >> 4;

  f32x4 acc[2][4];
  #pragma unroll
  for (int fr = 0; fr < 2; ++fr)
    #pragma unroll
    for (int cf = 0; cf < 4; ++cf) acc[fr][cf] = (f32x4){0.f,0.f,0.f,0.f};

  for (int k0 = 0; k0 < 512; k0 += 32) {
    int ka = k0 + ahalf*16, ka2 = ka + 8;
    bf16x8 av0 = *(const bf16x8*)(xbf + apart + (long)(ka  >> 6)*32768 + (ka  & 63));
    bf16x8 av1 = *(const bf16x8*)(xbf + apart + (long)(ka2 >> 6)*32768 + (ka2 & 63));
    bf16x8 bv  = *(const bf16x8*)(bP_st + k0);
    __syncthreads();
    *(bf16x8*)&aT[((ahalf*2 + 0)*128 + arow)*8] = av0;
    *(bf16x8*)&aT[((ahalf*2 + 1)*128 + arow)*8] = av1;
    *(bf16x8*)&bT[(bkg*64 + bcol)*8] = bv;
    __syncthreads();
    bf16x8 af[2], bfr[4];
    #pragma unroll
    for (int fr = 0; fr < 2; ++fr)
      af[fr] = *(const bf16x8*)&aT[(lg*128 + wv*32 + fr*16 + l15)*8];
    #pragma unroll
    for (int cf = 0; cf < 4; ++cf)
      bfr[cf] = *(const bf16x8*)&bT[(lg*64 + cf*16 + l15)*8];
    #pragma unroll
    for (int fr = 0; fr < 2; ++fr)
      #pragma unroll
      for (int cf = 0; cf < 4; ++cf)
        acc[fr][cf] = __builtin_amdgcn_mfma_f32_16x16x32_bf16(af[fr], bfr[cf], acc[fr][cf], 0, 0, 0);
  }

  #pragma unroll
  for (int fr = 0; fr < 2; ++fr) {
    #pragma unroll
    for (int r = 0; r < 4; ++r) {
      int rloc = wv*32 + fr*16 + lg*4 + r;
      int rg = rowsS[rloc];
      if (rg < 0) continue;
      #pragma unroll
      for (int cf = 0; cf < 4; ++cf)
        hp2[(long)rg*64 + cf*16 + l15] = acc[fr][cf][r];
    }
  }
}

// ---------------------------------------------------------------------------
// K4: GAT layer-1 attention. One 1024-thread block per (b,h).
// ---------------------------------------------------------------------------
__global__ __launch_bounds__(1024) void gat1_attn(
    u16* __restrict__ hp1b, const u64* __restrict__ maskw,
    const float* __restrict__ a_src, const float* __restrict__ a_dst,
    const float* __restrict__ b1)
{
  extern __shared__ char smc[];
  short* hpT  = (short*)smc;                 // [64][520] bf16 (66,560 B)
  short* pS   = (short*)(smc + 66560);       // [64][520] bf16 (66,560 B)
  float* srcS = (float*)(smc + 133120);      // [512]
  float* dstS = (float*)(smc + 135168);      // [512]
  float* asS  = (float*)(smc + 137216);      // [64]
  float* adS  = (float*)(smc + 137472);      // [64]

  int bh = blockIdx.x;
  int b = bh >> 3, h = bh & 7;
  int tid = threadIdx.x;

  if (tid < 64) asS[tid] = a_src[h*64 + tid];
  else if (tid < 128) adS[tid - 64] = a_dst[h*64 + (tid - 64)];
  __syncthreads();

  {
    int m = tid >> 1, half = tid & 1;
    const u16* hpRow = hp1b + ((long)bh*NN + m)*64 + half*32;
    float ps = 0.f, pd = 0.f;
    #pragma unroll
    for (int q = 0; q < 4; ++q) {
      bf16x8 hv = *(const bf16x8*)(hpRow + q*8);
      int o = half*32 + q*8;
      #pragma unroll
      for (int j = 0; j < 8; ++j) {
        float f = bf2f(hv[j]);
        ps += f * asS[o + j];
        pd += f * adS[o + j];
        hpT[(o + j)*520 + m] = hv[j];
      }
    }
    ps += __shfl_xor(ps, 1);
    pd += __shfl_xor(pd, 1);
    if ((tid & 1) == 0) { srcS[m] = ps; dstS[m] = pd; }
  }
  __syncthreads();

  int wv = tid >> 6, lane = tid & 63;
  int l15 = lane & 15, lg = lane >> 4;
  int cgl = wv >> 2, nt = wv & 3;
  const char* aBase = (const char*)pS  + (cgl*16 + l15)*1040 + lg*16;
  const char* bBase = (const char*)hpT + (nt*16  + l15)*1040 + lg*16;
  int   o_out = nt*16 + l15;
  float bb    = b1[o_out];

  for (int sup = 0; sup < 8; ++sup) {
    #pragma unroll
    for (int rr = 0; rr < 4; ++rr) {
      int rloc = wv*4 + rr;
      int row  = sup*64 + rloc;
      float srcv = srcS[row];
      const u64* mrow = maskw + ((long)(b*NN + row))*8;
      float ev[8];
      float emax = -3.0e38f;
      #pragma unroll
      for (int j = 0; j < 8; ++j) {
        u64 w = mrow[j];
        float s = srcv + dstS[j*64 + lane];
        float e = ((w >> lane) & 1ull) ? lrelu_f(s) : -1.0e9f;
        ev[j] = e;
        emax = fmaxf(emax, e);
      }
      #pragma unroll
      for (int mk = 1; mk <= 32; mk <<= 1) emax = fmaxf(emax, __shfl_xor(emax, mk));
      float lsum = 0.f;
      #pragma unroll
      for (int j = 0; j < 8; ++j) { float p = __expf(ev[j] - emax); ev[j] = p; lsum += p; }
      #pragma unroll
      for (int mk = 1; mk <= 32; mk <<= 1) lsum += __shfl_xor(lsum, mk);
      float rcp = 1.f / lsum;
      #pragma unroll
      for (int j = 0; j < 8; ++j)
        pS[rloc*520 + j*64 + lane] = f2bf(ev[j] * rcp);
    }
    __syncthreads();

    f32x4 acc = {0.f, 0.f, 0.f, 0.f};
    #pragma unroll
    for (int ks = 0; ks < 16; ++ks) {
      bf16x8 af = *(const bf16x8*)(aBase + ks*64);
      bf16x8 bf = *(const bf16x8*)(bBase + ks*64);
      acc = __builtin_amdgcn_mfma_f32_16x16x32_bf16(af, bf, acc, 0, 0, 0);
    }
    #pragma unroll
    for (int reg = 0; reg < 4; ++reg) {
      int row = sup*64 + cgl*16 + lg*4 + reg;
      float v = elu_f(acc[reg] + bb);
      hp1b[((long)bh*NN + row)*64 + o_out] = (u16)f2bf(v);
    }
    __syncthreads();
  }
}

// ---------------------------------------------------------------------------
// K6: GAT layer-2 attention (rows 0,1 only) + ELU + MLP + log_softmax.
// ---------------------------------------------------------------------------
__global__ __launch_bounds__(256) void gat2_final(
    const float* __restrict__ hp2, const u64* __restrict__ maskw,
    const float* __restrict__ a_src2, const float* __restrict__ a_dst2,
    const float* __restrict__ b2,
    const float* __restrict__ fc1_w, const float* __restrict__ fc1_b,
    const float* __restrict__ fc2_w, const float* __restrict__ fc2_b,
    const float* __restrict__ fc3_w, const float* __restrict__ fc3_b,
    float* __restrict__ out)
{
  extern __shared__ float sm[];
  float* hpS  = sm;              // 32768
  float* dstS = hpS + 32768;     // 512
  float* srcS = dstS + 512;      // 512
  float* pS   = srcS + 512;      // 512
  float* redS = pS + 512;        // 256
  float* outS = redS + 256;      // 128
  float* vS   = outS + 128;      // 64
  float* y1S  = vS + 64;         // 192
  float* redM = y1S + 192;       // 8
  float4* hpS4 = (float4*)hpS;

  int b = blockIdx.x;
  int tid = threadIdx.x;
  int og = tid & 15, m16 = tid >> 4;

  for (int it = 0; it < 32; ++it) {
    int fi = it*256 + tid;
    int m = fi >> 4, o4 = fi & 15;
    hpS4[m*16 + o4] = *(const float4*)(hp2 + (long)(b*NN + m)*64 + o4*4);
  }
  __syncthreads();

  float4 as4 = *(const float4*)(a_src2 + og*4);
  float4 ad4 = *(const float4*)(a_dst2 + og*4);
  for (int it = 0; it < 32; ++it) {
    int m = it*16 + m16;
    float4 hv = hpS4[m*16 + og];
    float ls = hv.x*as4.x + hv.y*as4.y + hv.z*as4.z + hv.w*as4.w;
    float ld = hv.x*ad4.x + hv.y*ad4.y + hv.z*ad4.z + hv.w*ad4.w;
    #pragma unroll
    for (int mk = 1; mk <= 8; mk <<= 1) {
      ls += __shfl_xor(ls, mk);
      ld += __shfl_xor(ld, mk);
    }
    if (og == 0) { srcS[m] = ls; dstS[m] = ld; }
  }
  __syncthreads();

  for (int n = 0; n < 2; ++n) {
    float srcv = srcS[n];
    const u64* mrow = maskw + (long)(b*NN + n)*8;
    int m0 = tid, m1 = tid + 256;
    u64 w0 = mrow[m0 >> 6], w1 = mrow[m1 >> 6];
    float s0 = srcv + dstS[m0], s1 = srcv + dstS[m1];
    float e0 = ((w0 >> (m0 & 63)) & 1ull) ? lrelu_f(s0) : -1.0e9f;
    float e1 = ((w1 >> (m1 & 63)) & 1ull) ? lrelu_f(s1) : -1.0e9f;
    float emax = fmaxf(e0, e1);
    #pragma unroll
    for (int mk = 1; mk <= 32; mk <<= 1) emax = fmaxf(emax, __shfl_xor(emax, mk));
    if ((tid & 63) == 0) redM[tid >> 6] = emax;
    __syncthreads();
    emax = fmaxf(fmaxf(redM[0], redM[1]), fmaxf(redM[2], redM[3]));
    float p0 = __expf(e0 - emax), p1 = __expf(e1 - emax);
    pS[m0] = p0; pS[m1] = p1;
    float lsum = p0 + p1;
    #pragma unroll
    for (int mk = 1; mk <= 32; mk <<= 1) lsum += __shfl_xor(lsum, mk);
    if ((tid & 63) == 0) redM[4 + (tid >> 6)] = lsum;
    __syncthreads();
    float rcp = 1.f / (redM[4] + redM[5] + redM[6] + redM[7]);

    float4 acc = make_float4(0.f,0.f,0.f,0.f);
    for (int mm = 0; mm < 32; ++mm) {
      int m = mm*16 + m16;
      float4 hv = hpS4[m*16 + og];
      float p = pS[m];
      acc.x += hv.x*p; acc.y += hv.y*p; acc.z += hv.z*p; acc.w += hv.w*p;
    }
    acc.x += __shfl_xor(acc.x, 16); acc.y += __shfl_xor(acc.y, 16);
    acc.z += __shfl_xor(acc.z, 16); acc.w += __shfl_xor(acc.w, 16);
    acc.x += __shfl_xor(acc.x, 32); acc.y += __shfl_xor(acc.y, 32);
    acc.z += __shfl_xor(acc.z, 32); acc.w += __shfl_xor(acc.w, 32);
    __syncthreads();
    if ((tid & 63) < 16) ((float4*)redS)[(tid >> 6)*16 + (tid & 15)] = acc;
    __syncthreads();
    if (tid < 16) {
      float4 s = make_float4(0.f,0.f,0.f,0.f);
      #pragma unroll
      for (int w = 0; w < 4; ++w) {
        float4 v = ((float4*)redS)[w*16 + tid];
        s.x += v.x; s.y += v.y; s.z += v.z; s.w += v.w;
      }
      float4 bv = *(const float4*)(b2 + tid*4);
      outS[n*64 + tid*4 + 0] = elu_f(s.x*rcp + bv.x);
      outS[n*64 + tid*4 + 1] = elu_f(s.y*rcp + bv.y);
      outS[n*64 + tid*4 + 2] = elu_f(s.z*rcp + bv.z);
      outS[n*64 + tid*4 + 3] = elu_f(s.w*rcp + bv.w);
    }
    __syncthreads();
  }

  if (tid < 64) vS[tid] = outS[tid] * outS[64 + tid];
  __syncthreads();
  if (tid < 192) {
    float a = fc1_b[tid];
    for (int o = 0; o < 64; ++o) a += vS[o]*fc1_w[o*192 + tid];
    y1S[tid] = a > 0.f ? a : 0.f;
  }
  __syncthreads();
  if (tid < 64) {
    float a = fc2_b[tid];
    for (int j = 0; j < 192; ++j) a += y1S[j]*fc2_w[j*64 + tid];
    vS[tid] = a > 0.f ? a : 0.f;
  }
  __syncthreads();
  if (tid == 0) {
    float t0 = fc3_b[0], t1 = fc3_b[1];
    for (int k = 0; k < 64; ++k) {
      float y = vS[k];
      t0 += y*fc3_w[k*2 + 0];
      t1 += y*fc3_w[k*2 + 1];
    }
    float mx = fmaxf(t0, t1);
    float lse = mx + logf(__expf(t0 - mx) + __expf(t1 - mx));
    out[b*2 + 0] = t0 - lse;
    out[b*2 + 1] = t1 - lse;
  }
}

// ---------------------------------------------------------------------------
extern "C" void kernel_launch(void* const* d_in, const int* in_sizes, int n_in,
                              void* d_out, int out_size, void* d_ws, size_t ws_size,
                              hipStream_t stream) {
  const float* emb    = (const float*)d_in[0];
  const int*   adj    = (const int*)d_in[1];
  const float* vt     = (const float*)d_in[2];
  const float* w1     = (const float*)d_in[3];
  const float* a_src1 = (const float*)d_in[4];
  const float* a_dst1 = (const float*)d_in[5];
  const float* b1     = (const float*)d_in[6];
  const float* w2     = (const float*)d_in[7];
  const float* a_src2 = (const float*)d_in[8];
  const float* a_dst2 = (const float*)d_in[9];
  const float* b2     = (const float*)d_in[10];
  const float* fc1_w  = (const float*)d_in[11];
  const float* fc1_b  = (const float*)d_in[12];
  const float* fc2_w  = (const float*)d_in[13];
  const float* fc2_b  = (const float*)d_in[14];
  const float* fc3_w  = (const float*)d_in[15];
  const float* fc3_b  = (const float*)d_in[16];

  char* ws = (char*)d_ws;
  int* counts  = (int*)ws;                       // @0
  int* rowlist = (int*)(ws + 4096);              // 196,608 B
  u64* maskw   = (u64*)(ws + 204800);            // 1 MB
  u16* w1t     = (u16*)(ws + 1310720);           // 2,359,296 B
  u16* w2t     = (u16*)(ws + 3670016);           // 196,608 B
  u16* hp1b    = (u16*)(ws + 3932160);           // 16,777,216 B (x in-place)
  float* hp2   = (float*)(ws + 20709376);        // 4,194,304 B  -> end 24.9 MB

  hipMemsetAsync(counts, 0, 16, stream);
  prep_kernel<<<NROWS/4, 256, 0, stream>>>(adj, maskw);
  rowlist_kernel<<<NROWS/256, 256, 0, stream>>>(vt, rowlist, counts);
  conv_w<<<27, 256, 0, stream>>>(w1, w2, w1t, w2t);

  gemm1_mfma<<<dim3(2, 128, 3), 256, 0, stream>>>(emb, w1t, rowlist, counts, hp1b);

  size_t sm1 = 137728;
  gat1_attn<<<BB*NH, 1024, sm1, stream>>>(hp1b, maskw, a_src1, a_dst1, b1);

  gemm2_mfma<<<dim3(1, 128, 3), 256, 0, stream>>>(hp1b, w2t, rowlist, counts, hp2);

  size_t sm2 = (size_t)(32768 + 512 + 512 + 512 + 256 + 128 + 64 + 192 + 8) * 4;
  gat2_final<<<BB, 256, sm2, stream>>>(hp2, maskw, a_src2, a_dst2, b2,
                                       fc1_w, fc1_b, fc2_w, fc2_b, fc3_w, fc3_b,
                                       (float*)d_out);
}

// Round 6
// 227.206 us; speedup vs baseline: 11.1816x; 1.0848x over previous
//
#include <hip/hip_runtime.h>

#define BB   32
#define NN   512
#define NH   8
#define FIN  768
#define FHID 64
#define NROWS (BB*NN)   // 16384

typedef __attribute__((ext_vector_type(8))) short bf16x8;
typedef __attribute__((ext_vector_type(4))) float f32x4;
typedef unsigned long long u64;
typedef unsigned short u16;

__device__ __forceinline__ float lrelu_f(float s){ return fmaxf(s, 0.2f*s); }
__device__ __forceinline__ float elu_f(float s){ return s > 0.f ? s : expm1f(s); }
__device__ __forceinline__ short f2bf(float f){
  unsigned u = __float_as_uint(f);
  return (short)((u + 0x7fffu + ((u >> 16) & 1u)) >> 16);   // RNE
}
__device__ __forceinline__ float bf2f(short s){
  return __uint_as_float(((unsigned)(u16)s) << 16);
}

// ---------------------------------------------------------------------------
// K1a: adjacency -> bitmask words (no atomics)
// ---------------------------------------------------------------------------
__global__ __launch_bounds__(256) void prep_kernel(
    const int* __restrict__ adj,
    u64* __restrict__ maskw)
{
  int row  = blockIdx.x * 4 + (threadIdx.x >> 6);
  int lane = threadIdx.x & 63;
  const int* arow = adj + (long)row * NN;
  #pragma unroll
  for (int w = 0; w < 8; ++w) {
    u64 bal = __ballot(arow[w*64 + lane] > 0);
    if (lane == 0) maskw[(long)row*8 + w] = bal;
  }
}

// ---------------------------------------------------------------------------
// K1b: per-type gathered row lists; 3 global atomics per block.
// ---------------------------------------------------------------------------
__global__ __launch_bounds__(256) void rowlist_kernel(
    const float* __restrict__ vt,
    int* __restrict__ rowlist, int* __restrict__ counts)
{
  __shared__ int lc[3];
  __shared__ int lbase[3];
  int tid = threadIdx.x;
  int row = blockIdx.x * 256 + tid;
  if (tid < 3) lc[tid] = 0;
  __syncthreads();
  const float* v = vt + (long)row*3;
  int t = v[1] > 0.5f ? 1 : (v[2] > 0.5f ? 2 : 0);
  int p = atomicAdd(&lc[t], 1);
  __syncthreads();
  if (tid < 3) lbase[tid] = atomicAdd(&counts[tid], lc[tid]);
  __syncthreads();
  rowlist[t*NROWS + lbase[t] + p] = row;
}

// ---------------------------------------------------------------------------
// K2: weight transpose+cast: w1[t][h][768][64] -> w1t[(t*8+h)][64][768] bf16
//     w2[t][512][64]        -> w2t[t][64][512] bf16
// ---------------------------------------------------------------------------
__global__ __launch_bounds__(256) void conv_w(
    const float* __restrict__ w1, const float* __restrict__ w2,
    u16* __restrict__ w1t, u16* __restrict__ w2t)
{
  __shared__ float tile[64][68];
  int bid = blockIdx.x, tid = threadIdx.x;
  const float* src; u16* dst; int K;
  if (bid < 24) { src = w1 + (long)bid*768*64; dst = w1t + (long)bid*64*768; K = 768; }
  else { int t = bid - 24; src = w2 + (long)t*512*64; dst = w2t + (long)t*64*512; K = 512; }

  for (int k0 = 0; k0 < K; k0 += 64) {
    __syncthreads();
    #pragma unroll
    for (int i = 0; i < 4; ++i) {
      int kk = i*16 + (tid >> 4);
      int oo = (tid & 15) * 4;
      float4 v = *(const float4*)(src + (long)(k0 + kk)*64 + oo);
      *(float4*)&tile[kk][oo] = v;
    }
    __syncthreads();
    int o = tid >> 2, kp = (tid & 3) * 16;
    bf16x8 r0, r1;
    #pragma unroll
    for (int j = 0; j < 8; ++j) r0[j] = f2bf(tile[kp + j][o]);
    #pragma unroll
    for (int j = 0; j < 8; ++j) r1[j] = f2bf(tile[kp + 8 + j][o]);
    u16* d = dst + (long)o*K + k0 + kp;
    *(bf16x8*)d = r0;
    *(bf16x8*)(d + 8) = r1;
  }
}

// ---------------------------------------------------------------------------
// K3: layer-1 gathered GEMM via bf16 MFMA.
// BM=64, BN=128 (head pair hb), 4 waves, wave tile 32x64, prefetch k+32.
// ~1032 active blocks -> ~4 blocks/CU (was 258 -> 1/CU, latency-starved).
// ---------------------------------------------------------------------------
__global__ __launch_bounds__(256) void gemm1_mfma(
    const float* __restrict__ emb,
    const u16* __restrict__ w1t,
    const int* __restrict__ rowlist, const int* __restrict__ counts,
    u16* __restrict__ hp1b)
{
  int t   = blockIdx.z;
  int cnt = counts[t];
  int r0  = blockIdx.y * 64;
  if (r0 >= cnt) return;
  int hb  = blockIdx.x;                 // 0..3 (head pair)

  __shared__ short aT[4*64*8];          // [kg][row][8]  4 KB
  __shared__ short bT[4*128*8];         // [kg][col][8]  8 KB
  __shared__ int rowsS[64];

  int tid = threadIdx.x;
  if (tid < 64) {
    int rr = r0 + tid;
    rowsS[tid] = (rr < cnt) ? rowlist[t*NROWS + rr] : -1;
  }
  __syncthreads();

  int arow = tid & 63, akg = tid >> 6;          // akg 0..3
  int sg = rowsS[arow]; if (sg < 0) sg = rowsS[0];
  const float* aP = emb + (long)sg*768 + akg*8;

  int bcol = tid & 127, bkh = tid >> 7;         // bkh 0..1
  const u16* bP = w1t + (((long)t*8 + hb*2)*64 + bcol)*768 + bkh*16;

  int wv = tid >> 6, l = tid & 63;
  int wr = wv >> 1, wc = wv & 1;
  int l15 = l & 15, lg = l >> 4;

  f32x4 acc[2][4];
  #pragma unroll
  for (int fr = 0; fr < 2; ++fr)
    #pragma unroll
    for (int cf = 0; cf < 4; ++cf) acc[fr][cf] = (f32x4){0.f,0.f,0.f,0.f};

  float4 ra0 = *(const float4*)(aP);
  float4 ra1 = *(const float4*)(aP + 4);
  bf16x8 rb0 = *(const bf16x8*)(bP);
  bf16x8 rb1 = *(const bf16x8*)(bP + 8);

  for (int k0 = 0; k0 < 768; k0 += 32) {
    __syncthreads();
    bf16x8 pa;
    pa[0]=f2bf(ra0.x); pa[1]=f2bf(ra0.y); pa[2]=f2bf(ra0.z); pa[3]=f2bf(ra0.w);
    pa[4]=f2bf(ra1.x); pa[5]=f2bf(ra1.y); pa[6]=f2bf(ra1.z); pa[7]=f2bf(ra1.w);
    *(bf16x8*)&aT[(akg*64 + arow)*8] = pa;
    *(bf16x8*)&bT[((bkh*2+0)*128 + bcol)*8] = rb0;
    *(bf16x8*)&bT[((bkh*2+1)*128 + bcol)*8] = rb1;
    __syncthreads();
    if (k0 + 32 < 768) {                       // prefetch next k-tile
      ra0 = *(const float4*)(aP + k0 + 32);
      ra1 = *(const float4*)(aP + k0 + 36);
      rb0 = *(const bf16x8*)(bP + k0 + 32);
      rb1 = *(const bf16x8*)(bP + k0 + 40);
    }
    bf16x8 af[2], bfr[4];
    #pragma unroll
    for (int fr = 0; fr < 2; ++fr)
      af[fr] = *(const bf16x8*)&aT[(lg*64 + wr*32 + fr*16 + l15)*8];
    #pragma unroll
    for (int cf = 0; cf < 4; ++cf)
      bfr[cf] = *(const bf16x8*)&bT[(lg*128 + wc*64 + cf*16 + l15)*8];
    #pragma unroll
    for (int fr = 0; fr < 2; ++fr)
      #pragma unroll
      for (int cf = 0; cf < 4; ++cf)
        acc[fr][cf] = __builtin_amdgcn_mfma_f32_16x16x32_bf16(af[fr], bfr[cf], acc[fr][cf], 0, 0, 0);
  }

  #pragma unroll
  for (int fr = 0; fr < 2; ++fr) {
    #pragma unroll
    for (int r = 0; r < 4; ++r) {
      int rloc = wr*32 + fr*16 + lg*4 + r;
      int rg = rowsS[rloc];
      if (rg < 0) continue;
      long obase = ((long)(rg >> 9) * 8) * 32768 + (long)(rg & 511) * 64;
      #pragma unroll
      for (int cf = 0; cf < 4; ++cf) {
        int c = wc*64 + cf*16 + l15;   // 0..127
        hp1b[obase + (long)(hb*2 + (c >> 6))*32768 + (c & 63)] = (u16)f2bf(acc[fr][cf][r]);
      }
    }
  }
}

// ---------------------------------------------------------------------------
// K5: layer-2 gathered GEMM via bf16 MFMA. BM=64, BN=64, wave tile 16x64,
// prefetch k+32. ~258 active blocks (was ~129).
// ---------------------------------------------------------------------------
__global__ __launch_bounds__(256) void gemm2_mfma(
    const u16* __restrict__ xbf,
    const u16* __restrict__ w2t,
    const int* __restrict__ rowlist, const int* __restrict__ counts,
    float* __restrict__ hp2)
{
  int t   = blockIdx.z;
  int cnt = counts[t];
  int r0  = blockIdx.y * 64;
  if (r0 >= cnt) return;

  __shared__ short aT[4*64*8];   // 4 KB
  __shared__ short bT[4*64*8];   // 4 KB
  __shared__ int rowsS[64];

  int tid = threadIdx.x;
  if (tid < 64) {
    int rr = r0 + tid;
    rowsS[tid] = (rr < cnt) ? rowlist[t*NROWS + rr] : -1;
  }
  __syncthreads();

  int arow = tid & 63, akg = tid >> 6;
  int sg = rowsS[arow]; if (sg < 0) sg = rowsS[0];
  long apart = ((long)(sg >> 9) * 8) * 32768 + (long)(sg & 511) * 64;

  int bcol = tid & 63, bkg = tid >> 6;
  const u16* bP = w2t + ((long)t*64 + bcol)*512 + bkg*8;

  int wv = tid >> 6, l = tid & 63;
  int l15 = l & 15, lg = l >> 4;

  f32x4 acc[4];
  #pragma unroll
  for (int cf = 0; cf < 4; ++cf) acc[cf] = (f32x4){0.f,0.f,0.f,0.f};

  int ka = akg*8;
  bf16x8 ra = *(const bf16x8*)(xbf + apart + (long)(ka >> 6)*32768 + (ka & 63));
  bf16x8 rb = *(const bf16x8*)(bP);

  for (int k0 = 0; k0 < 512; k0 += 32) {
    __syncthreads();
    *(bf16x8*)&aT[(akg*64 + arow)*8] = ra;
    *(bf16x8*)&bT[(bkg*64 + bcol)*8] = rb;
    __syncthreads();
    if (k0 + 32 < 512) {
      int kn = k0 + 32 + akg*8;
      ra = *(const bf16x8*)(xbf + apart + (long)(kn >> 6)*32768 + (kn & 63));
      rb = *(const bf16x8*)(bP + k0 + 32);
    }
    bf16x8 af, bfr[4];
    af = *(const bf16x8*)&aT[(lg*64 + wv*16 + l15)*8];
    #pragma unroll
    for (int cf = 0; cf < 4; ++cf)
      bfr[cf] = *(const bf16x8*)&bT[(lg*64 + cf*16 + l15)*8];
    #pragma unroll
    for (int cf = 0; cf < 4; ++cf)
      acc[cf] = __builtin_amdgcn_mfma_f32_16x16x32_bf16(af, bfr[cf], acc[cf], 0, 0, 0);
  }

  #pragma unroll
  for (int r = 0; r < 4; ++r) {
    int rloc = wv*16 + lg*4 + r;
    int rg = rowsS[rloc];
    if (rg < 0) continue;
    #pragma unroll
    for (int cf = 0; cf < 4; ++cf)
      hp2[(long)rg*64 + cf*16 + l15] = acc[cf][r];
  }
}

// ---------------------------------------------------------------------------
// K4: GAT layer-1 attention. One 1024-thread block per (b,h). (unchanged)
// ---------------------------------------------------------------------------
__global__ __launch_bounds__(1024) void gat1_attn(
    u16* __restrict__ hp1b, const u64* __restrict__ maskw,
    const float* __restrict__ a_src, const float* __restrict__ a_dst,
    const float* __restrict__ b1)
{
  extern __shared__ char smc[];
  short* hpT  = (short*)smc;                 // [64][520] bf16 (66,560 B)
  short* pS   = (short*)(smc + 66560);       // [64][520] bf16 (66,560 B)
  float* srcS = (float*)(smc + 133120);      // [512]
  float* dstS = (float*)(smc + 135168);      // [512]
  float* asS  = (float*)(smc + 137216);      // [64]
  float* adS  = (float*)(smc + 137472);      // [64]

  int bh = blockIdx.x;
  int b = bh >> 3, h = bh & 7;
  int tid = threadIdx.x;

  if (tid < 64) asS[tid] = a_src[h*64 + tid];
  else if (tid < 128) adS[tid - 64] = a_dst[h*64 + (tid - 64)];
  __syncthreads();

  {
    int m = tid >> 1, half = tid & 1;
    const u16* hpRow = hp1b + ((long)bh*NN + m)*64 + half*32;
    float ps = 0.f, pd = 0.f;
    #pragma unroll
    for (int q = 0; q < 4; ++q) {
      bf16x8 hv = *(const bf16x8*)(hpRow + q*8);
      int o = half*32 + q*8;
      #pragma unroll
      for (int j = 0; j < 8; ++j) {
        float f = bf2f(hv[j]);
        ps += f * asS[o + j];
        pd += f * adS[o + j];
        hpT[(o + j)*520 + m] = hv[j];
      }
    }
    ps += __shfl_xor(ps, 1);
    pd += __shfl_xor(pd, 1);
    if ((tid & 1) == 0) { srcS[m] = ps; dstS[m] = pd; }
  }
  __syncthreads();

  int wv = tid >> 6, lane = tid & 63;
  int l15 = lane & 15, lg = lane >> 4;
  int cgl = wv >> 2, nt = wv & 3;
  const char* aBase = (const char*)pS  + (cgl*16 + l15)*1040 + lg*16;
  const char* bBase = (const char*)hpT + (nt*16  + l15)*1040 + lg*16;
  int   o_out = nt*16 + l15;
  float bb    = b1[o_out];

  for (int sup = 0; sup < 8; ++sup) {
    #pragma unroll
    for (int rr = 0; rr < 4; ++rr) {
      int rloc = wv*4 + rr;
      int row  = sup*64 + rloc;
      float srcv = srcS[row];
      const u64* mrow = maskw + ((long)(b*NN + row))*8;
      float ev[8];
      float emax = -3.0e38f;
      #pragma unroll
      for (int j = 0; j < 8; ++j) {
        u64 w = mrow[j];
        float s = srcv + dstS[j*64 + lane];
        float e = ((w >> lane) & 1ull) ? lrelu_f(s) : -1.0e9f;
        ev[j] = e;
        emax = fmaxf(emax, e);
      }
      #pragma unroll
      for (int mk = 1; mk <= 32; mk <<= 1) emax = fmaxf(emax, __shfl_xor(emax, mk));
      float lsum = 0.f;
      #pragma unroll
      for (int j = 0; j < 8; ++j) { float p = __expf(ev[j] - emax); ev[j] = p; lsum += p; }
      #pragma unroll
      for (int mk = 1; mk <= 32; mk <<= 1) lsum += __shfl_xor(lsum, mk);
      float rcp = 1.f / lsum;
      #pragma unroll
      for (int j = 0; j < 8; ++j)
        pS[rloc*520 + j*64 + lane] = f2bf(ev[j] * rcp);
    }
    __syncthreads();

    f32x4 acc = {0.f, 0.f, 0.f, 0.f};
    #pragma unroll
    for (int ks = 0; ks < 16; ++ks) {
      bf16x8 af = *(const bf16x8*)(aBase + ks*64);
      bf16x8 bf = *(const bf16x8*)(bBase + ks*64);
      acc = __builtin_amdgcn_mfma_f32_16x16x32_bf16(af, bf, acc, 0, 0, 0);
    }
    #pragma unroll
    for (int reg = 0; reg < 4; ++reg) {
      int row = sup*64 + cgl*16 + lg*4 + reg;
      float v = elu_f(acc[reg] + bb);
      hp1b[((long)bh*NN + row)*64 + o_out] = (u16)f2bf(v);
    }
    __syncthreads();
  }
}

// ---------------------------------------------------------------------------
// K6: GAT layer-2 attention (rows 0,1 only) + ELU + MLP + log_softmax.
// ---------------------------------------------------------------------------
__global__ __launch_bounds__(256) void gat2_final(
    const float* __restrict__ hp2, const u64* __restrict__ maskw,
    const float* __restrict__ a_src2, const float* __restrict__ a_dst2,
    const float* __restrict__ b2,
    const float* __restrict__ fc1_w, const float* __restrict__ fc1_b,
    const float* __restrict__ fc2_w, const float* __restrict__ fc2_b,
    const float* __restrict__ fc3_w, const float* __restrict__ fc3_b,
    float* __restrict__ out)
{
  extern __shared__ float sm[];
  float* hpS  = sm;              // 32768
  float* dstS = hpS + 32768;     // 512
  float* srcS = dstS + 512;      // 512
  float* pS   = srcS + 512;      // 512
  float* redS = pS + 512;        // 256
  float* outS = redS + 256;      // 128
  float* vS   = outS + 128;      // 64
  float* y1S  = vS + 64;         // 192
  float* redM = y1S + 192;       // 8
  float4* hpS4 = (float4*)hpS;

  int b = blockIdx.x;
  int tid = threadIdx.x;
  int og = tid & 15, m16 = tid >> 4;

  for (int it = 0; it < 32; ++it) {
    int fi = it*256 + tid;
    int m = fi >> 4, o4 = fi & 15;
    hpS4[m*16 + o4] = *(const float4*)(hp2 + (long)(b*NN + m)*64 + o4*4);
  }
  __syncthreads();

  float4 as4 = *(const float4*)(a_src2 + og*4);
  float4 ad4 = *(const float4*)(a_dst2 + og*4);
  for (int it = 0; it < 32; ++it) {
    int m = it*16 + m16;
    float4 hv = hpS4[m*16 + og];
    float ls = hv.x*as4.x + hv.y*as4.y + hv.z*as4.z + hv.w*as4.w;
    float ld = hv.x*ad4.x + hv.y*ad4.y + hv.z*ad4.z + hv.w*ad4.w;
    #pragma unroll
    for (int mk = 1; mk <= 8; mk <<= 1) {
      ls += __shfl_xor(ls, mk);
      ld += __shfl_xor(ld, mk);
    }
    if (og == 0) { srcS[m] = ls; dstS[m] = ld; }
  }
  __syncthreads();

  for (int n = 0; n < 2; ++n) {
    float srcv = srcS[n];
    const u64* mrow = maskw + (long)(b*NN + n)*8;
    int m0 = tid, m1 = tid + 256;
    u64 w0 = mrow[m0 >> 6], w1 = mrow[m1 >> 6];
    float s0 = srcv + dstS[m0], s1 = srcv + dstS[m1];
    float e0 = ((w0 >> (m0 & 63)) & 1ull) ? lrelu_f(s0) : -1.0e9f;
    float e1 = ((w1 >> (m1 & 63)) & 1ull) ? lrelu_f(s1) : -1.0e9f;
    float emax = fmaxf(e0, e1);
    #pragma unroll
    for (int mk = 1; mk <= 32; mk <<= 1) emax = fmaxf(emax, __shfl_xor(emax, mk));
    if ((tid & 63) == 0) redM[tid >> 6] = emax;
    __syncthreads();
    emax = fmaxf(fmaxf(redM[0], redM[1]), fmaxf(redM[2], redM[3]));
    float p0 = __expf(e0 - emax), p1 = __expf(e1 - emax);
    pS[m0] = p0; pS[m1] = p1;
    float lsum = p0 + p1;
    #pragma unroll
    for (int mk = 1; mk <= 32; mk <<= 1) lsum += __shfl_xor(lsum, mk);
    if ((tid & 63) == 0) redM[4 + (tid >> 6)] = lsum;
    __syncthreads();
    float rcp = 1.f / (redM[4] + redM[5] + redM[6] + redM[7]);

    float4 acc = make_float4(0.f,0.f,0.f,0.f);
    for (int mm = 0; mm < 32; ++mm) {
      int m = mm*16 + m16;
      float4 hv = hpS4[m*16 + og];
      float p = pS[m];
      acc.x += hv.x*p; acc.y += hv.y*p; acc.z += hv.z*p; acc.w += hv.w*p;
    }
    acc.x += __shfl_xor(acc.x, 16); acc.y += __shfl_xor(acc.y, 16);
    acc.z += __shfl_xor(acc.z, 16); acc.w += __shfl_xor(acc.w, 16);
    acc.x += __shfl_xor(acc.x, 32); acc.y += __shfl_xor(acc.y, 32);
    acc.z += __shfl_xor(acc.z, 32); acc.w += __shfl_xor(acc.w, 32);
    __syncthreads();
    if ((tid & 63) < 16) ((float4*)redS)[(tid >> 6)*16 + (tid & 15)] = acc;
    __syncthreads();
    if (tid < 16) {
      float4 s = make_float4(0.f,0.f,0.f,0.f);
      #pragma unroll
      for (int w = 0; w < 4; ++w) {
        float4 v = ((float4*)redS)[w*16 + tid];
        s.x += v.x; s.y += v.y; s.z += v.z; s.w += v.w;
      }
      float4 bv = *(const float4*)(b2 + tid*4);
      outS[n*64 + tid*4 + 0] = elu_f(s.x*rcp + bv.x);
      outS[n*64 + tid*4 + 1] = elu_f(s.y*rcp + bv.y);
      outS[n*64 + tid*4 + 2] = elu_f(s.z*rcp + bv.z);
      outS[n*64 + tid*4 + 3] = elu_f(s.w*rcp + bv.w);
    }
    __syncthreads();
  }

  if (tid < 64) vS[tid] = outS[tid] * outS[64 + tid];
  __syncthreads();
  if (tid < 192) {
    float a = fc1_b[tid];
    for (int o = 0; o < 64; ++o) a += vS[o]*fc1_w[o*192 + tid];
    y1S[tid] = a > 0.f ? a : 0.f;
  }
  __syncthreads();
  if (tid < 64) {
    float a = fc2_b[tid];
    for (int j = 0; j < 192; ++j) a += y1S[j]*fc2_w[j*64 + tid];
    vS[tid] = a > 0.f ? a : 0.f;
  }
  __syncthreads();
  if (tid == 0) {
    float t0 = fc3_b[0], t1 = fc3_b[1];
    for (int k = 0; k < 64; ++k) {
      float y = vS[k];
      t0 += y*fc3_w[k*2 + 0];
      t1 += y*fc3_w[k*2 + 1];
    }
    float mx = fmaxf(t0, t1);
    float lse = mx + logf(__expf(t0 - mx) + __expf(t1 - mx));
    out[b*2 + 0] = t0 - lse;
    out[b*2 + 1] = t1 - lse;
  }
}

// ---------------------------------------------------------------------------
extern "C" void kernel_launch(void* const* d_in, const int* in_sizes, int n_in,
                              void* d_out, int out_size, void* d_ws, size_t ws_size,
                              hipStream_t stream) {
  const float* emb    = (const float*)d_in[0];
  const int*   adj    = (const int*)d_in[1];
  const float* vt     = (const float*)d_in[2];
  const float* w1     = (const float*)d_in[3];
  const float* a_src1 = (const float*)d_in[4];
  const float* a_dst1 = (const float*)d_in[5];
  const float* b1     = (const float*)d_in[6];
  const float* w2     = (const float*)d_in[7];
  const float* a_src2 = (const float*)d_in[8];
  const float* a_dst2 = (const float*)d_in[9];
  const float* b2     = (const float*)d_in[10];
  const float* fc1_w  = (const float*)d_in[11];
  const float* fc1_b  = (const float*)d_in[12];
  const float* fc2_w  = (const float*)d_in[13];
  const float* fc2_b  = (const float*)d_in[14];
  const float* fc3_w  = (const float*)d_in[15];
  const float* fc3_b  = (const float*)d_in[16];

  char* ws = (char*)d_ws;
  int* counts  = (int*)ws;                       // @0
  int* rowlist = (int*)(ws + 4096);              // 196,608 B
  u64* maskw   = (u64*)(ws + 204800);            // 1 MB
  u16* w1t     = (u16*)(ws + 1310720);           // 2,359,296 B
  u16* w2t     = (u16*)(ws + 3670016);           // 196,608 B
  u16* hp1b    = (u16*)(ws + 3932160);           // 16,777,216 B (x in-place)
  float* hp2   = (float*)(ws + 20709376);        // 4,194,304 B  -> end 24.9 MB

  hipMemsetAsync(counts, 0, 16, stream);
  prep_kernel<<<NROWS/4, 256, 0, stream>>>(adj, maskw);
  rowlist_kernel<<<NROWS/256, 256, 0, stream>>>(vt, rowlist, counts);
  conv_w<<<27, 256, 0, stream>>>(w1, w2, w1t, w2t);

  gemm1_mfma<<<dim3(4, 256, 3), 256, 0, stream>>>(emb, w1t, rowlist, counts, hp1b);

  size_t sm1 = 137728;
  gat1_attn<<<BB*NH, 1024, sm1, stream>>>(hp1b, maskw, a_src1, a_dst1, b1);

  gemm2_mfma<<<dim3(1, 256, 3), 256, 0, stream>>>(hp1b, w2t, rowlist, counts, hp2);

  size_t sm2 = (size_t)(32768 + 512 + 512 + 512 + 256 + 128 + 64 + 192 + 8) * 4;
  gat2_final<<<BB, 256, sm2, stream>>>(hp2, maskw, a_src2, a_dst2, b2,
                                       fc1_w, fc1_b, fc2_w, fc2_b, fc3_w, fc3_b,
                                       (float*)d_out);
}

// Round 7
// 206.879 us; speedup vs baseline: 12.2802x; 1.0983x over previous
//
#include <hip/hip_runtime.h>

#define BB   32
#define NN   512
#define NH   8
#define FIN  768
#define FHID 64
#define NROWS (BB*NN)   // 16384

typedef __attribute__((ext_vector_type(8))) short bf16x8;
typedef __attribute__((ext_vector_type(4))) float f32x4;
typedef unsigned long long u64;
typedef unsigned short u16;

__device__ __forceinline__ float lrelu_f(float s){ return fmaxf(s, 0.2f*s); }
__device__ __forceinline__ float elu_f(float s){ return s > 0.f ? s : expm1f(s); }
__device__ __forceinline__ short f2bf(float f){
  unsigned u = __float_as_uint(f);
  return (short)((u + 0x7fffu + ((u >> 16) & 1u)) >> 16);   // RNE
}
__device__ __forceinline__ float bf2f(short s){
  return __uint_as_float(((unsigned)(u16)s) << 16);
}

// ---------------------------------------------------------------------------
// K1a: adjacency -> bitmask words (no atomics)
// ---------------------------------------------------------------------------
__global__ __launch_bounds__(256) void prep_kernel(
    const int* __restrict__ adj,
    u64* __restrict__ maskw)
{
  int row  = blockIdx.x * 4 + (threadIdx.x >> 6);
  int lane = threadIdx.x & 63;
  const int* arow = adj + (long)row * NN;
  #pragma unroll
  for (int w = 0; w < 8; ++w) {
    u64 bal = __ballot(arow[w*64 + lane] > 0);
    if (lane == 0) maskw[(long)row*8 + w] = bal;
  }
}

// ---------------------------------------------------------------------------
// K1b: per-type gathered row lists; 3 global atomics per block.
// ---------------------------------------------------------------------------
__global__ __launch_bounds__(256) void rowlist_kernel(
    const float* __restrict__ vt,
    int* __restrict__ rowlist, int* __restrict__ counts)
{
  __shared__ int lc[3];
  __shared__ int lbase[3];
  int tid = threadIdx.x;
  int row = blockIdx.x * 256 + tid;
  if (tid < 3) lc[tid] = 0;
  __syncthreads();
  const float* v = vt + (long)row*3;
  int t = v[1] > 0.5f ? 1 : (v[2] > 0.5f ? 2 : 0);
  int p = atomicAdd(&lc[t], 1);
  __syncthreads();
  if (tid < 3) lbase[tid] = atomicAdd(&counts[tid], lc[tid]);
  __syncthreads();
  rowlist[t*NROWS + lbase[t] + p] = row;
}

// ---------------------------------------------------------------------------
// K2: weight transpose+cast: w1[t][h][768][64] -> w1t[(t*8+h)][64][768] bf16
//     w2[t][512][64]        -> w2t[t][64][512] bf16
// blockIdx.y = K-quarter (27 blocks was a latency straggler; now 108).
// ---------------------------------------------------------------------------
__global__ __launch_bounds__(256) void conv_w(
    const float* __restrict__ w1, const float* __restrict__ w2,
    u16* __restrict__ w1t, u16* __restrict__ w2t)
{
  __shared__ float tile[64][68];
  int bid = blockIdx.x, tid = threadIdx.x;
  const float* src; u16* dst; int K;
  if (bid < 24) { src = w1 + (long)bid*768*64; dst = w1t + (long)bid*64*768; K = 768; }
  else { int t = bid - 24; src = w2 + (long)t*512*64; dst = w2t + (long)t*64*512; K = 512; }
  int kq = blockIdx.y;              // 0..3
  int kstart = kq * (K >> 2), kend = kstart + (K >> 2);

  for (int k0 = kstart; k0 < kend; k0 += 64) {
    __syncthreads();
    #pragma unroll
    for (int i = 0; i < 4; ++i) {
      int kk = i*16 + (tid >> 4);
      int oo = (tid & 15) * 4;
      float4 v = *(const float4*)(src + (long)(k0 + kk)*64 + oo);
      *(float4*)&tile[kk][oo] = v;
    }
    __syncthreads();
    int o = tid >> 2, kp = (tid & 3) * 16;
    bf16x8 r0, r1;
    #pragma unroll
    for (int j = 0; j < 8; ++j) r0[j] = f2bf(tile[kp + j][o]);
    #pragma unroll
    for (int j = 0; j < 8; ++j) r1[j] = f2bf(tile[kp + 8 + j][o]);
    u16* d = dst + (long)o*K + k0 + kp;
    *(bf16x8*)d = r0;
    *(bf16x8*)(d + 8) = r1;
  }
}

// ---------------------------------------------------------------------------
// K3: layer-1 gathered GEMM via bf16 MFMA.
// BM=64, BN=128, 4 waves, wave tile 32x64, reg-prefetch k+32.
// XCD-locality decode: blockIdx.x%8 selects XCD (round-robin assumption);
// the 4 hb-blocks of one row-block are spaced 8 apart -> same XCD -> the
// A-tile is fetched once from HBM/L3 and L2-hit by the other 3 (the round-6
// profile showed ~4.4 TB/s of L3-level re-read traffic as the binding cap).
// ---------------------------------------------------------------------------
__global__ __launch_bounds__(256) void gemm1_mfma(
    const float* __restrict__ emb,
    const u16* __restrict__ w1t,
    const int* __restrict__ rowlist, const int* __restrict__ counts,
    u16* __restrict__ hp1b)
{
  int t   = blockIdx.z;
  int cnt = counts[t];
  int i   = blockIdx.x;           // 0..351
  int xcd = i & 7;
  int q   = i >> 3;               // 0..43
  int hb  = q & 3;                // head pair group
  int rb  = (q >> 2) * 8 + xcd;   // 0..87
  int r0  = rb * 64;
  if (r0 >= cnt) return;

  __shared__ short aT[4*64*8];          // [kg][row][8]  4 KB
  __shared__ short bT[4*128*8];         // [kg][col][8]  8 KB
  __shared__ int rowsS[64];

  int tid = threadIdx.x;
  if (tid < 64) {
    int rr = r0 + tid;
    rowsS[tid] = (rr < cnt) ? rowlist[t*NROWS + rr] : -1;
  }
  __syncthreads();

  int arow = tid & 63, akg = tid >> 6;          // akg 0..3
  int sg = rowsS[arow]; if (sg < 0) sg = rowsS[0];
  const float* aP = emb + (long)sg*768 + akg*8;

  int bcol = tid & 127, bkh = tid >> 7;         // bkh 0..1
  const u16* bP = w1t + (((long)t*8 + hb*2)*64 + bcol)*768 + bkh*16;

  int wv = tid >> 6, l = tid & 63;
  int wr = wv >> 1, wc = wv & 1;
  int l15 = l & 15, lg = l >> 4;

  f32x4 acc[2][4];
  #pragma unroll
  for (int fr = 0; fr < 2; ++fr)
    #pragma unroll
    for (int cf = 0; cf < 4; ++cf) acc[fr][cf] = (f32x4){0.f,0.f,0.f,0.f};

  float4 ra0 = *(const float4*)(aP);
  float4 ra1 = *(const float4*)(aP + 4);
  bf16x8 rb0 = *(const bf16x8*)(bP);
  bf16x8 rb1 = *(const bf16x8*)(bP + 8);

  for (int k0 = 0; k0 < 768; k0 += 32) {
    __syncthreads();
    bf16x8 pa;
    pa[0]=f2bf(ra0.x); pa[1]=f2bf(ra0.y); pa[2]=f2bf(ra0.z); pa[3]=f2bf(ra0.w);
    pa[4]=f2bf(ra1.x); pa[5]=f2bf(ra1.y); pa[6]=f2bf(ra1.z); pa[7]=f2bf(ra1.w);
    *(bf16x8*)&aT[(akg*64 + arow)*8] = pa;
    *(bf16x8*)&bT[((bkh*2+0)*128 + bcol)*8] = rb0;
    *(bf16x8*)&bT[((bkh*2+1)*128 + bcol)*8] = rb1;
    __syncthreads();
    if (k0 + 32 < 768) {                       // prefetch next k-tile
      ra0 = *(const float4*)(aP + k0 + 32);
      ra1 = *(const float4*)(aP + k0 + 36);
      rb0 = *(const bf16x8*)(bP + k0 + 32);
      rb1 = *(const bf16x8*)(bP + k0 + 40);
    }
    bf16x8 af[2], bfr[4];
    #pragma unroll
    for (int fr = 0; fr < 2; ++fr)
      af[fr] = *(const bf16x8*)&aT[(lg*64 + wr*32 + fr*16 + l15)*8];
    #pragma unroll
    for (int cf = 0; cf < 4; ++cf)
      bfr[cf] = *(const bf16x8*)&bT[(lg*128 + wc*64 + cf*16 + l15)*8];
    #pragma unroll
    for (int fr = 0; fr < 2; ++fr)
      #pragma unroll
      for (int cf = 0; cf < 4; ++cf)
        acc[fr][cf] = __builtin_amdgcn_mfma_f32_16x16x32_bf16(af[fr], bfr[cf], acc[fr][cf], 0, 0, 0);
  }

  #pragma unroll
  for (int fr = 0; fr < 2; ++fr) {
    #pragma unroll
    for (int r = 0; r < 4; ++r) {
      int rloc = wr*32 + fr*16 + lg*4 + r;
      int rg = rowsS[rloc];
      if (rg < 0) continue;
      long obase = ((long)(rg >> 9) * 8) * 32768 + (long)(rg & 511) * 64;
      #pragma unroll
      for (int cf = 0; cf < 4; ++cf) {
        int c = wc*64 + cf*16 + l15;   // 0..127
        hp1b[obase + (long)(hb*2 + (c >> 6))*32768 + (c & 63)] = (u16)f2bf(acc[fr][cf][r]);
      }
    }
  }
}

// ---------------------------------------------------------------------------
// K5: layer-2 gathered GEMM via bf16 MFMA. BM=64, BN=64, wave tile 16x64,
// prefetch k+32.
// ---------------------------------------------------------------------------
__global__ __launch_bounds__(256) void gemm2_mfma(
    const u16* __restrict__ xbf,
    const u16* __restrict__ w2t,
    const int* __restrict__ rowlist, const int* __restrict__ counts,
    float* __restrict__ hp2)
{
  int t   = blockIdx.z;
  int cnt = counts[t];
  int r0  = blockIdx.y * 64;
  if (r0 >= cnt) return;

  __shared__ short aT[4*64*8];   // 4 KB
  __shared__ short bT[4*64*8];   // 4 KB
  __shared__ int rowsS[64];

  int tid = threadIdx.x;
  if (tid < 64) {
    int rr = r0 + tid;
    rowsS[tid] = (rr < cnt) ? rowlist[t*NROWS + rr] : -1;
  }
  __syncthreads();

  int arow = tid & 63, akg = tid >> 6;
  int sg = rowsS[arow]; if (sg < 0) sg = rowsS[0];
  long apart = ((long)(sg >> 9) * 8) * 32768 + (long)(sg & 511) * 64;

  int bcol = tid & 63, bkg = tid >> 6;
  const u16* bP = w2t + ((long)t*64 + bcol)*512 + bkg*8;

  int wv = tid >> 6, l = tid & 63;
  int l15 = l & 15, lg = l >> 4;

  f32x4 acc[4];
  #pragma unroll
  for (int cf = 0; cf < 4; ++cf) acc[cf] = (f32x4){0.f,0.f,0.f,0.f};

  int ka = akg*8;
  bf16x8 ra = *(const bf16x8*)(xbf + apart + (long)(ka >> 6)*32768 + (ka & 63));
  bf16x8 rb = *(const bf16x8*)(bP);

  for (int k0 = 0; k0 < 512; k0 += 32) {
    __syncthreads();
    *(bf16x8*)&aT[(akg*64 + arow)*8] = ra;
    *(bf16x8*)&bT[(bkg*64 + bcol)*8] = rb;
    __syncthreads();
    if (k0 + 32 < 512) {
      int kn = k0 + 32 + akg*8;
      ra = *(const bf16x8*)(xbf + apart + (long)(kn >> 6)*32768 + (kn & 63));
      rb = *(const bf16x8*)(bP + k0 + 32);
    }
    bf16x8 af, bfr[4];
    af = *(const bf16x8*)&aT[(lg*64 + wv*16 + l15)*8];
    #pragma unroll
    for (int cf = 0; cf < 4; ++cf)
      bfr[cf] = *(const bf16x8*)&bT[(lg*64 + cf*16 + l15)*8];
    #pragma unroll
    for (int cf = 0; cf < 4; ++cf)
      acc[cf] = __builtin_amdgcn_mfma_f32_16x16x32_bf16(af, bfr[cf], acc[cf], 0, 0, 0);
  }

  #pragma unroll
  for (int r = 0; r < 4; ++r) {
    int rloc = wv*16 + lg*4 + r;
    int rg = rowsS[rloc];
    if (rg < 0) continue;
    #pragma unroll
    for (int cf = 0; cf < 4; ++cf)
      hp2[(long)rg*64 + cf*16 + l15] = acc[cf][r];
  }
}

// ---------------------------------------------------------------------------
// K4: GAT layer-1 attention. One 1024-thread block per (b,h). (unchanged)
// ---------------------------------------------------------------------------
__global__ __launch_bounds__(1024) void gat1_attn(
    u16* __restrict__ hp1b, const u64* __restrict__ maskw,
    const float* __restrict__ a_src, const float* __restrict__ a_dst,
    const float* __restrict__ b1)
{
  extern __shared__ char smc[];
  short* hpT  = (short*)smc;                 // [64][520] bf16 (66,560 B)
  short* pS   = (short*)(smc + 66560);       // [64][520] bf16 (66,560 B)
  float* srcS = (float*)(smc + 133120);      // [512]
  float* dstS = (float*)(smc + 135168);      // [512]
  float* asS  = (float*)(smc + 137216);      // [64]
  float* adS  = (float*)(smc + 137472);      // [64]

  int bh = blockIdx.x;
  int b = bh >> 3, h = bh & 7;
  int tid = threadIdx.x;

  if (tid < 64) asS[tid] = a_src[h*64 + tid];
  else if (tid < 128) adS[tid - 64] = a_dst[h*64 + (tid - 64)];
  __syncthreads();

  {
    int m = tid >> 1, half = tid & 1;
    const u16* hpRow = hp1b + ((long)bh*NN + m)*64 + half*32;
    float ps = 0.f, pd = 0.f;
    #pragma unroll
    for (int q = 0; q < 4; ++q) {
      bf16x8 hv = *(const bf16x8*)(hpRow + q*8);
      int o = half*32 + q*8;
      #pragma unroll
      for (int j = 0; j < 8; ++j) {
        float f = bf2f(hv[j]);
        ps += f * asS[o + j];
        pd += f * adS[o + j];
        hpT[(o + j)*520 + m] = hv[j];
      }
    }
    ps += __shfl_xor(ps, 1);
    pd += __shfl_xor(pd, 1);
    if ((tid & 1) == 0) { srcS[m] = ps; dstS[m] = pd; }
  }
  __syncthreads();

  int wv = tid >> 6, lane = tid & 63;
  int l15 = lane & 15, lg = lane >> 4;
  int cgl = wv >> 2, nt = wv & 3;
  const char* aBase = (const char*)pS  + (cgl*16 + l15)*1040 + lg*16;
  const char* bBase = (const char*)hpT + (nt*16  + l15)*1040 + lg*16;
  int   o_out = nt*16 + l15;
  float bb    = b1[o_out];

  for (int sup = 0; sup < 8; ++sup) {
    #pragma unroll
    for (int rr = 0; rr < 4; ++rr) {
      int rloc = wv*4 + rr;
      int row  = sup*64 + rloc;
      float srcv = srcS[row];
      const u64* mrow = maskw + ((long)(b*NN + row))*8;
      float ev[8];
      float emax = -3.0e38f;
      #pragma unroll
      for (int j = 0; j < 8; ++j) {
        u64 w = mrow[j];
        float s = srcv + dstS[j*64 + lane];
        float e = ((w >> lane) & 1ull) ? lrelu_f(s) : -1.0e9f;
        ev[j] = e;
        emax = fmaxf(emax, e);
      }
      #pragma unroll
      for (int mk = 1; mk <= 32; mk <<= 1) emax = fmaxf(emax, __shfl_xor(emax, mk));
      float lsum = 0.f;
      #pragma unroll
      for (int j = 0; j < 8; ++j) { float p = __expf(ev[j] - emax); ev[j] = p; lsum += p; }
      #pragma unroll
      for (int mk = 1; mk <= 32; mk <<= 1) lsum += __shfl_xor(lsum, mk);
      float rcp = 1.f / lsum;
      #pragma unroll
      for (int j = 0; j < 8; ++j)
        pS[rloc*520 + j*64 + lane] = f2bf(ev[j] * rcp);
    }
    __syncthreads();

    f32x4 acc = {0.f, 0.f, 0.f, 0.f};
    #pragma unroll
    for (int ks = 0; ks < 16; ++ks) {
      bf16x8 af = *(const bf16x8*)(aBase + ks*64);
      bf16x8 bf = *(const bf16x8*)(bBase + ks*64);
      acc = __builtin_amdgcn_mfma_f32_16x16x32_bf16(af, bf, acc, 0, 0, 0);
    }
    #pragma unroll
    for (int reg = 0; reg < 4; ++reg) {
      int row = sup*64 + cgl*16 + lg*4 + reg;
      float v = elu_f(acc[reg] + bb);
      hp1b[((long)bh*NN + row)*64 + o_out] = (u16)f2bf(v);
    }
    __syncthreads();
  }
}

// ---------------------------------------------------------------------------
// K6: GAT layer-2 attention (rows 0,1 only) + ELU + MLP + log_softmax.
// ---------------------------------------------------------------------------
__global__ __launch_bounds__(256) void gat2_final(
    const float* __restrict__ hp2, const u64* __restrict__ maskw,
    const float* __restrict__ a_src2, const float* __restrict__ a_dst2,
    const float* __restrict__ b2,
    const float* __restrict__ fc1_w, const float* __restrict__ fc1_b,
    const float* __restrict__ fc2_w, const float* __restrict__ fc2_b,
    const float* __restrict__ fc3_w, const float* __restrict__ fc3_b,
    float* __restrict__ out)
{
  extern __shared__ float sm[];
  float* hpS  = sm;              // 32768
  float* dstS = hpS + 32768;     // 512
  float* srcS = dstS + 512;      // 512
  float* pS   = srcS + 512;      // 512
  float* redS = pS + 512;        // 256
  float* outS = redS + 256;      // 128
  float* vS   = outS + 128;      // 64
  float* y1S  = vS + 64;         // 192
  float* redM = y1S + 192;       // 8
  float4* hpS4 = (float4*)hpS;

  int b = blockIdx.x;
  int tid = threadIdx.x;
  int og = tid & 15, m16 = tid >> 4;

  for (int it = 0; it < 32; ++it) {
    int fi = it*256 + tid;
    int m = fi >> 4, o4 = fi & 15;
    hpS4[m*16 + o4] = *(const float4*)(hp2 + (long)(b*NN + m)*64 + o4*4);
  }
  __syncthreads();

  float4 as4 = *(const float4*)(a_src2 + og*4);
  float4 ad4 = *(const float4*)(a_dst2 + og*4);
  for (int it = 0; it < 32; ++it) {
    int m = it*16 + m16;
    float4 hv = hpS4[m*16 + og];
    float ls = hv.x*as4.x + hv.y*as4.y + hv.z*as4.z + hv.w*as4.w;
    float ld = hv.x*ad4.x + hv.y*ad4.y + hv.z*ad4.z + hv.w*ad4.w;
    #pragma unroll
    for (int mk = 1; mk <= 8; mk <<= 1) {
      ls += __shfl_xor(ls, mk);
      ld += __shfl_xor(ld, mk);
    }
    if (og == 0) { srcS[m] = ls; dstS[m] = ld; }
  }
  __syncthreads();

  for (int n = 0; n < 2; ++n) {
    float srcv = srcS[n];
    const u64* mrow = maskw + (long)(b*NN + n)*8;
    int m0 = tid, m1 = tid + 256;
    u64 w0 = mrow[m0 >> 6], w1 = mrow[m1 >> 6];
    float s0 = srcv + dstS[m0], s1 = srcv + dstS[m1];
    float e0 = ((w0 >> (m0 & 63)) & 1ull) ? lrelu_f(s0) : -1.0e9f;
    float e1 = ((w1 >> (m1 & 63)) & 1ull) ? lrelu_f(s1) : -1.0e9f;
    float emax = fmaxf(e0, e1);
    #pragma unroll
    for (int mk = 1; mk <= 32; mk <<= 1) emax = fmaxf(emax, __shfl_xor(emax, mk));
    if ((tid & 63) == 0) redM[tid >> 6] = emax;
    __syncthreads();
    emax = fmaxf(fmaxf(redM[0], redM[1]), fmaxf(redM[2], redM[3]));
    float p0 = __expf(e0 - emax), p1 = __expf(e1 - emax);
    pS[m0] = p0; pS[m1] = p1;
    float lsum = p0 + p1;
    #pragma unroll
    for (int mk = 1; mk <= 32; mk <<= 1) lsum += __shfl_xor(lsum, mk);
    if ((tid & 63) == 0) redM[4 + (tid >> 6)] = lsum;
    __syncthreads();
    float rcp = 1.f / (redM[4] + redM[5] + redM[6] + redM[7]);

    float4 acc = make_float4(0.f,0.f,0.f,0.f);
    for (int mm = 0; mm < 32; ++mm) {
      int m = mm*16 + m16;
      float4 hv = hpS4[m*16 + og];
      float p = pS[m];
      acc.x += hv.x*p; acc.y += hv.y*p; acc.z += hv.z*p; acc.w += hv.w*p;
    }
    acc.x += __shfl_xor(acc.x, 16); acc.y += __shfl_xor(acc.y, 16);
    acc.z += __shfl_xor(acc.z, 16); acc.w += __shfl_xor(acc.w, 16);
    acc.x += __shfl_xor(acc.x, 32); acc.y += __shfl_xor(acc.y, 32);
    acc.z += __shfl_xor(acc.z, 32); acc.w += __shfl_xor(acc.w, 32);
    __syncthreads();
    if ((tid & 63) < 16) ((float4*)redS)[(tid >> 6)*16 + (tid & 15)] = acc;
    __syncthreads();
    if (tid < 16) {
      float4 s = make_float4(0.f,0.f,0.f,0.f);
      #pragma unroll
      for (int w = 0; w < 4; ++w) {
        float4 v = ((float4*)redS)[w*16 + tid];
        s.x += v.x; s.y += v.y; s.z += v.z; s.w += v.w;
      }
      float4 bv = *(const float4*)(b2 + tid*4);
      outS[n*64 + tid*4 + 0] = elu_f(s.x*rcp + bv.x);
      outS[n*64 + tid*4 + 1] = elu_f(s.y*rcp + bv.y);
      outS[n*64 + tid*4 + 2] = elu_f(s.z*rcp + bv.z);
      outS[n*64 + tid*4 + 3] = elu_f(s.w*rcp + bv.w);
    }
    __syncthreads();
  }

  if (tid < 64) vS[tid] = outS[tid] * outS[64 + tid];
  __syncthreads();
  if (tid < 192) {
    float a = fc1_b[tid];
    for (int o = 0; o < 64; ++o) a += vS[o]*fc1_w[o*192 + tid];
    y1S[tid] = a > 0.f ? a : 0.f;
  }
  __syncthreads();
  if (tid < 64) {
    float a = fc2_b[tid];
    for (int j = 0; j < 192; ++j) a += y1S[j]*fc2_w[j*64 + tid];
    vS[tid] = a > 0.f ? a : 0.f;
  }
  __syncthreads();
  if (tid == 0) {
    float t0 = fc3_b[0], t1 = fc3_b[1];
    for (int k = 0; k < 64; ++k) {
      float y = vS[k];
      t0 += y*fc3_w[k*2 + 0];
      t1 += y*fc3_w[k*2 + 1];
    }
    float mx = fmaxf(t0, t1);
    float lse = mx + logf(__expf(t0 - mx) + __expf(t1 - mx));
    out[b*2 + 0] = t0 - lse;
    out[b*2 + 1] = t1 - lse;
  }
}

// ---------------------------------------------------------------------------
extern "C" void kernel_launch(void* const* d_in, const int* in_sizes, int n_in,
                              void* d_out, int out_size, void* d_ws, size_t ws_size,
                              hipStream_t stream) {
  const float* emb    = (const float*)d_in[0];
  const int*   adj    = (const int*)d_in[1];
  const float* vt     = (const float*)d_in[2];
  const float* w1     = (const float*)d_in[3];
  const float* a_src1 = (const float*)d_in[4];
  const float* a_dst1 = (const float*)d_in[5];
  const float* b1     = (const float*)d_in[6];
  const float* w2     = (const float*)d_in[7];
  const float* a_src2 = (const float*)d_in[8];
  const float* a_dst2 = (const float*)d_in[9];
  const float* b2     = (const float*)d_in[10];
  const float* fc1_w  = (const float*)d_in[11];
  const float* fc1_b  = (const float*)d_in[12];
  const float* fc2_w  = (const float*)d_in[13];
  const float* fc2_b  = (const float*)d_in[14];
  const float* fc3_w  = (const float*)d_in[15];
  const float* fc3_b  = (const float*)d_in[16];

  char* ws = (char*)d_ws;
  int* counts  = (int*)ws;                       // @0
  int* rowlist = (int*)(ws + 4096);              // 196,608 B
  u64* maskw   = (u64*)(ws + 204800);            // 1 MB
  u16* w1t     = (u16*)(ws + 1310720);           // 2,359,296 B
  u16* w2t     = (u16*)(ws + 3670016);           // 196,608 B
  u16* hp1b    = (u16*)(ws + 3932160);           // 16,777,216 B (x in-place)
  float* hp2   = (float*)(ws + 20709376);        // 4,194,304 B  -> end 24.9 MB

  hipMemsetAsync(counts, 0, 16, stream);
  prep_kernel<<<NROWS/4, 256, 0, stream>>>(adj, maskw);
  rowlist_kernel<<<NROWS/256, 256, 0, stream>>>(vt, rowlist, counts);
  conv_w<<<dim3(27, 4), 256, 0, stream>>>(w1, w2, w1t, w2t);

  gemm1_mfma<<<dim3(352, 1, 3), 256, 0, stream>>>(emb, w1t, rowlist, counts, hp1b);

  size_t sm1 = 137728;
  gat1_attn<<<BB*NH, 1024, sm1, stream>>>(hp1b, maskw, a_src1, a_dst1, b1);

  gemm2_mfma<<<dim3(1, 256, 3), 256, 0, stream>>>(hp1b, w2t, rowlist, counts, hp2);

  size_t sm2 = (size_t)(32768 + 512 + 512 + 512 + 256 + 128 + 64 + 192 + 8) * 4;
  gat2_final<<<BB, 256, sm2, stream>>>(hp2, maskw, a_src2, a_dst2, b2,
                                       fc1_w, fc1_b, fc2_w, fc2_b, fc3_w, fc3_b,
                                       (float*)d_out);
}

// Round 8
// 170.514 us; speedup vs baseline: 14.8992x; 1.2133x over previous
//
#include <hip/hip_runtime.h>

#define BB   32
#define NN   512
#define NH   8
#define FIN  768
#define FHID 64
#define NROWS (BB*NN)   // 16384

typedef __attribute__((ext_vector_type(8))) short bf16x8;
typedef __attribute__((ext_vector_type(4))) short s16x4;
typedef __attribute__((ext_vector_type(4))) float f32x4;
typedef unsigned long long u64;
typedef unsigned short u16;

__device__ __forceinline__ float lrelu_f(float s){ return fmaxf(s, 0.2f*s); }
__device__ __forceinline__ float elu_f(float s){ return s > 0.f ? s : expm1f(s); }
__device__ __forceinline__ short f2bf(float f){
  unsigned u = __float_as_uint(f);
  return (short)((u + 0x7fffu + ((u >> 16) & 1u)) >> 16);   // RNE
}
__device__ __forceinline__ float bf2f(short s){
  return __uint_as_float(((unsigned)(u16)s) << 16);
}

// ---------------------------------------------------------------------------
// K1a: adjacency -> bitmask words
// ---------------------------------------------------------------------------
__global__ __launch_bounds__(256) void prep_kernel(
    const int* __restrict__ adj,
    u64* __restrict__ maskw)
{
  int row  = blockIdx.x * 4 + (threadIdx.x >> 6);
  int lane = threadIdx.x & 63;
  const int* arow = adj + (long)row * NN;
  #pragma unroll
  for (int w = 0; w < 8; ++w) {
    u64 bal = __ballot(arow[w*64 + lane] > 0);
    if (lane == 0) maskw[(long)row*8 + w] = bal;
  }
}

// ---------------------------------------------------------------------------
// K1b: per-type gathered row lists; 3 global atomics per block.
// ---------------------------------------------------------------------------
__global__ __launch_bounds__(256) void rowlist_kernel(
    const float* __restrict__ vt,
    int* __restrict__ rowlist, int* __restrict__ counts)
{
  __shared__ int lc[3];
  __shared__ int lbase[3];
  int tid = threadIdx.x;
  int row = blockIdx.x * 256 + tid;
  if (tid < 3) lc[tid] = 0;
  __syncthreads();
  const float* v = vt + (long)row*3;
  int t = v[1] > 0.5f ? 1 : (v[2] > 0.5f ? 2 : 0);
  int p = atomicAdd(&lc[t], 1);
  __syncthreads();
  if (tid < 3) lbase[tid] = atomicAdd(&counts[tid], lc[tid]);
  __syncthreads();
  rowlist[t*NROWS + lbase[t] + p] = row;
}

// ---------------------------------------------------------------------------
// K2: weight transpose+cast; blockIdx.y = K-quarter.
// ---------------------------------------------------------------------------
__global__ __launch_bounds__(256) void conv_w(
    const float* __restrict__ w1, const float* __restrict__ w2,
    u16* __restrict__ w1t, u16* __restrict__ w2t)
{
  __shared__ float tile[64][68];
  int bid = blockIdx.x, tid = threadIdx.x;
  const float* src; u16* dst; int K;
  if (bid < 24) { src = w1 + (long)bid*768*64; dst = w1t + (long)bid*64*768; K = 768; }
  else { int t = bid - 24; src = w2 + (long)t*512*64; dst = w2t + (long)t*64*512; K = 512; }
  int kq = blockIdx.y;
  int kstart = kq * (K >> 2), kend = kstart + (K >> 2);

  for (int k0 = kstart; k0 < kend; k0 += 64) {
    __syncthreads();
    #pragma unroll
    for (int i = 0; i < 4; ++i) {
      int kk = i*16 + (tid >> 4);
      int oo = (tid & 15) * 4;
      float4 v = *(const float4*)(src + (long)(k0 + kk)*64 + oo);
      *(float4*)&tile[kk][oo] = v;
    }
    __syncthreads();
    int o = tid >> 2, kp = (tid & 3) * 16;
    bf16x8 r0, r1;
    #pragma unroll
    for (int j = 0; j < 8; ++j) r0[j] = f2bf(tile[kp + j][o]);
    #pragma unroll
    for (int j = 0; j < 8; ++j) r1[j] = f2bf(tile[kp + 8 + j][o]);
    u16* d = dst + (long)o*K + k0 + kp;
    *(bf16x8*)d = r0;
    *(bf16x8*)(d + 8) = r1;
  }
}

// ---------------------------------------------------------------------------
// K3: layer-1 gathered GEMM, bf16 MFMA. BM=64, BN=128, 4 waves (32x64 tile).
// COALESCED staging: 4 consecutive lanes load consecutive 16B of one
// gathered row / one weight col (was 64-distinct-line gathers per wave =
// L1-transaction-bound, round-7 diagnosis). XCD-locality decode kept.
// ---------------------------------------------------------------------------
__global__ __launch_bounds__(256) void gemm1_mfma(
    const float* __restrict__ emb,
    const u16* __restrict__ w1t,
    const int* __restrict__ rowlist, const int* __restrict__ counts,
    u16* __restrict__ hp1b)
{
  int t   = blockIdx.z;
  int cnt = counts[t];
  int i   = blockIdx.x;
  int xcd = i & 7;
  int q   = i >> 3;
  int hb  = q & 3;
  int rb  = (q >> 2) * 8 + xcd;
  int r0  = rb * 64;
  if (r0 >= cnt) return;

  __shared__ short aT[4*66*8];          // [kg][66 rows][8]  padded
  __shared__ short bT[4*130*8];         // [kg][130 cols][8] padded
  __shared__ int rowsS[64];

  int tid = threadIdx.x;
  if (tid < 64) {
    int rr = r0 + tid;
    rowsS[tid] = (rr < cnt) ? rowlist[t*NROWS + rr] : -1;
  }
  __syncthreads();

  // A loader: thread -> (row ar, 16B chunk ac); lanes 0..3 same row.
  int ar = tid >> 2, ac = tid & 3;
  int sg = rowsS[ar]; if (sg < 0) sg = rowsS[0];
  const float* aP = emb + (long)sg*768;

  // B loader: thread -> (col, 16B chunk off); handles col and col+64.
  int colb = tid >> 2, off = tid & 3;           // colb 0..63
  const u16* bP1 = w1t + (((long)t*8 + hb*2 + 0)*64 + colb)*768;
  const u16* bP2 = w1t + (((long)t*8 + hb*2 + 1)*64 + colb)*768;

  int wv = tid >> 6, l = tid & 63;
  int wr = wv >> 1, wc = wv & 1;
  int l15 = l & 15, lg = l >> 4;

  f32x4 acc[2][4];
  #pragma unroll
  for (int fr = 0; fr < 2; ++fr)
    #pragma unroll
    for (int cf = 0; cf < 4; ++cf) acc[fr][cf] = (f32x4){0.f,0.f,0.f,0.f};

  float4 ra0 = *(const float4*)(aP + ac*4);
  float4 ra1 = *(const float4*)(aP + 16 + ac*4);
  bf16x8 rb1 = *(const bf16x8*)(bP1 + off*8);
  bf16x8 rb2 = *(const bf16x8*)(bP2 + off*8);

  for (int k0 = 0; k0 < 768; k0 += 32) {
    __syncthreads();
    s16x4 w0, w1;
    w0[0]=f2bf(ra0.x); w0[1]=f2bf(ra0.y); w0[2]=f2bf(ra0.z); w0[3]=f2bf(ra0.w);
    w1[0]=f2bf(ra1.x); w1[1]=f2bf(ra1.y); w1[2]=f2bf(ra1.z); w1[3]=f2bf(ra1.w);
    *(s16x4*)&aT[(( (ac>>1)     )*66 + ar)*8 + (ac&1)*4] = w0;
    *(s16x4*)&aT[(( 2 + (ac>>1) )*66 + ar)*8 + (ac&1)*4] = w1;
    *(bf16x8*)&bT[(off*130 + colb     )*8] = rb1;
    *(bf16x8*)&bT[(off*130 + colb + 64)*8] = rb2;
    __syncthreads();
    if (k0 + 32 < 768) {
      ra0 = *(const float4*)(aP + k0 + 32 + ac*4);
      ra1 = *(const float4*)(aP + k0 + 48 + ac*4);
      rb1 = *(const bf16x8*)(bP1 + k0 + 32 + off*8);
      rb2 = *(const bf16x8*)(bP2 + k0 + 32 + off*8);
    }
    bf16x8 af[2], bfr[4];
    #pragma unroll
    for (int fr = 0; fr < 2; ++fr)
      af[fr] = *(const bf16x8*)&aT[(lg*66 + wr*32 + fr*16 + l15)*8];
    #pragma unroll
    for (int cf = 0; cf < 4; ++cf)
      bfr[cf] = *(const bf16x8*)&bT[(lg*130 + wc*64 + cf*16 + l15)*8];
    #pragma unroll
    for (int fr = 0; fr < 2; ++fr)
      #pragma unroll
      for (int cf = 0; cf < 4; ++cf)
        acc[fr][cf] = __builtin_amdgcn_mfma_f32_16x16x32_bf16(af[fr], bfr[cf], acc[fr][cf], 0, 0, 0);
  }

  #pragma unroll
  for (int fr = 0; fr < 2; ++fr) {
    #pragma unroll
    for (int r = 0; r < 4; ++r) {
      int rloc = wr*32 + fr*16 + lg*4 + r;
      int rg = rowsS[rloc];
      if (rg < 0) continue;
      long obase = ((long)(rg >> 9) * 8) * 32768 + (long)(rg & 511) * 64;
      #pragma unroll
      for (int cf = 0; cf < 4; ++cf) {
        int c = wc*64 + cf*16 + l15;
        hp1b[obase + (long)(hb*2 + (c >> 6))*32768 + (c & 63)] = (u16)f2bf(acc[fr][cf][r]);
      }
    }
  }
}

// ---------------------------------------------------------------------------
// K5: layer-2 gathered GEMM, bf16 MFMA. BM=64, BN=64, wave tile 16x64.
// Same coalesced staging scheme.
// ---------------------------------------------------------------------------
__global__ __launch_bounds__(256) void gemm2_mfma(
    const u16* __restrict__ xbf,
    const u16* __restrict__ w2t,
    const int* __restrict__ rowlist, const int* __restrict__ counts,
    float* __restrict__ hp2)
{
  int t   = blockIdx.z;
  int cnt = counts[t];
  int r0  = blockIdx.y * 64;
  if (r0 >= cnt) return;

  __shared__ short aT[4*66*8];
  __shared__ short bT[4*66*8];
  __shared__ int rowsS[64];

  int tid = threadIdx.x;
  if (tid < 64) {
    int rr = r0 + tid;
    rowsS[tid] = (rr < cnt) ? rowlist[t*NROWS + rr] : -1;
  }
  __syncthreads();

  int ar = tid >> 2, ac = tid & 3;
  int sg = rowsS[ar]; if (sg < 0) sg = rowsS[0];
  long apart = ((long)(sg >> 9) * 8) * 32768 + (long)(sg & 511) * 64;

  int colb = tid >> 2, off = tid & 3;
  const u16* bP = w2t + ((long)t*64 + colb)*512;

  int wv = tid >> 6, l = tid & 63;
  int l15 = l & 15, lg = l >> 4;

  f32x4 acc[4];
  #pragma unroll
  for (int cf = 0; cf < 4; ++cf) acc[cf] = (f32x4){0.f,0.f,0.f,0.f};

  int ka0 = ac*8;
  bf16x8 ra = *(const bf16x8*)(xbf + apart + (long)(ka0 >> 6)*32768 + (ka0 & 63));
  bf16x8 rb = *(const bf16x8*)(bP + off*8);

  for (int k0 = 0; k0 < 512; k0 += 32) {
    __syncthreads();
    *(bf16x8*)&aT[(ac*66 + ar)*8]   = ra;
    *(bf16x8*)&bT[(off*66 + colb)*8] = rb;
    __syncthreads();
    if (k0 + 32 < 512) {
      int kn = k0 + 32 + ac*8;
      ra = *(const bf16x8*)(xbf + apart + (long)(kn >> 6)*32768 + (kn & 63));
      rb = *(const bf16x8*)(bP + k0 + 32 + off*8);
    }
    bf16x8 af, bfr[4];
    af = *(const bf16x8*)&aT[(lg*66 + wv*16 + l15)*8];
    #pragma unroll
    for (int cf = 0; cf < 4; ++cf)
      bfr[cf] = *(const bf16x8*)&bT[(lg*66 + cf*16 + l15)*8];
    #pragma unroll
    for (int cf = 0; cf < 4; ++cf)
      acc[cf] = __builtin_amdgcn_mfma_f32_16x16x32_bf16(af, bfr[cf], acc[cf], 0, 0, 0);
  }

  #pragma unroll
  for (int r = 0; r < 4; ++r) {
    int rloc = wv*16 + lg*4 + r;
    int rg = rowsS[rloc];
    if (rg < 0) continue;
    #pragma unroll
    for (int cf = 0; cf < 4; ++cf)
      hp2[(long)rg*64 + cf*16 + l15] = acc[cf][r];
  }
}

// ---------------------------------------------------------------------------
// K4: GAT layer-1 attention. One 1024-thread block per (b,h).
// Fragment-order LDS layouts [koct][col|row pad66][8] so MFMA ds_read_b128
// lane groups are contiguous 256B -> conflict-free (round-7: 4.98M
// SQ_LDS_BANK_CONFLICT from the 1040B-stride layout was the kernel).
// ---------------------------------------------------------------------------
__global__ __launch_bounds__(1024) void gat1_attn(
    u16* __restrict__ hp1b, const u64* __restrict__ maskw,
    const float* __restrict__ a_src, const float* __restrict__ a_dst,
    const float* __restrict__ b1)
{
  extern __shared__ char smc[];
  short* hpTf = (short*)smc;                  // [64 koct][66 o][8]  67,584 B
  short* pSf  = (short*)(smc + 67584);        // [64 koct][66 row][8] 67,584 B
  float* srcS = (float*)(smc + 135168);       // [512]
  float* dstS = (float*)(smc + 137216);       // [512]
  float* asS  = (float*)(smc + 139264);       // [64]
  float* adS  = (float*)(smc + 139520);       // [64]  end 139,776

  int bh = blockIdx.x;
  int b = bh >> 3, h = bh & 7;
  int tid = threadIdx.x;

  if (tid < 64) asS[tid] = a_src[h*64 + tid];
  else if (tid < 128) adS[tid - 64] = a_dst[h*64 + (tid - 64)];
  __syncthreads();

  // phase 0: load V slice, src/dst dots, scatter V into fragment order
  {
    int m = tid >> 1, half = tid & 1;
    int koct = m >> 3, sub = m & 7;
    const u16* hpRow = hp1b + ((long)bh*NN + m)*64 + half*32;
    float ps = 0.f, pd = 0.f;
    #pragma unroll
    for (int qq = 0; qq < 4; ++qq) {
      bf16x8 hv = *(const bf16x8*)(hpRow + qq*8);
      int o0 = half*32 + qq*8;
      #pragma unroll
      for (int j = 0; j < 8; ++j) {
        float f = bf2f(hv[j]);
        ps += f * asS[o0 + j];
        pd += f * adS[o0 + j];
        hpTf[(koct*66 + o0 + j)*8 + sub] = hv[j];
      }
    }
    ps += __shfl_xor(ps, 1);
    pd += __shfl_xor(pd, 1);
    if ((tid & 1) == 0) { srcS[m] = ps; dstS[m] = pd; }
  }
  __syncthreads();

  int wv = tid >> 6, lane = tid & 63;
  int l15 = lane & 15, lg = lane >> 4;
  int cgl = wv >> 2, nt = wv & 3;
  int lk = lane >> 3, ls = lane & 7;
  int o_out = nt*16 + l15;
  float bb  = b1[o_out];

  for (int sup = 0; sup < 8; ++sup) {
    // softmax: wave wv owns rows sup*64 + wv*4 + {0..3}
    #pragma unroll
    for (int rr = 0; rr < 4; ++rr) {
      int rloc = wv*4 + rr;
      int row  = sup*64 + rloc;
      float srcv = srcS[row];
      const u64* mrow = maskw + ((long)(b*NN + row))*8;
      float ev[8];
      float emax = -3.0e38f;
      #pragma unroll
      for (int j = 0; j < 8; ++j) {
        u64 w = mrow[j];
        float s = srcv + dstS[j*64 + lane];
        float e = ((w >> lane) & 1ull) ? lrelu_f(s) : -1.0e9f;
        ev[j] = e;
        emax = fmaxf(emax, e);
      }
      #pragma unroll
      for (int mk = 1; mk <= 32; mk <<= 1) emax = fmaxf(emax, __shfl_xor(emax, mk));
      float lsum = 0.f;
      #pragma unroll
      for (int j = 0; j < 8; ++j) { float p = __expf(ev[j] - emax); ev[j] = p; lsum += p; }
      #pragma unroll
      for (int mk = 1; mk <= 32; mk <<= 1) lsum += __shfl_xor(lsum, mk);
      float rcp = 1.f / lsum;
      #pragma unroll
      for (int j = 0; j < 8; ++j)
        pSf[((j*8 + lk)*66 + rloc)*8 + ls] = f2bf(ev[j] * rcp);
    }
    __syncthreads();

    // PV via MFMA: wave (cgl,nt) -> rows cgl*16, cols nt*16, K=512
    f32x4 acc = {0.f, 0.f, 0.f, 0.f};
    #pragma unroll
    for (int ks = 0; ks < 16; ++ks) {
      int koct = ks*4 + lg;
      bf16x8 af = *(const bf16x8*)&pSf [(koct*66 + cgl*16 + l15)*8];
      bf16x8 bf = *(const bf16x8*)&hpTf[(koct*66 + nt*16  + l15)*8];
      acc = __builtin_amdgcn_mfma_f32_16x16x32_bf16(af, bf, acc, 0, 0, 0);
    }
    #pragma unroll
    for (int reg = 0; reg < 4; ++reg) {
      int row = sup*64 + cgl*16 + lg*4 + reg;
      float v = elu_f(acc[reg] + bb);
      hp1b[((long)bh*NN + row)*64 + o_out] = (u16)f2bf(v);
    }
    __syncthreads();
  }
}

// ---------------------------------------------------------------------------
// K6: GAT layer-2 attention (rows 0,1 only) + ELU + MLP + log_softmax.
// ---------------------------------------------------------------------------
__global__ __launch_bounds__(256) void gat2_final(
    const float* __restrict__ hp2, const u64* __restrict__ maskw,
    const float* __restrict__ a_src2, const float* __restrict__ a_dst2,
    const float* __restrict__ b2,
    const float* __restrict__ fc1_w, const float* __restrict__ fc1_b,
    const float* __restrict__ fc2_w, const float* __restrict__ fc2_b,
    const float* __restrict__ fc3_w, const float* __restrict__ fc3_b,
    float* __restrict__ out)
{
  extern __shared__ float sm[];
  float* hpS  = sm;              // 32768
  float* dstS = hpS + 32768;     // 512
  float* srcS = dstS + 512;      // 512
  float* pS   = srcS + 512;      // 512
  float* redS = pS + 512;        // 256
  float* outS = redS + 256;      // 128
  float* vS   = outS + 128;      // 64
  float* y1S  = vS + 64;         // 192
  float* redM = y1S + 192;       // 8
  float4* hpS4 = (float4*)hpS;

  int b = blockIdx.x;
  int tid = threadIdx.x;
  int og = tid & 15, m16 = tid >> 4;

  for (int it = 0; it < 32; ++it) {
    int fi = it*256 + tid;
    int m = fi >> 4, o4 = fi & 15;
    hpS4[m*16 + o4] = *(const float4*)(hp2 + (long)(b*NN + m)*64 + o4*4);
  }
  __syncthreads();

  float4 as4 = *(const float4*)(a_src2 + og*4);
  float4 ad4 = *(const float4*)(a_dst2 + og*4);
  for (int it = 0; it < 32; ++it) {
    int m = it*16 + m16;
    float4 hv = hpS4[m*16 + og];
    float ls = hv.x*as4.x + hv.y*as4.y + hv.z*as4.z + hv.w*as4.w;
    float ld = hv.x*ad4.x + hv.y*ad4.y + hv.z*ad4.z + hv.w*ad4.w;
    #pragma unroll
    for (int mk = 1; mk <= 8; mk <<= 1) {
      ls += __shfl_xor(ls, mk);
      ld += __shfl_xor(ld, mk);
    }
    if (og == 0) { srcS[m] = ls; dstS[m] = ld; }
  }
  __syncthreads();

  for (int n = 0; n < 2; ++n) {
    float srcv = srcS[n];
    const u64* mrow = maskw + (long)(b*NN + n)*8;
    int m0 = tid, m1 = tid + 256;
    u64 w0 = mrow[m0 >> 6], w1 = mrow[m1 >> 6];
    float s0 = srcv + dstS[m0], s1 = srcv + dstS[m1];
    float e0 = ((w0 >> (m0 & 63)) & 1ull) ? lrelu_f(s0) : -1.0e9f;
    float e1 = ((w1 >> (m1 & 63)) & 1ull) ? lrelu_f(s1) : -1.0e9f;
    float emax = fmaxf(e0, e1);
    #pragma unroll
    for (int mk = 1; mk <= 32; mk <<= 1) emax = fmaxf(emax, __shfl_xor(emax, mk));
    if ((tid & 63) == 0) redM[tid >> 6] = emax;
    __syncthreads();
    emax = fmaxf(fmaxf(redM[0], redM[1]), fmaxf(redM[2], redM[3]));
    float p0 = __expf(e0 - emax), p1 = __expf(e1 - emax);
    pS[m0] = p0; pS[m1] = p1;
    float lsum = p0 + p1;
    #pragma unroll
    for (int mk = 1; mk <= 32; mk <<= 1) lsum += __shfl_xor(lsum, mk);
    if ((tid & 63) == 0) redM[4 + (tid >> 6)] = lsum;
    __syncthreads();
    float rcp = 1.f / (redM[4] + redM[5] + redM[6] + redM[7]);

    float4 acc = make_float4(0.f,0.f,0.f,0.f);
    for (int mm = 0; mm < 32; ++mm) {
      int m = mm*16 + m16;
      float4 hv = hpS4[m*16 + og];
      float p = pS[m];
      acc.x += hv.x*p; acc.y += hv.y*p; acc.z += hv.z*p; acc.w += hv.w*p;
    }
    acc.x += __shfl_xor(acc.x, 16); acc.y += __shfl_xor(acc.y, 16);
    acc.z += __shfl_xor(acc.z, 16); acc.w += __shfl_xor(acc.w, 16);
    acc.x += __shfl_xor(acc.x, 32); acc.y += __shfl_xor(acc.y, 32);
    acc.z += __shfl_xor(acc.z, 32); acc.w += __shfl_xor(acc.w, 32);
    __syncthreads();
    if ((tid & 63) < 16) ((float4*)redS)[(tid >> 6)*16 + (tid & 15)] = acc;
    __syncthreads();
    if (tid < 16) {
      float4 s = make_float4(0.f,0.f,0.f,0.f);
      #pragma unroll
      for (int w = 0; w < 4; ++w) {
        float4 v = ((float4*)redS)[w*16 + tid];
        s.x += v.x; s.y += v.y; s.z += v.z; s.w += v.w;
      }
      float4 bv = *(const float4*)(b2 + tid*4);
      outS[n*64 + tid*4 + 0] = elu_f(s.x*rcp + bv.x);
      outS[n*64 + tid*4 + 1] = elu_f(s.y*rcp + bv.y);
      outS[n*64 + tid*4 + 2] = elu_f(s.z*rcp + bv.z);
      outS[n*64 + tid*4 + 3] = elu_f(s.w*rcp + bv.w);
    }
    __syncthreads();
  }

  if (tid < 64) vS[tid] = outS[tid] * outS[64 + tid];
  __syncthreads();
  if (tid < 192) {
    float a = fc1_b[tid];
    for (int o = 0; o < 64; ++o) a += vS[o]*fc1_w[o*192 + tid];
    y1S[tid] = a > 0.f ? a : 0.f;
  }
  __syncthreads();
  if (tid < 64) {
    float a = fc2_b[tid];
    for (int j = 0; j < 192; ++j) a += y1S[j]*fc2_w[j*64 + tid];
    vS[tid] = a > 0.f ? a : 0.f;
  }
  __syncthreads();
  if (tid == 0) {
    float t0 = fc3_b[0], t1 = fc3_b[1];
    for (int k = 0; k < 64; ++k) {
      float y = vS[k];
      t0 += y*fc3_w[k*2 + 0];
      t1 += y*fc3_w[k*2 + 1];
    }
    float mx = fmaxf(t0, t1);
    float lse = mx + logf(__expf(t0 - mx) + __expf(t1 - mx));
    out[b*2 + 0] = t0 - lse;
    out[b*2 + 1] = t1 - lse;
  }
}

// ---------------------------------------------------------------------------
extern "C" void kernel_launch(void* const* d_in, const int* in_sizes, int n_in,
                              void* d_out, int out_size, void* d_ws, size_t ws_size,
                              hipStream_t stream) {
  const float* emb    = (const float*)d_in[0];
  const int*   adj    = (const int*)d_in[1];
  const float* vt     = (const float*)d_in[2];
  const float* w1     = (const float*)d_in[3];
  const float* a_src1 = (const float*)d_in[4];
  const float* a_dst1 = (const float*)d_in[5];
  const float* b1     = (const float*)d_in[6];
  const float* w2     = (const float*)d_in[7];
  const float* a_src2 = (const float*)d_in[8];
  const float* a_dst2 = (const float*)d_in[9];
  const float* b2     = (const float*)d_in[10];
  const float* fc1_w  = (const float*)d_in[11];
  const float* fc1_b  = (const float*)d_in[12];
  const float* fc2_w  = (const float*)d_in[13];
  const float* fc2_b  = (const float*)d_in[14];
  const float* fc3_w  = (const float*)d_in[15];
  const float* fc3_b  = (const float*)d_in[16];

  char* ws = (char*)d_ws;
  int* counts  = (int*)ws;
  int* rowlist = (int*)(ws + 4096);
  u64* maskw   = (u64*)(ws + 204800);
  u16* w1t     = (u16*)(ws + 1310720);
  u16* w2t     = (u16*)(ws + 3670016);
  u16* hp1b    = (u16*)(ws + 3932160);
  float* hp2   = (float*)(ws + 20709376);

  hipMemsetAsync(counts, 0, 16, stream);
  prep_kernel<<<NROWS/4, 256, 0, stream>>>(adj, maskw);
  rowlist_kernel<<<NROWS/256, 256, 0, stream>>>(vt, rowlist, counts);
  conv_w<<<dim3(27, 4), 256, 0, stream>>>(w1, w2, w1t, w2t);

  gemm1_mfma<<<dim3(352, 1, 3), 256, 0, stream>>>(emb, w1t, rowlist, counts, hp1b);

  size_t sm1 = 139776;
  gat1_attn<<<BB*NH, 1024, sm1, stream>>>(hp1b, maskw, a_src1, a_dst1, b1);

  gemm2_mfma<<<dim3(1, 256, 3), 256, 0, stream>>>(hp1b, w2t, rowlist, counts, hp2);

  size_t sm2 = (size_t)(32768 + 512 + 512 + 512 + 256 + 128 + 64 + 192 + 8) * 4;
  gat2_final<<<BB, 256, sm2, stream>>>(hp2, maskw, a_src2, a_dst2, b2,
                                       fc1_w, fc1_b, fc2_w, fc2_b, fc3_w, fc3_b,
                                       (float*)d_out);
}

// Round 9
// 158.884 us; speedup vs baseline: 15.9898x; 1.0732x over previous
//
#include <hip/hip_runtime.h>

#define BB   32
#define NN   512
#define NH   8
#define FIN  768
#define FHID 64
#define NROWS (BB*NN)   // 16384

typedef __attribute__((ext_vector_type(8))) short bf16x8;
typedef __attribute__((ext_vector_type(4))) short s16x4;
typedef __attribute__((ext_vector_type(4))) float f32x4;
typedef unsigned long long u64;
typedef unsigned short u16;

__device__ __forceinline__ float lrelu_f(float s){ return fmaxf(s, 0.2f*s); }
__device__ __forceinline__ float elu_f(float s){ return s > 0.f ? s : expm1f(s); }
__device__ __forceinline__ short f2bf(float f){
  unsigned u = __float_as_uint(f);
  return (short)((u + 0x7fffu + ((u >> 16) & 1u)) >> 16);   // RNE
}
__device__ __forceinline__ float bf2f(short s){
  return __uint_as_float(((unsigned)(u16)s) << 16);
}

// ---------------------------------------------------------------------------
// K1a: adjacency -> bitmask words
// ---------------------------------------------------------------------------
__global__ __launch_bounds__(256) void prep_kernel(
    const int* __restrict__ adj,
    u64* __restrict__ maskw)
{
  int row  = blockIdx.x * 4 + (threadIdx.x >> 6);
  int lane = threadIdx.x & 63;
  const int* arow = adj + (long)row * NN;
  #pragma unroll
  for (int w = 0; w < 8; ++w) {
    u64 bal = __ballot(arow[w*64 + lane] > 0);
    if (lane == 0) maskw[(long)row*8 + w] = bal;
  }
}

// ---------------------------------------------------------------------------
// K1b: per-type gathered row lists; 3 global atomics per block.
// ---------------------------------------------------------------------------
__global__ __launch_bounds__(256) void rowlist_kernel(
    const float* __restrict__ vt,
    int* __restrict__ rowlist, int* __restrict__ counts)
{
  __shared__ int lc[3];
  __shared__ int lbase[3];
  int tid = threadIdx.x;
  int row = blockIdx.x * 256 + tid;
  if (tid < 3) lc[tid] = 0;
  __syncthreads();
  const float* v = vt + (long)row*3;
  int t = v[1] > 0.5f ? 1 : (v[2] > 0.5f ? 2 : 0);
  int p = atomicAdd(&lc[t], 1);
  __syncthreads();
  if (tid < 3) lbase[tid] = atomicAdd(&counts[tid], lc[tid]);
  __syncthreads();
  rowlist[t*NROWS + lbase[t] + p] = row;
}

// ---------------------------------------------------------------------------
// K2: weight transpose+cast; blockIdx.y = K-quarter.
// ---------------------------------------------------------------------------
__global__ __launch_bounds__(256) void conv_w(
    const float* __restrict__ w1, const float* __restrict__ w2,
    u16* __restrict__ w1t, u16* __restrict__ w2t)
{
  __shared__ float tile[64][68];
  int bid = blockIdx.x, tid = threadIdx.x;
  const float* src; u16* dst; int K;
  if (bid < 24) { src = w1 + (long)bid*768*64; dst = w1t + (long)bid*64*768; K = 768; }
  else { int t = bid - 24; src = w2 + (long)t*512*64; dst = w2t + (long)t*64*512; K = 512; }
  int kq = blockIdx.y;
  int kstart = kq * (K >> 2), kend = kstart + (K >> 2);

  for (int k0 = kstart; k0 < kend; k0 += 64) {
    __syncthreads();
    #pragma unroll
    for (int i = 0; i < 4; ++i) {
      int kk = i*16 + (tid >> 4);
      int oo = (tid & 15) * 4;
      float4 v = *(const float4*)(src + (long)(k0 + kk)*64 + oo);
      *(float4*)&tile[kk][oo] = v;
    }
    __syncthreads();
    int o = tid >> 2, kp = (tid & 3) * 16;
    bf16x8 r0, r1;
    #pragma unroll
    for (int j = 0; j < 8; ++j) r0[j] = f2bf(tile[kp + j][o]);
    #pragma unroll
    for (int j = 0; j < 8; ++j) r1[j] = f2bf(tile[kp + 8 + j][o]);
    u16* d = dst + (long)o*K + k0 + kp;
    *(bf16x8*)d = r0;
    *(bf16x8*)(d + 8) = r1;
  }
}

// ---------------------------------------------------------------------------
// K3: layer-1 gathered GEMM, bf16 MFMA. BM=64, BN=128, 4 waves (32x64 tile).
// Coalesced staging + XCD-locality decode. (unchanged from round 8)
// ---------------------------------------------------------------------------
__global__ __launch_bounds__(256) void gemm1_mfma(
    const float* __restrict__ emb,
    const u16* __restrict__ w1t,
    const int* __restrict__ rowlist, const int* __restrict__ counts,
    u16* __restrict__ hp1b)
{
  int t   = blockIdx.z;
  int cnt = counts[t];
  int i   = blockIdx.x;
  int xcd = i & 7;
  int q   = i >> 3;
  int hb  = q & 3;
  int rb  = (q >> 2) * 8 + xcd;
  int r0  = rb * 64;
  if (r0 >= cnt) return;

  __shared__ short aT[4*66*8];
  __shared__ short bT[4*130*8];
  __shared__ int rowsS[64];

  int tid = threadIdx.x;
  if (tid < 64) {
    int rr = r0 + tid;
    rowsS[tid] = (rr < cnt) ? rowlist[t*NROWS + rr] : -1;
  }
  __syncthreads();

  int ar = tid >> 2, ac = tid & 3;
  int sg = rowsS[ar]; if (sg < 0) sg = rowsS[0];
  const float* aP = emb + (long)sg*768;

  int colb = tid >> 2, off = tid & 3;
  const u16* bP1 = w1t + (((long)t*8 + hb*2 + 0)*64 + colb)*768;
  const u16* bP2 = w1t + (((long)t*8 + hb*2 + 1)*64 + colb)*768;

  int wv = tid >> 6, l = tid & 63;
  int wr = wv >> 1, wc = wv & 1;
  int l15 = l & 15, lg = l >> 4;

  f32x4 acc[2][4];
  #pragma unroll
  for (int fr = 0; fr < 2; ++fr)
    #pragma unroll
    for (int cf = 0; cf < 4; ++cf) acc[fr][cf] = (f32x4){0.f,0.f,0.f,0.f};

  float4 ra0 = *(const float4*)(aP + ac*4);
  float4 ra1 = *(const float4*)(aP + 16 + ac*4);
  bf16x8 rb1 = *(const bf16x8*)(bP1 + off*8);
  bf16x8 rb2 = *(const bf16x8*)(bP2 + off*8);

  for (int k0 = 0; k0 < 768; k0 += 32) {
    __syncthreads();
    s16x4 w0, w1;
    w0[0]=f2bf(ra0.x); w0[1]=f2bf(ra0.y); w0[2]=f2bf(ra0.z); w0[3]=f2bf(ra0.w);
    w1[0]=f2bf(ra1.x); w1[1]=f2bf(ra1.y); w1[2]=f2bf(ra1.z); w1[3]=f2bf(ra1.w);
    *(s16x4*)&aT[(( (ac>>1)     )*66 + ar)*8 + (ac&1)*4] = w0;
    *(s16x4*)&aT[(( 2 + (ac>>1) )*66 + ar)*8 + (ac&1)*4] = w1;
    *(bf16x8*)&bT[(off*130 + colb     )*8] = rb1;
    *(bf16x8*)&bT[(off*130 + colb + 64)*8] = rb2;
    __syncthreads();
    if (k0 + 32 < 768) {
      ra0 = *(const float4*)(aP + k0 + 32 + ac*4);
      ra1 = *(const float4*)(aP + k0 + 48 + ac*4);
      rb1 = *(const bf16x8*)(bP1 + k0 + 32 + off*8);
      rb2 = *(const bf16x8*)(bP2 + k0 + 32 + off*8);
    }
    bf16x8 af[2], bfr[4];
    #pragma unroll
    for (int fr = 0; fr < 2; ++fr)
      af[fr] = *(const bf16x8*)&aT[(lg*66 + wr*32 + fr*16 + l15)*8];
    #pragma unroll
    for (int cf = 0; cf < 4; ++cf)
      bfr[cf] = *(const bf16x8*)&bT[(lg*130 + wc*64 + cf*16 + l15)*8];
    #pragma unroll
    for (int fr = 0; fr < 2; ++fr)
      #pragma unroll
      for (int cf = 0; cf < 4; ++cf)
        acc[fr][cf] = __builtin_amdgcn_mfma_f32_16x16x32_bf16(af[fr], bfr[cf], acc[fr][cf], 0, 0, 0);
  }

  #pragma unroll
  for (int fr = 0; fr < 2; ++fr) {
    #pragma unroll
    for (int r = 0; r < 4; ++r) {
      int rloc = wr*32 + fr*16 + lg*4 + r;
      int rg = rowsS[rloc];
      if (rg < 0) continue;
      long obase = ((long)(rg >> 9) * 8) * 32768 + (long)(rg & 511) * 64;
      #pragma unroll
      for (int cf = 0; cf < 4; ++cf) {
        int c = wc*64 + cf*16 + l15;
        hp1b[obase + (long)(hb*2 + (c >> 6))*32768 + (c & 63)] = (u16)f2bf(acc[fr][cf][r]);
      }
    }
  }
}

// ---------------------------------------------------------------------------
// K5: layer-2 gathered GEMM, bf16 MFMA. BM=64, BN=64. (unchanged)
// ---------------------------------------------------------------------------
__global__ __launch_bounds__(256) void gemm2_mfma(
    const u16* __restrict__ xbf,
    const u16* __restrict__ w2t,
    const int* __restrict__ rowlist, const int* __restrict__ counts,
    float* __restrict__ hp2)
{
  int t   = blockIdx.z;
  int cnt = counts[t];
  int r0  = blockIdx.y * 64;
  if (r0 >= cnt) return;

  __shared__ short aT[4*66*8];
  __shared__ short bT[4*66*8];
  __shared__ int rowsS[64];

  int tid = threadIdx.x;
  if (tid < 64) {
    int rr = r0 + tid;
    rowsS[tid] = (rr < cnt) ? rowlist[t*NROWS + rr] : -1;
  }
  __syncthreads();

  int ar = tid >> 2, ac = tid & 3;
  int sg = rowsS[ar]; if (sg < 0) sg = rowsS[0];
  long apart = ((long)(sg >> 9) * 8) * 32768 + (long)(sg & 511) * 64;

  int colb = tid >> 2, off = tid & 3;
  const u16* bP = w2t + ((long)t*64 + colb)*512;

  int wv = tid >> 6, l = tid & 63;
  int l15 = l & 15, lg = l >> 4;

  f32x4 acc[4];
  #pragma unroll
  for (int cf = 0; cf < 4; ++cf) acc[cf] = (f32x4){0.f,0.f,0.f,0.f};

  int ka0 = ac*8;
  bf16x8 ra = *(const bf16x8*)(xbf + apart + (long)(ka0 >> 6)*32768 + (ka0 & 63));
  bf16x8 rb = *(const bf16x8*)(bP + off*8);

  for (int k0 = 0; k0 < 512; k0 += 32) {
    __syncthreads();
    *(bf16x8*)&aT[(ac*66 + ar)*8]   = ra;
    *(bf16x8*)&bT[(off*66 + colb)*8] = rb;
    __syncthreads();
    if (k0 + 32 < 512) {
      int kn = k0 + 32 + ac*8;
      ra = *(const bf16x8*)(xbf + apart + (long)(kn >> 6)*32768 + (kn & 63));
      rb = *(const bf16x8*)(bP + k0 + 32 + off*8);
    }
    bf16x8 af, bfr[4];
    af = *(const bf16x8*)&aT[(lg*66 + wv*16 + l15)*8];
    #pragma unroll
    for (int cf = 0; cf < 4; ++cf)
      bfr[cf] = *(const bf16x8*)&bT[(lg*66 + cf*16 + l15)*8];
    #pragma unroll
    for (int cf = 0; cf < 4; ++cf)
      acc[cf] = __builtin_amdgcn_mfma_f32_16x16x32_bf16(af, bfr[cf], acc[cf], 0, 0, 0);
  }

  #pragma unroll
  for (int r = 0; r < 4; ++r) {
    int rloc = wv*16 + lg*4 + r;
    int rg = rowsS[rloc];
    if (rg < 0) continue;
    #pragma unroll
    for (int cf = 0; cf < 4; ++cf)
      hp2[(long)rg*64 + cf*16 + l15] = acc[cf][r];
  }
}

// ---------------------------------------------------------------------------
// K4: GAT layer-1 attention. One 1024-thread block per (b,h).
// Round-9 softmax restructure: (1) NO max subtraction -- scores are O(5),
// exp can't overflow, masked lanes exp(-1e9)=0 exactly (shift-invariance);
// (2) UNNORMALIZED p written to LDS immediately; row-sum reduction result
// (rcp) consumed only at the PV epilogue (latency hidden). This removes
// both serial 6-level shuffle chains from the P-write critical path
// (round-8: conflict counter bit-identical across layouts => shuffles,
// not ds_read, were the LDS cost; VALUBusy 46% latency-bound).
// ---------------------------------------------------------------------------
__global__ __launch_bounds__(1024) void gat1_attn(
    u16* __restrict__ hp1b, const u64* __restrict__ maskw,
    const float* __restrict__ a_src, const float* __restrict__ a_dst,
    const float* __restrict__ b1)
{
  extern __shared__ char smc[];
  short* hpTf = (short*)smc;                  // [64 koct][66 o][8]  67,584 B
  short* pSf  = (short*)(smc + 67584);        // [64 koct][66 row][8] 67,584 B
  float* srcS = (float*)(smc + 135168);       // [512]
  float* dstS = (float*)(smc + 137216);       // [512]
  float* asS  = (float*)(smc + 139264);       // [64]
  float* adS  = (float*)(smc + 139520);       // [64]
  float* rcpS = (float*)(smc + 139776);       // [64]  end 140,032

  int bh = blockIdx.x;
  int b = bh >> 3, h = bh & 7;
  int tid = threadIdx.x;

  if (tid < 64) asS[tid] = a_src[h*64 + tid];
  else if (tid < 128) adS[tid - 64] = a_dst[h*64 + (tid - 64)];
  __syncthreads();

  // phase 0: load V slice, src/dst dots, scatter V into fragment order
  {
    int m = tid >> 1, half = tid & 1;
    int koct = m >> 3, sub = m & 7;
    const u16* hpRow = hp1b + ((long)bh*NN + m)*64 + half*32;
    float ps = 0.f, pd = 0.f;
    #pragma unroll
    for (int qq = 0; qq < 4; ++qq) {
      bf16x8 hv = *(const bf16x8*)(hpRow + qq*8);
      int o0 = half*32 + qq*8;
      #pragma unroll
      for (int j = 0; j < 8; ++j) {
        float f = bf2f(hv[j]);
        ps += f * asS[o0 + j];
        pd += f * adS[o0 + j];
        hpTf[(koct*66 + o0 + j)*8 + sub] = hv[j];
      }
    }
    ps += __shfl_xor(ps, 1);
    pd += __shfl_xor(pd, 1);
    if ((tid & 1) == 0) { srcS[m] = ps; dstS[m] = pd; }
  }
  __syncthreads();

  int wv = tid >> 6, lane = tid & 63;
  int l15 = lane & 15, lg = lane >> 4;
  int cgl = wv >> 2, nt = wv & 3;
  int lk = lane >> 3, ls = lane & 7;
  int o_out = nt*16 + l15;
  float bb  = b1[o_out];

  for (int sup = 0; sup < 8; ++sup) {
    // softmax (no-max, unnormalized): wave wv owns rows sup*64 + wv*4 + {0..3}
    #pragma unroll
    for (int rr = 0; rr < 4; ++rr) {
      int rloc = wv*4 + rr;
      int row  = sup*64 + rloc;
      float srcv = srcS[row];
      const u64* mrow = maskw + ((long)(b*NN + row))*8;
      float lsum = 0.f;
      #pragma unroll
      for (int j = 0; j < 8; ++j) {
        u64 w = mrow[j];
        float s = srcv + dstS[j*64 + lane];
        float e = ((w >> lane) & 1ull) ? lrelu_f(s) : -1.0e9f;
        float p = __expf(e);                        // masked -> exactly 0
        lsum += p;
        pSf[((j*8 + lk)*66 + rloc)*8 + ls] = f2bf(p);   // no sum dependence
      }
      #pragma unroll
      for (int mk = 1; mk <= 32; mk <<= 1) lsum += __shfl_xor(lsum, mk);
      if (lane == 0) rcpS[rloc] = 1.f / lsum;       // consumed at PV epilogue
    }
    __syncthreads();

    // PV via MFMA: wave (cgl,nt) -> rows cgl*16.., cols nt*16.., K=512
    f32x4 acc = {0.f, 0.f, 0.f, 0.f};
    #pragma unroll
    for (int ks = 0; ks < 16; ++ks) {
      int koct = ks*4 + lg;
      bf16x8 af = *(const bf16x8*)&pSf [(koct*66 + cgl*16 + l15)*8];
      bf16x8 bf = *(const bf16x8*)&hpTf[(koct*66 + nt*16  + l15)*8];
      acc = __builtin_amdgcn_mfma_f32_16x16x32_bf16(af, bf, acc, 0, 0, 0);
    }
    #pragma unroll
    for (int reg = 0; reg < 4; ++reg) {
      int rloc = cgl*16 + lg*4 + reg;
      int row  = sup*64 + rloc;
      float v = elu_f(acc[reg] * rcpS[rloc] + bb);  // deferred normalization
      hp1b[((long)bh*NN + row)*64 + o_out] = (u16)f2bf(v);
    }
    __syncthreads();
  }
}

// ---------------------------------------------------------------------------
// K6: GAT layer-2 attention (rows 0,1 only) + ELU + MLP + log_softmax.
// ---------------------------------------------------------------------------
__global__ __launch_bounds__(256) void gat2_final(
    const float* __restrict__ hp2, const u64* __restrict__ maskw,
    const float* __restrict__ a_src2, const float* __restrict__ a_dst2,
    const float* __restrict__ b2,
    const float* __restrict__ fc1_w, const float* __restrict__ fc1_b,
    const float* __restrict__ fc2_w, const float* __restrict__ fc2_b,
    const float* __restrict__ fc3_w, const float* __restrict__ fc3_b,
    float* __restrict__ out)
{
  extern __shared__ float sm[];
  float* hpS  = sm;              // 32768
  float* dstS = hpS + 32768;     // 512
  float* srcS = dstS + 512;      // 512
  float* pS   = srcS + 512;      // 512
  float* redS = pS + 512;        // 256
  float* outS = redS + 256;      // 128
  float* vS   = outS + 128;      // 64
  float* y1S  = vS + 64;         // 192
  float* redM = y1S + 192;       // 8
  float4* hpS4 = (float4*)hpS;

  int b = blockIdx.x;
  int tid = threadIdx.x;
  int og = tid & 15, m16 = tid >> 4;

  for (int it = 0; it < 32; ++it) {
    int fi = it*256 + tid;
    int m = fi >> 4, o4 = fi & 15;
    hpS4[m*16 + o4] = *(const float4*)(hp2 + (long)(b*NN + m)*64 + o4*4);
  }
  __syncthreads();

  float4 as4 = *(const float4*)(a_src2 + og*4);
  float4 ad4 = *(const float4*)(a_dst2 + og*4);
  for (int it = 0; it < 32; ++it) {
    int m = it*16 + m16;
    float4 hv = hpS4[m*16 + og];
    float ls = hv.x*as4.x + hv.y*as4.y + hv.z*as4.z + hv.w*as4.w;
    float ld = hv.x*ad4.x + hv.y*ad4.y + hv.z*ad4.z + hv.w*ad4.w;
    #pragma unroll
    for (int mk = 1; mk <= 8; mk <<= 1) {
      ls += __shfl_xor(ls, mk);
      ld += __shfl_xor(ld, mk);
    }
    if (og == 0) { srcS[m] = ls; dstS[m] = ld; }
  }
  __syncthreads();

  for (int n = 0; n < 2; ++n) {
    float srcv = srcS[n];
    const u64* mrow = maskw + (long)(b*NN + n)*8;
    int m0 = tid, m1 = tid + 256;
    u64 w0 = mrow[m0 >> 6], w1 = mrow[m1 >> 6];
    float s0 = srcv + dstS[m0], s1 = srcv + dstS[m1];
    float e0 = ((w0 >> (m0 & 63)) & 1ull) ? lrelu_f(s0) : -1.0e9f;
    float e1 = ((w1 >> (m1 & 63)) & 1ull) ? lrelu_f(s1) : -1.0e9f;
    float emax = fmaxf(e0, e1);
    #pragma unroll
    for (int mk = 1; mk <= 32; mk <<= 1) emax = fmaxf(emax, __shfl_xor(emax, mk));
    if ((tid & 63) == 0) redM[tid >> 6] = emax;
    __syncthreads();
    emax = fmaxf(fmaxf(redM[0], redM[1]), fmaxf(redM[2], redM[3]));
    float p0 = __expf(e0 - emax), p1 = __expf(e1 - emax);
    pS[m0] = p0; pS[m1] = p1;
    float lsum = p0 + p1;
    #pragma unroll
    for (int mk = 1; mk <= 32; mk <<= 1) lsum += __shfl_xor(lsum, mk);
    if ((tid & 63) == 0) redM[4 + (tid >> 6)] = lsum;
    __syncthreads();
    float rcp = 1.f / (redM[4] + redM[5] + redM[6] + redM[7]);

    float4 acc = make_float4(0.f,0.f,0.f,0.f);
    for (int mm = 0; mm < 32; ++mm) {
      int m = mm*16 + m16;
      float4 hv = hpS4[m*16 + og];
      float p = pS[m];
      acc.x += hv.x*p; acc.y += hv.y*p; acc.z += hv.z*p; acc.w += hv.w*p;
    }
    acc.x += __shfl_xor(acc.x, 16); acc.y += __shfl_xor(acc.y, 16);
    acc.z += __shfl_xor(acc.z, 16); acc.w += __shfl_xor(acc.w, 16);
    acc.x += __shfl_xor(acc.x, 32); acc.y += __shfl_xor(acc.y, 32);
    acc.z += __shfl_xor(acc.z, 32); acc.w += __shfl_xor(acc.w, 32);
    __syncthreads();
    if ((tid & 63) < 16) ((float4*)redS)[(tid >> 6)*16 + (tid & 15)] = acc;
    __syncthreads();
    if (tid < 16) {
      float4 s = make_float4(0.f,0.f,0.f,0.f);
      #pragma unroll
      for (int w = 0; w < 4; ++w) {
        float4 v = ((float4*)redS)[w*16 + tid];
        s.x += v.x; s.y += v.y; s.z += v.z; s.w += v.w;
      }
      float4 bv = *(const float4*)(b2 + tid*4);
      outS[n*64 + tid*4 + 0] = elu_f(s.x*rcp + bv.x);
      outS[n*64 + tid*4 + 1] = elu_f(s.y*rcp + bv.y);
      outS[n*64 + tid*4 + 2] = elu_f(s.z*rcp + bv.z);
      outS[n*64 + tid*4 + 3] = elu_f(s.w*rcp + bv.w);
    }
    __syncthreads();
  }

  if (tid < 64) vS[tid] = outS[tid] * outS[64 + tid];
  __syncthreads();
  if (tid < 192) {
    float a = fc1_b[tid];
    for (int o = 0; o < 64; ++o) a += vS[o]*fc1_w[o*192 + tid];
    y1S[tid] = a > 0.f ? a : 0.f;
  }
  __syncthreads();
  if (tid < 64) {
    float a = fc2_b[tid];
    for (int j = 0; j < 192; ++j) a += y1S[j]*fc2_w[j*64 + tid];
    vS[tid] = a > 0.f ? a : 0.f;
  }
  __syncthreads();
  if (tid == 0) {
    float t0 = fc3_b[0], t1 = fc3_b[1];
    for (int k = 0; k < 64; ++k) {
      float y = vS[k];
      t0 += y*fc3_w[k*2 + 0];
      t1 += y*fc3_w[k*2 + 1];
    }
    float mx = fmaxf(t0, t1);
    float lse = mx + logf(__expf(t0 - mx) + __expf(t1 - mx));
    out[b*2 + 0] = t0 - lse;
    out[b*2 + 1] = t1 - lse;
  }
}

// ---------------------------------------------------------------------------
extern "C" void kernel_launch(void* const* d_in, const int* in_sizes, int n_in,
                              void* d_out, int out_size, void* d_ws, size_t ws_size,
                              hipStream_t stream) {
  const float* emb    = (const float*)d_in[0];
  const int*   adj    = (const int*)d_in[1];
  const float* vt     = (const float*)d_in[2];
  const float* w1     = (const float*)d_in[3];
  const float* a_src1 = (const float*)d_in[4];
  const float* a_dst1 = (const float*)d_in[5];
  const float* b1     = (const float*)d_in[6];
  const float* w2     = (const float*)d_in[7];
  const float* a_src2 = (const float*)d_in[8];
  const float* a_dst2 = (const float*)d_in[9];
  const float* b2     = (const float*)d_in[10];
  const float* fc1_w  = (const float*)d_in[11];
  const float* fc1_b  = (const float*)d_in[12];
  const float* fc2_w  = (const float*)d_in[13];
  const float* fc2_b  = (const float*)d_in[14];
  const float* fc3_w  = (const float*)d_in[15];
  const float* fc3_b  = (const float*)d_in[16];

  char* ws = (char*)d_ws;
  int* counts  = (int*)ws;
  int* rowlist = (int*)(ws + 4096);
  u64* maskw   = (u64*)(ws + 204800);
  u16* w1t     = (u16*)(ws + 1310720);
  u16* w2t     = (u16*)(ws + 3670016);
  u16* hp1b    = (u16*)(ws + 3932160);
  float* hp2   = (float*)(ws + 20709376);

  hipMemsetAsync(counts, 0, 16, stream);
  prep_kernel<<<NROWS/4, 256, 0, stream>>>(adj, maskw);
  rowlist_kernel<<<NROWS/256, 256, 0, stream>>>(vt, rowlist, counts);
  conv_w<<<dim3(27, 4), 256, 0, stream>>>(w1, w2, w1t, w2t);

  gemm1_mfma<<<dim3(352, 1, 3), 256, 0, stream>>>(emb, w1t, rowlist, counts, hp1b);

  size_t sm1 = 140032;
  gat1_attn<<<BB*NH, 1024, sm1, stream>>>(hp1b, maskw, a_src1, a_dst1, b1);

  gemm2_mfma<<<dim3(1, 256, 3), 256, 0, stream>>>(hp1b, w2t, rowlist, counts, hp2);

  size_t sm2 = (size_t)(32768 + 512 + 512 + 512 + 256 + 128 + 64 + 192 + 8) * 4;
  gat2_final<<<BB, 256, sm2, stream>>>(hp2, maskw, a_src2, a_dst2, b2,
                                       fc1_w, fc1_b, fc2_w, fc2_b, fc3_w, fc3_b,
                                       (float*)d_out);
}